// Round 1
// baseline (3046.453 us; speedup 1.0000x reference)
//
#include <hip/hip_runtime.h>

constexpr int NN  = 20000;   // nodes
constexpr int NE  = 320000;  // edges
constexpr int NIN = 64;      // node feature dim
constexpr int HH  = 256;     // hidden
constexpr int NG  = 64;      // graphs

// workspace layout (in floats)
constexpr size_t OFF_W1C   = 0;                          // 256*64
constexpr size_t OFF_B1C   = 16384;                      // 64
constexpr size_t OFF_W2C   = 16448;                      // 256*256
constexpr size_t OFF_B2C   = 81984;                      // 256
constexpr size_t OFF_AGGR1 = 82240;                      // 20000*64
constexpr size_t OFF_AGGR2 = 1362240;                    // 20000*256
constexpr size_t OFF_H1    = 6482240;                    // 20000*256
constexpr size_t OFF_POOL  = 11602240;                   // 64*256
constexpr size_t OFF_CNT   = 11618624;                   // 64

__device__ __forceinline__ float4 relu4(float a, float b, float c, float d) {
  float4 r; r.x = fmaxf(a, 0.f); r.y = fmaxf(b, 0.f); r.z = fmaxf(c, 0.f); r.w = fmaxf(d, 0.f);
  return r;
}

// ---------------------------------------------------------------------------
// Register-tiled GEMM: acc[TM][TN] += As(64 x K, XOR-swizzled LDS) @ B(K x NOUT, global)
// Swizzle: element (m,k) stored at word m*K + (k ^ (((m>>2)&7)<<2))
// ---------------------------------------------------------------------------
template <int TM, int TN, int K, int NOUT>
__device__ __forceinline__ void tile_gemm(const float* __restrict__ As,
                                          const float* __restrict__ B,
                                          float (&acc)[TM][TN], int m0, int n0) {
  const float4* A4 = (const float4*)As;
  constexpr int KW = K / 4;
  for (int k = 0; k < K; k += 4) {
    float4 a[TM];
#pragma unroll
    for (int i = 0; i < TM; ++i) {
      int m = m0 + i;
      a[i] = A4[m * KW + ((k >> 2) ^ ((m >> 2) & 7))];
    }
#pragma unroll
    for (int kk = 0; kk < 4; ++kk) {
      float bv[TN];
#pragma unroll
      for (int j4 = 0; j4 < TN / 4; ++j4) {
        float4 w = *(const float4*)&B[(size_t)(k + kk) * NOUT + n0 + j4 * 4];
        bv[j4 * 4 + 0] = w.x; bv[j4 * 4 + 1] = w.y; bv[j4 * 4 + 2] = w.z; bv[j4 * 4 + 3] = w.w;
      }
#pragma unroll
      for (int i = 0; i < TM; ++i) {
        float av = (kk == 0) ? a[i].x : (kk == 1) ? a[i].y : (kk == 2) ? a[i].z : a[i].w;
#pragma unroll
        for (int j = 0; j < TN; ++j) acc[i][j] = fmaf(av, bv[j], acc[i][j]);
      }
    }
  }
}

// ---------------------------------------------------------------------------
// Fold edge-MLP second layer into the GINE edge projections:
// W1c = ew2 @ le1_w, b1c = eb2 @ le1_w + le1_b  (and same for 2)
// ---------------------------------------------------------------------------
__global__ __launch_bounds__(256) void prep_weights(
    const float* __restrict__ ew2, const float* __restrict__ eb2,
    const float* __restrict__ le1_w, const float* __restrict__ le1_b,
    const float* __restrict__ le2_w, const float* __restrict__ le2_b,
    float* __restrict__ W1c, float* __restrict__ b1c,
    float* __restrict__ W2c, float* __restrict__ b2c) {
  int idx = blockIdx.x * 256 + threadIdx.x;
  if (idx < 16384) {
    int i = idx >> 6, j = idx & 63;
    float s = 0.f;
    for (int k = 0; k < 256; ++k) s = fmaf(ew2[i * 256 + k], le1_w[k * 64 + j], s);
    W1c[idx] = s;
  } else if (idx < 16384 + 65536) {
    int t = idx - 16384;
    int i = t >> 8, j = t & 255;
    float s = 0.f;
    for (int k = 0; k < 256; ++k) s = fmaf(ew2[i * 256 + k], le2_w[k * 256 + j], s);
    W2c[t] = s;
  } else if (idx < 16384 + 65536 + 64) {
    int j = idx - 16384 - 65536;
    float s = le1_b[j];
    for (int k = 0; k < 256; ++k) s = fmaf(eb2[k], le1_w[k * 64 + j], s);
    b1c[j] = s;
  } else if (idx < 16384 + 65536 + 64 + 256) {
    int j = idx - 16384 - 65536 - 64;
    float s = le2_b[j];
    for (int k = 0; k < 256; ++k) s = fmaf(eb2[k], le2_w[k * 256 + j], s);
    b2c[j] = s;
  }
}

// ---------------------------------------------------------------------------
// Edge conv pass: per 64-edge tile:
//   t = ReLU(edge_attr @ ew1 + eb1)            [64 x 256] in LDS (swizzled)
//   p = t @ Wc + bc                            [64 x NOUT] in regs
//   msg = ReLU(gat[src] + p); atomicAdd(aggr[dst], msg)
// ---------------------------------------------------------------------------
template <int NOUT>
__global__ __launch_bounds__(256, 2) void edge_conv(
    const float* __restrict__ edge_attr, const int* __restrict__ eidx,
    const float* __restrict__ ew1, const float* __restrict__ eb1,
    const float* __restrict__ Wc, const float* __restrict__ bc,
    const float* __restrict__ gat, float* __restrict__ aggr) {
  constexpr int TM = (NOUT == 64) ? 4 : 8;
  constexpr int TN = TM;
  constexpr int CGC = NOUT / TN;  // 16 or 32 column-groups
  __shared__ float ea_s[64 * 16];
  __shared__ float t_s[64 * 256];
  __shared__ int src_s[64];
  __shared__ int dst_s[64];
  const int tid = threadIdx.x;
  const int e0 = blockIdx.x * 64;

  if (tid < 64) {
    src_s[tid] = eidx[e0 + tid];
    dst_s[tid] = eidx[NE + e0 + tid];
  }
  // 64 edges x 16 attrs = 256 float4
  ((float4*)ea_s)[tid] = ((const float4*)edge_attr)[(size_t)e0 * 4 + tid];
  __syncthreads();

  // phase 2: column tid of t for all 64 edges
  float wcol[16];
#pragma unroll
  for (int k = 0; k < 16; ++k) wcol[k] = ew1[k * 256 + tid];
  const float bias = eb1[tid];
  const float4* ea4 = (const float4*)ea_s;
  for (int m = 0; m < 64; ++m) {
    float4 a0 = ea4[m * 4 + 0], a1 = ea4[m * 4 + 1], a2 = ea4[m * 4 + 2], a3 = ea4[m * 4 + 3];
    float s = bias;
    s = fmaf(a0.x, wcol[0], s);  s = fmaf(a0.y, wcol[1], s);
    s = fmaf(a0.z, wcol[2], s);  s = fmaf(a0.w, wcol[3], s);
    s = fmaf(a1.x, wcol[4], s);  s = fmaf(a1.y, wcol[5], s);
    s = fmaf(a1.z, wcol[6], s);  s = fmaf(a1.w, wcol[7], s);
    s = fmaf(a2.x, wcol[8], s);  s = fmaf(a2.y, wcol[9], s);
    s = fmaf(a2.z, wcol[10], s); s = fmaf(a2.w, wcol[11], s);
    s = fmaf(a3.x, wcol[12], s); s = fmaf(a3.y, wcol[13], s);
    s = fmaf(a3.z, wcol[14], s); s = fmaf(a3.w, wcol[15], s);
    t_s[m * 256 + (tid ^ (((m >> 2) & 7) << 2))] = fmaxf(s, 0.f);
  }
  __syncthreads();

  const int eg = tid / CGC, cg = tid % CGC;
  const int m0 = eg * TM, n0 = cg * TN;
  float acc[TM][TN];
#pragma unroll
  for (int j4 = 0; j4 < TN / 4; ++j4) {
    float4 b = *(const float4*)&bc[n0 + j4 * 4];
#pragma unroll
    for (int i = 0; i < TM; ++i) {
      acc[i][j4 * 4 + 0] = b.x; acc[i][j4 * 4 + 1] = b.y;
      acc[i][j4 * 4 + 2] = b.z; acc[i][j4 * 4 + 3] = b.w;
    }
  }
  tile_gemm<TM, TN, 256, NOUT>(t_s, Wc, acc, m0, n0);

  // epilogue: gather, ReLU, scatter-add
#pragma unroll
  for (int i = 0; i < TM; ++i) {
    const int m = m0 + i;
    const int src = src_s[m], dst = dst_s[m];
#pragma unroll
    for (int j4 = 0; j4 < TN / 4; ++j4) {
      float4 xv = *(const float4*)&gat[(size_t)src * NOUT + n0 + j4 * 4];
      float v0 = fmaxf(xv.x + acc[i][j4 * 4 + 0], 0.f);
      float v1 = fmaxf(xv.y + acc[i][j4 * 4 + 1], 0.f);
      float v2 = fmaxf(xv.z + acc[i][j4 * 4 + 2], 0.f);
      float v3 = fmaxf(xv.w + acc[i][j4 * 4 + 3], 0.f);
      float* dp = &aggr[(size_t)dst * NOUT + n0 + j4 * 4];
      atomicAdd(dp + 0, v0); atomicAdd(dp + 1, v1);
      atomicAdd(dp + 2, v2); atomicAdd(dp + 3, v3);
    }
  }
}

// ---------------------------------------------------------------------------
// Node MLP 1: h1 = ReLU(ReLU((x + aggr1) @ w1 + b1) @ w2 + b2)
// ---------------------------------------------------------------------------
__global__ __launch_bounds__(256, 2) void node_mlp1(
    const float* __restrict__ x, const float* __restrict__ aggr1,
    const float* __restrict__ w1, const float* __restrict__ b1,
    const float* __restrict__ w2, const float* __restrict__ b2,
    float* __restrict__ h1) {
  __shared__ float u_s[64 * 64];
  __shared__ float v_s[64 * 256];
  const int tid = threadIdx.x;
  const int i0 = blockIdx.x * 64;
#pragma unroll
  for (int r = 0; r < 4; ++r) {
    int idx4 = tid + r * 256;       // 1024 float4
    int m = idx4 >> 4, k = (idx4 & 15) * 4;
    int node = i0 + m;
    float4 v = make_float4(0.f, 0.f, 0.f, 0.f);
    if (node < NN) {
      float4 a = *(const float4*)&x[(size_t)node * 64 + k];
      float4 b = *(const float4*)&aggr1[(size_t)node * 64 + k];
      v = make_float4(a.x + b.x, a.y + b.y, a.z + b.z, a.w + b.w);
    }
    *(float4*)&u_s[m * 64 + (k ^ (((m >> 2) & 7) << 2))] = v;
  }
  __syncthreads();
  const int eg = tid / 32, cg = tid % 32;
  const int m0 = eg * 8, n0 = cg * 8;
  float acc[8][8];
#pragma unroll
  for (int j4 = 0; j4 < 2; ++j4) {
    float4 b = *(const float4*)&b1[n0 + j4 * 4];
#pragma unroll
    for (int i = 0; i < 8; ++i) {
      acc[i][j4 * 4 + 0] = b.x; acc[i][j4 * 4 + 1] = b.y;
      acc[i][j4 * 4 + 2] = b.z; acc[i][j4 * 4 + 3] = b.w;
    }
  }
  tile_gemm<8, 8, 64, 256>(u_s, w1, acc, m0, n0);
#pragma unroll
  for (int i = 0; i < 8; ++i) {
    int m = m0 + i, key = ((m >> 2) & 7) << 2;
#pragma unroll
    for (int j4 = 0; j4 < 2; ++j4) {
      *(float4*)&v_s[m * 256 + ((n0 + j4 * 4) ^ key)] =
          relu4(acc[i][j4 * 4 + 0], acc[i][j4 * 4 + 1], acc[i][j4 * 4 + 2], acc[i][j4 * 4 + 3]);
    }
  }
  __syncthreads();
  float acc2[8][8];
#pragma unroll
  for (int j4 = 0; j4 < 2; ++j4) {
    float4 b = *(const float4*)&b2[n0 + j4 * 4];
#pragma unroll
    for (int i = 0; i < 8; ++i) {
      acc2[i][j4 * 4 + 0] = b.x; acc2[i][j4 * 4 + 1] = b.y;
      acc2[i][j4 * 4 + 2] = b.z; acc2[i][j4 * 4 + 3] = b.w;
    }
  }
  tile_gemm<8, 8, 256, 256>(v_s, w2, acc2, m0, n0);
#pragma unroll
  for (int i = 0; i < 8; ++i) {
    int node = i0 + m0 + i;
    if (node < NN) {
#pragma unroll
      for (int j4 = 0; j4 < 2; ++j4) {
        *(float4*)&h1[(size_t)node * 256 + n0 + j4 * 4] =
            relu4(acc2[i][j4 * 4 + 0], acc2[i][j4 * 4 + 1], acc2[i][j4 * 4 + 2], acc2[i][j4 * 4 + 3]);
      }
    }
  }
}

// ---------------------------------------------------------------------------
// Node MLP 2 + fused mean-pool numerator: h2 = ReLU(MLP(h1 + aggr2));
// segmented column sums into pool[batch] (batch is sorted)
// ---------------------------------------------------------------------------
__global__ __launch_bounds__(256) void node_mlp2(
    const float* __restrict__ h1, const float* __restrict__ aggr2,
    const float* __restrict__ w1, const float* __restrict__ b1,
    const float* __restrict__ w2, const float* __restrict__ b2,
    const int* __restrict__ batch, float* __restrict__ pool) {
  __shared__ float u_s[64 * 256];
  __shared__ float v_s[64 * 256];
  __shared__ int batch_s[64];
  const int tid = threadIdx.x;
  const int i0 = blockIdx.x * 64;
  if (tid < 64) batch_s[tid] = (i0 + tid < NN) ? batch[i0 + tid] : -1;
#pragma unroll 4
  for (int r = 0; r < 16; ++r) {
    int idx4 = tid + r * 256;       // 4096 float4
    int m = idx4 >> 6, k = (idx4 & 63) * 4;
    int node = i0 + m;
    float4 v = make_float4(0.f, 0.f, 0.f, 0.f);
    if (node < NN) {
      float4 a = *(const float4*)&h1[(size_t)node * 256 + k];
      float4 b = *(const float4*)&aggr2[(size_t)node * 256 + k];
      v = make_float4(a.x + b.x, a.y + b.y, a.z + b.z, a.w + b.w);
    }
    *(float4*)&u_s[m * 256 + (k ^ (((m >> 2) & 7) << 2))] = v;
  }
  __syncthreads();
  const int eg = tid / 32, cg = tid % 32;
  const int m0 = eg * 8, n0 = cg * 8;
  float acc[8][8];
#pragma unroll
  for (int j4 = 0; j4 < 2; ++j4) {
    float4 b = *(const float4*)&b1[n0 + j4 * 4];
#pragma unroll
    for (int i = 0; i < 8; ++i) {
      acc[i][j4 * 4 + 0] = b.x; acc[i][j4 * 4 + 1] = b.y;
      acc[i][j4 * 4 + 2] = b.z; acc[i][j4 * 4 + 3] = b.w;
    }
  }
  tile_gemm<8, 8, 256, 256>(u_s, w1, acc, m0, n0);
#pragma unroll
  for (int i = 0; i < 8; ++i) {
    int m = m0 + i, key = ((m >> 2) & 7) << 2;
#pragma unroll
    for (int j4 = 0; j4 < 2; ++j4) {
      *(float4*)&v_s[m * 256 + ((n0 + j4 * 4) ^ key)] =
          relu4(acc[i][j4 * 4 + 0], acc[i][j4 * 4 + 1], acc[i][j4 * 4 + 2], acc[i][j4 * 4 + 3]);
    }
  }
  __syncthreads();
  float acc2[8][8];
#pragma unroll
  for (int j4 = 0; j4 < 2; ++j4) {
    float4 b = *(const float4*)&b2[n0 + j4 * 4];
#pragma unroll
    for (int i = 0; i < 8; ++i) {
      acc2[i][j4 * 4 + 0] = b.x; acc2[i][j4 * 4 + 1] = b.y;
      acc2[i][j4 * 4 + 2] = b.z; acc2[i][j4 * 4 + 3] = b.w;
    }
  }
  tile_gemm<8, 8, 256, 256>(v_s, w2, acc2, m0, n0);
  // h2 -> u_s (plain layout), then segmented pool
#pragma unroll
  for (int i = 0; i < 8; ++i) {
    int m = m0 + i;
#pragma unroll
    for (int j4 = 0; j4 < 2; ++j4) {
      *(float4*)&u_s[m * 256 + n0 + j4 * 4] =
          relu4(acc2[i][j4 * 4 + 0], acc2[i][j4 * 4 + 1], acc2[i][j4 * 4 + 2], acc2[i][j4 * 4 + 3]);
    }
  }
  __syncthreads();
  float run = 0.f;
  int curg = -2;
  for (int m = 0; m < 64; ++m) {
    int g = batch_s[m];
    if (g != curg) {
      if (curg >= 0) atomicAdd(&pool[curg * 256 + tid], run);
      run = 0.f; curg = g;
    }
    if (g >= 0) run += u_s[m * 256 + tid];
  }
  if (curg >= 0) atomicAdd(&pool[curg * 256 + tid], run);
}

__global__ __launch_bounds__(256) void count_nodes(const int* __restrict__ batch,
                                                   float* __restrict__ counts) {
  int i = blockIdx.x * 256 + threadIdx.x;
  if (i < NN) atomicAdd(&counts[batch[i]], 1.0f);
}

// ---------------------------------------------------------------------------
// Readout: g = pool/cnt -> ReLU(128) -> ReLU(64) -> 3 heads
// ---------------------------------------------------------------------------
__global__ __launch_bounds__(128) void head_kernel(
    const float* __restrict__ pool, const float* __restrict__ counts,
    const float* __restrict__ l1w, const float* __restrict__ l1b,
    const float* __restrict__ l2w, const float* __restrict__ l2b,
    const float* __restrict__ hs_w, const float* __restrict__ hs_b,
    const float* __restrict__ hp_w, const float* __restrict__ hp_b,
    const float* __restrict__ hn_w, const float* __restrict__ hn_b,
    float* __restrict__ out) {
  const int g = blockIdx.x, tid = threadIdx.x;
  __shared__ float g_s[256], g1_s[128], g2_s[64];
  float cnt = fmaxf(counts[g], 1.0f);
  g_s[tid] = pool[g * 256 + tid] / cnt;
  g_s[tid + 128] = pool[g * 256 + tid + 128] / cnt;
  __syncthreads();
  float s = l1b[tid];
  for (int k = 0; k < 256; ++k) s = fmaf(g_s[k], l1w[k * 128 + tid], s);
  g1_s[tid] = fmaxf(s, 0.f);
  __syncthreads();
  if (tid < 64) {
    float s2 = l2b[tid];
    for (int k = 0; k < 128; ++k) s2 = fmaf(g1_s[k], l2w[k * 64 + tid], s2);
    g2_s[tid] = fmaxf(s2, 0.f);
  }
  __syncthreads();
  if (tid < 64) {
    float v = g2_s[tid];
    float a = v * hs_w[tid], b = v * hp_w[tid], c = v * hn_w[tid];
    for (int off = 32; off > 0; off >>= 1) {
      a += __shfl_down(a, off, 64);
      b += __shfl_down(b, off, 64);
      c += __shfl_down(c, off, 64);
    }
    if (tid == 0) {
      out[g]        = a + hs_b[0];
      out[64 + g]   = b + hp_b[0];
      out[128 + g]  = c + hn_b[0];
    }
  }
}

extern "C" void kernel_launch(void* const* d_in, const int* in_sizes, int n_in,
                              void* d_out, int out_size, void* d_ws, size_t ws_size,
                              hipStream_t stream) {
  (void)in_sizes; (void)n_in; (void)out_size; (void)ws_size;
  const float* x         = (const float*)d_in[0];
  const int*   eidx      = (const int*)d_in[1];
  const int*   batch     = (const int*)d_in[2];
  const float* edge_attr = (const float*)d_in[3];
  const float* ew1  = (const float*)d_in[4];
  const float* eb1  = (const float*)d_in[5];
  const float* ew2  = (const float*)d_in[6];
  const float* eb2  = (const float*)d_in[7];
  const float* le1w = (const float*)d_in[8];
  const float* le1b = (const float*)d_in[9];
  const float* le2w = (const float*)d_in[10];
  const float* le2b = (const float*)d_in[11];
  const float* n1w1 = (const float*)d_in[12];
  const float* n1b1 = (const float*)d_in[13];
  const float* n1w2 = (const float*)d_in[14];
  const float* n1b2 = (const float*)d_in[15];
  const float* n2w1 = (const float*)d_in[16];
  const float* n2b1 = (const float*)d_in[17];
  const float* n2w2 = (const float*)d_in[18];
  const float* n2b2 = (const float*)d_in[19];
  const float* l1w  = (const float*)d_in[20];
  const float* l1b  = (const float*)d_in[21];
  const float* l2w  = (const float*)d_in[22];
  const float* l2b  = (const float*)d_in[23];
  const float* hs_w = (const float*)d_in[24];
  const float* hs_b = (const float*)d_in[25];
  const float* hp_w = (const float*)d_in[26];
  const float* hp_b = (const float*)d_in[27];
  const float* hn_w = (const float*)d_in[28];
  const float* hn_b = (const float*)d_in[29];

  float* ws    = (float*)d_ws;
  float* W1c   = ws + OFF_W1C;
  float* b1c   = ws + OFF_B1C;
  float* W2c   = ws + OFF_W2C;
  float* b2c   = ws + OFF_B2C;
  float* aggr1 = ws + OFF_AGGR1;
  float* aggr2 = ws + OFF_AGGR2;
  float* h1    = ws + OFF_H1;
  float* pool  = ws + OFF_POOL;
  float* cnts  = ws + OFF_CNT;
  float* out   = (float*)d_out;

  hipMemsetAsync(aggr1, 0, (size_t)NN * 64 * 4, stream);
  hipMemsetAsync(aggr2, 0, (size_t)NN * 256 * 4, stream);
  hipMemsetAsync(pool, 0, (size_t)NG * 256 * 4, stream);
  hipMemsetAsync(cnts, 0, (size_t)NG * 4, stream);

  prep_weights<<<322, 256, 0, stream>>>(ew2, eb2, le1w, le1b, le2w, le2b, W1c, b1c, W2c, b2c);
  count_nodes<<<(NN + 255) / 256, 256, 0, stream>>>(batch, cnts);

  edge_conv<64><<<NE / 64, 256, 0, stream>>>(edge_attr, eidx, ew1, eb1, W1c, b1c, x, aggr1);
  node_mlp1<<<(NN + 63) / 64, 256, 0, stream>>>(x, aggr1, n1w1, n1b1, n1w2, n1b2, h1);
  edge_conv<256><<<NE / 64, 256, 0, stream>>>(edge_attr, eidx, ew1, eb1, W2c, b2c, h1, aggr2);
  node_mlp2<<<(NN + 63) / 64, 256, 0, stream>>>(h1, aggr2, n2w1, n2b1, n2w2, n2b2, batch, pool);
  head_kernel<<<NG, 128, 0, stream>>>(pool, cnts, l1w, l1b, l2w, l2b,
                                      hs_w, hs_b, hp_w, hp_b, hn_w, hn_b, out);
}

// Round 2
// 1296.711 us; speedup vs baseline: 2.3494x; 2.3494x over previous
//
#include <hip/hip_runtime.h>

constexpr int NN  = 20000;   // nodes
constexpr int NE  = 320000;  // edges
constexpr int NG  = 64;      // graphs

// workspace layout (in 4-byte units)
constexpr size_t OFF_W1C    = 0;                          // 256*64
constexpr size_t OFF_B1C    = 16384;                      // 64
constexpr size_t OFF_W2C    = 16448;                      // 256*256
constexpr size_t OFF_B2C    = 81984;                      // 256
constexpr size_t OFF_AGGR1  = 82240;                      // 20000*64
constexpr size_t OFF_AGGR2  = 1362240;                    // 20000*256
constexpr size_t OFF_H1     = 6482240;                    // 20000*256
constexpr size_t OFF_POOL   = 11602240;                   // 64*256
constexpr size_t OFF_CNT    = 11618624;                   // 64
constexpr size_t OFF_CURSOR = 11618688;                   // 20000 ints (deg, then cursor)
constexpr size_t OFF_ROWPTR = 11638688;                   // 20001 ints
constexpr size_t OFF_PERM   = 11658689;                   // 320000 ints

__device__ __forceinline__ float4 relu4(float a, float b, float c, float d) {
  float4 r; r.x = fmaxf(a, 0.f); r.y = fmaxf(b, 0.f); r.z = fmaxf(c, 0.f); r.w = fmaxf(d, 0.f);
  return r;
}

// ---------------------------------------------------------------------------
// Register-tiled GEMM: acc[TM][TN] += As(64 x K, XOR-swizzled LDS) @ B(K x NOUT, global)
// Swizzle: element (m,k) stored at word m*K + (k ^ (((m>>2)&7)<<2))
// ---------------------------------------------------------------------------
template <int TM, int TN, int K, int NOUT>
__device__ __forceinline__ void tile_gemm(const float* __restrict__ As,
                                          const float* __restrict__ B,
                                          float (&acc)[TM][TN], int m0, int n0) {
  const float4* A4 = (const float4*)As;
  constexpr int KW = K / 4;
  for (int k = 0; k < K; k += 4) {
    float4 a[TM];
#pragma unroll
    for (int i = 0; i < TM; ++i) {
      int m = m0 + i;
      a[i] = A4[m * KW + ((k >> 2) ^ ((m >> 2) & 7))];
    }
#pragma unroll
    for (int kk = 0; kk < 4; ++kk) {
      float bv[TN];
#pragma unroll
      for (int j4 = 0; j4 < TN / 4; ++j4) {
        float4 w = *(const float4*)&B[(size_t)(k + kk) * NOUT + n0 + j4 * 4];
        bv[j4 * 4 + 0] = w.x; bv[j4 * 4 + 1] = w.y; bv[j4 * 4 + 2] = w.z; bv[j4 * 4 + 3] = w.w;
      }
#pragma unroll
      for (int i = 0; i < TM; ++i) {
        float av = (kk == 0) ? a[i].x : (kk == 1) ? a[i].y : (kk == 2) ? a[i].z : a[i].w;
#pragma unroll
        for (int j = 0; j < TN; ++j) acc[i][j] = fmaf(av, bv[j], acc[i][j]);
      }
    }
  }
}

// ---------------------------------------------------------------------------
// Fold edge-MLP second layer into the GINE edge projections:
// W1c = ew2 @ le1_w, b1c = eb2 @ le1_w + le1_b  (and same for 2)
// ---------------------------------------------------------------------------
__global__ __launch_bounds__(256) void prep_weights(
    const float* __restrict__ ew2, const float* __restrict__ eb2,
    const float* __restrict__ le1_w, const float* __restrict__ le1_b,
    const float* __restrict__ le2_w, const float* __restrict__ le2_b,
    float* __restrict__ W1c, float* __restrict__ b1c,
    float* __restrict__ W2c, float* __restrict__ b2c) {
  int idx = blockIdx.x * 256 + threadIdx.x;
  if (idx < 16384) {
    int i = idx >> 6, j = idx & 63;
    float s = 0.f;
    for (int k = 0; k < 256; ++k) s = fmaf(ew2[i * 256 + k], le1_w[k * 64 + j], s);
    W1c[idx] = s;
  } else if (idx < 16384 + 65536) {
    int t = idx - 16384;
    int i = t >> 8, j = t & 255;
    float s = 0.f;
    for (int k = 0; k < 256; ++k) s = fmaf(ew2[i * 256 + k], le2_w[k * 256 + j], s);
    W2c[t] = s;
  } else if (idx < 16384 + 65536 + 64) {
    int j = idx - 16384 - 65536;
    float s = le1_b[j];
    for (int k = 0; k < 256; ++k) s = fmaf(eb2[k], le1_w[k * 64 + j], s);
    b1c[j] = s;
  } else if (idx < 16384 + 65536 + 64 + 256) {
    int j = idx - 16384 - 65536 - 64;
    float s = le2_b[j];
    for (int k = 0; k < 256; ++k) s = fmaf(eb2[k], le2_w[k * 256 + j], s);
    b2c[j] = s;
  }
}

// ---------------------------------------------------------------------------
// CSR build: count degrees, scan, scatter slots, per-node sort (determinism)
// ---------------------------------------------------------------------------
__global__ __launch_bounds__(256) void count_deg(const int* __restrict__ eidx,
                                                 int* __restrict__ deg) {
  int e = blockIdx.x * 256 + threadIdx.x;
  if (e < NE) atomicAdd(&deg[eidx[NE + e]], 1);
}

__global__ __launch_bounds__(256) void scan_rowptr(int* __restrict__ degcur,
                                                   int* __restrict__ rowptr) {
  // single block; inclusive wave scans chained over 256-chunks
  __shared__ int wsum[4];
  const int tid = threadIdx.x, lane = tid & 63, w = tid >> 6;
  int base = 0;
  for (int c0 = 0; c0 < NN; c0 += 256) {
    int i = c0 + tid;
    int v = (i < NN) ? degcur[i] : 0;
    int x = v;
#pragma unroll
    for (int off = 1; off < 64; off <<= 1) {
      int y = __shfl_up(x, off, 64);
      if (lane >= off) x += y;
    }
    if (lane == 63) wsum[w] = x;
    __syncthreads();
    int woff = 0;
    for (int k = 0; k < w; ++k) woff += wsum[k];
    int tot = wsum[0] + wsum[1] + wsum[2] + wsum[3];
    if (i < NN) {
      int ex = base + woff + x - v;   // exclusive prefix
      rowptr[i] = ex;
      degcur[i] = ex;                 // becomes the scatter cursor
    }
    base += tot;
    __syncthreads();
  }
  if (tid == 0) rowptr[NN] = base;
}

__global__ __launch_bounds__(256) void scatter_perm(const int* __restrict__ eidx,
                                                    int* __restrict__ cursor,
                                                    int* __restrict__ perm) {
  int e = blockIdx.x * 256 + threadIdx.x;
  if (e < NE) {
    int d = eidx[NE + e];
    int slot = atomicAdd(&cursor[d], 1);
    perm[slot] = e;
  }
}

__global__ __launch_bounds__(256) void sort_segments(const int* __restrict__ rowptr,
                                                     int* __restrict__ perm) {
  int n = blockIdx.x * 256 + threadIdx.x;
  if (n < NN) {
    int s = rowptr[n], t = rowptr[n + 1];
    for (int i = s + 1; i < t; ++i) {
      int key = perm[i], j = i - 1;
      while (j >= s && perm[j] > key) { perm[j + 1] = perm[j]; --j; }
      perm[j + 1] = key;
    }
  }
}

// ---------------------------------------------------------------------------
// Edge conv pass over dst-sorted edges: per 64-edge tile:
//   t = ReLU(edge_attr[perm] @ ew1 + eb1)      [64 x 256] in LDS (swizzled)
//   p = t @ Wc + bc                            [64 x NOUT] in regs
//   msg = ReLU(gat[src] + p) -> LDS; segmented column-reduce over sorted dst
//   -> one atomicAdd per (run, column)
// ---------------------------------------------------------------------------
template <int NOUT>
__global__ __launch_bounds__(256, 2) void edge_conv(
    const float* __restrict__ edge_attr, const int* __restrict__ eidx,
    const int* __restrict__ perm,
    const float* __restrict__ ew1, const float* __restrict__ eb1,
    const float* __restrict__ Wc, const float* __restrict__ bc,
    const float* __restrict__ gat, float* __restrict__ aggr) {
  constexpr int TM = (NOUT == 64) ? 4 : 8;
  constexpr int TN = TM;
  constexpr int CGC = NOUT / TN;  // column-groups: 16 or 32
  __shared__ float ea_s[64 * 16];
  __shared__ float t_s[64 * 256];
  __shared__ int perm_s[64];
  __shared__ int src_s[64];
  __shared__ int dst_s[64];
  const int tid = threadIdx.x;
  const int e0 = blockIdx.x * 64;

  if (tid < 64) {
    int p = perm[e0 + tid];
    perm_s[tid] = p;
    src_s[tid] = eidx[p];
    dst_s[tid] = eidx[NE + p];
  }
  __syncthreads();
  {
    int r = tid >> 2, q = tid & 3;
    *(float4*)&ea_s[r * 16 + q * 4] =
        *(const float4*)&edge_attr[(size_t)perm_s[r] * 16 + q * 4];
  }
  __syncthreads();

  // phase 2: column tid of t for all 64 edges
  float wcol[16];
#pragma unroll
  for (int k = 0; k < 16; ++k) wcol[k] = ew1[k * 256 + tid];
  const float bias = eb1[tid];
  const float4* ea4 = (const float4*)ea_s;
  for (int m = 0; m < 64; ++m) {
    float4 a0 = ea4[m * 4 + 0], a1 = ea4[m * 4 + 1], a2 = ea4[m * 4 + 2], a3 = ea4[m * 4 + 3];
    float s = bias;
    s = fmaf(a0.x, wcol[0], s);  s = fmaf(a0.y, wcol[1], s);
    s = fmaf(a0.z, wcol[2], s);  s = fmaf(a0.w, wcol[3], s);
    s = fmaf(a1.x, wcol[4], s);  s = fmaf(a1.y, wcol[5], s);
    s = fmaf(a1.z, wcol[6], s);  s = fmaf(a1.w, wcol[7], s);
    s = fmaf(a2.x, wcol[8], s);  s = fmaf(a2.y, wcol[9], s);
    s = fmaf(a2.z, wcol[10], s); s = fmaf(a2.w, wcol[11], s);
    s = fmaf(a3.x, wcol[12], s); s = fmaf(a3.y, wcol[13], s);
    s = fmaf(a3.z, wcol[14], s); s = fmaf(a3.w, wcol[15], s);
    t_s[m * 256 + (tid ^ (((m >> 2) & 7) << 2))] = fmaxf(s, 0.f);
  }
  __syncthreads();

  const int eg = tid / CGC, cg = tid % CGC;
  const int m0 = eg * TM, n0 = cg * TN;
  float acc[TM][TN];
#pragma unroll
  for (int j4 = 0; j4 < TN / 4; ++j4) {
    float4 b = *(const float4*)&bc[n0 + j4 * 4];
#pragma unroll
    for (int i = 0; i < TM; ++i) {
      acc[i][j4 * 4 + 0] = b.x; acc[i][j4 * 4 + 1] = b.y;
      acc[i][j4 * 4 + 2] = b.z; acc[i][j4 * 4 + 3] = b.w;
    }
  }
  tile_gemm<TM, TN, 256, NOUT>(t_s, Wc, acc, m0, n0);

  __syncthreads();  // all GEMM reads of t_s done; reuse as msg tile [64][NOUT]
#pragma unroll
  for (int i = 0; i < TM; ++i) {
    const int m = m0 + i, key = ((m >> 2) & 7) << 2;
    const int src = src_s[m];
#pragma unroll
    for (int j4 = 0; j4 < TN / 4; ++j4) {
      float4 xv = *(const float4*)&gat[(size_t)src * NOUT + n0 + j4 * 4];
      *(float4*)&t_s[m * NOUT + ((n0 + j4 * 4) ^ key)] =
          relu4(xv.x + acc[i][j4 * 4 + 0], xv.y + acc[i][j4 * 4 + 1],
                xv.z + acc[i][j4 * 4 + 2], xv.w + acc[i][j4 * 4 + 3]);
    }
  }
  __syncthreads();

  // segmented column reduction over sorted dst runs
  if (tid < NOUT) {
    float run = 0.f;
    int cur = dst_s[0];
    for (int m = 0; m < 64; ++m) {
      int d = dst_s[m];
      if (d != cur) {
        atomicAdd(&aggr[(size_t)cur * NOUT + tid], run);
        run = 0.f; cur = d;
      }
      run += t_s[m * NOUT + (tid ^ (((m >> 2) & 7) << 2))];
    }
    atomicAdd(&aggr[(size_t)cur * NOUT + tid], run);
  }
}

// ---------------------------------------------------------------------------
// Node MLP 1: h1 = ReLU(ReLU((x + aggr1) @ w1 + b1) @ w2 + b2)
// ---------------------------------------------------------------------------
__global__ __launch_bounds__(256, 2) void node_mlp1(
    const float* __restrict__ x, const float* __restrict__ aggr1,
    const float* __restrict__ w1, const float* __restrict__ b1,
    const float* __restrict__ w2, const float* __restrict__ b2,
    float* __restrict__ h1) {
  __shared__ float u_s[64 * 64];
  __shared__ float v_s[64 * 256];
  const int tid = threadIdx.x;
  const int i0 = blockIdx.x * 64;
#pragma unroll
  for (int r = 0; r < 4; ++r) {
    int idx4 = tid + r * 256;       // 1024 float4
    int m = idx4 >> 4, k = (idx4 & 15) * 4;
    int node = i0 + m;
    float4 v = make_float4(0.f, 0.f, 0.f, 0.f);
    if (node < NN) {
      float4 a = *(const float4*)&x[(size_t)node * 64 + k];
      float4 b = *(const float4*)&aggr1[(size_t)node * 64 + k];
      v = make_float4(a.x + b.x, a.y + b.y, a.z + b.z, a.w + b.w);
    }
    *(float4*)&u_s[m * 64 + (k ^ (((m >> 2) & 7) << 2))] = v;
  }
  __syncthreads();
  const int eg = tid / 32, cg = tid % 32;
  const int m0 = eg * 8, n0 = cg * 8;
  float acc[8][8];
#pragma unroll
  for (int j4 = 0; j4 < 2; ++j4) {
    float4 b = *(const float4*)&b1[n0 + j4 * 4];
#pragma unroll
    for (int i = 0; i < 8; ++i) {
      acc[i][j4 * 4 + 0] = b.x; acc[i][j4 * 4 + 1] = b.y;
      acc[i][j4 * 4 + 2] = b.z; acc[i][j4 * 4 + 3] = b.w;
    }
  }
  tile_gemm<8, 8, 64, 256>(u_s, w1, acc, m0, n0);
#pragma unroll
  for (int i = 0; i < 8; ++i) {
    int m = m0 + i, key = ((m >> 2) & 7) << 2;
#pragma unroll
    for (int j4 = 0; j4 < 2; ++j4) {
      *(float4*)&v_s[m * 256 + ((n0 + j4 * 4) ^ key)] =
          relu4(acc[i][j4 * 4 + 0], acc[i][j4 * 4 + 1], acc[i][j4 * 4 + 2], acc[i][j4 * 4 + 3]);
    }
  }
  __syncthreads();
  float acc2[8][8];
#pragma unroll
  for (int j4 = 0; j4 < 2; ++j4) {
    float4 b = *(const float4*)&b2[n0 + j4 * 4];
#pragma unroll
    for (int i = 0; i < 8; ++i) {
      acc2[i][j4 * 4 + 0] = b.x; acc2[i][j4 * 4 + 1] = b.y;
      acc2[i][j4 * 4 + 2] = b.z; acc2[i][j4 * 4 + 3] = b.w;
    }
  }
  tile_gemm<8, 8, 256, 256>(v_s, w2, acc2, m0, n0);
#pragma unroll
  for (int i = 0; i < 8; ++i) {
    int node = i0 + m0 + i;
    if (node < NN) {
#pragma unroll
      for (int j4 = 0; j4 < 2; ++j4) {
        *(float4*)&h1[(size_t)node * 256 + n0 + j4 * 4] =
            relu4(acc2[i][j4 * 4 + 0], acc2[i][j4 * 4 + 1], acc2[i][j4 * 4 + 2], acc2[i][j4 * 4 + 3]);
      }
    }
  }
}

// ---------------------------------------------------------------------------
// Node MLP 2 + fused mean-pool numerator: h2 = ReLU(MLP(h1 + aggr2));
// segmented column sums into pool[batch] (batch is sorted)
// ---------------------------------------------------------------------------
__global__ __launch_bounds__(256) void node_mlp2(
    const float* __restrict__ h1, const float* __restrict__ aggr2,
    const float* __restrict__ w1, const float* __restrict__ b1,
    const float* __restrict__ w2, const float* __restrict__ b2,
    const int* __restrict__ batch, float* __restrict__ pool) {
  __shared__ float u_s[64 * 256];
  __shared__ float v_s[64 * 256];
  __shared__ int batch_s[64];
  const int tid = threadIdx.x;
  const int i0 = blockIdx.x * 64;
  if (tid < 64) batch_s[tid] = (i0 + tid < NN) ? batch[i0 + tid] : -1;
#pragma unroll 4
  for (int r = 0; r < 16; ++r) {
    int idx4 = tid + r * 256;       // 4096 float4
    int m = idx4 >> 6, k = (idx4 & 63) * 4;
    int node = i0 + m;
    float4 v = make_float4(0.f, 0.f, 0.f, 0.f);
    if (node < NN) {
      float4 a = *(const float4*)&h1[(size_t)node * 256 + k];
      float4 b = *(const float4*)&aggr2[(size_t)node * 256 + k];
      v = make_float4(a.x + b.x, a.y + b.y, a.z + b.z, a.w + b.w);
    }
    *(float4*)&u_s[m * 256 + (k ^ (((m >> 2) & 7) << 2))] = v;
  }
  __syncthreads();
  const int eg = tid / 32, cg = tid % 32;
  const int m0 = eg * 8, n0 = cg * 8;
  float acc[8][8];
#pragma unroll
  for (int j4 = 0; j4 < 2; ++j4) {
    float4 b = *(const float4*)&b1[n0 + j4 * 4];
#pragma unroll
    for (int i = 0; i < 8; ++i) {
      acc[i][j4 * 4 + 0] = b.x; acc[i][j4 * 4 + 1] = b.y;
      acc[i][j4 * 4 + 2] = b.z; acc[i][j4 * 4 + 3] = b.w;
    }
  }
  tile_gemm<8, 8, 256, 256>(u_s, w1, acc, m0, n0);
#pragma unroll
  for (int i = 0; i < 8; ++i) {
    int m = m0 + i, key = ((m >> 2) & 7) << 2;
#pragma unroll
    for (int j4 = 0; j4 < 2; ++j4) {
      *(float4*)&v_s[m * 256 + ((n0 + j4 * 4) ^ key)] =
          relu4(acc[i][j4 * 4 + 0], acc[i][j4 * 4 + 1], acc[i][j4 * 4 + 2], acc[i][j4 * 4 + 3]);
    }
  }
  __syncthreads();
  float acc2[8][8];
#pragma unroll
  for (int j4 = 0; j4 < 2; ++j4) {
    float4 b = *(const float4*)&b2[n0 + j4 * 4];
#pragma unroll
    for (int i = 0; i < 8; ++i) {
      acc2[i][j4 * 4 + 0] = b.x; acc2[i][j4 * 4 + 1] = b.y;
      acc2[i][j4 * 4 + 2] = b.z; acc2[i][j4 * 4 + 3] = b.w;
    }
  }
  tile_gemm<8, 8, 256, 256>(v_s, w2, acc2, m0, n0);
  // h2 -> u_s (plain layout), then segmented pool
#pragma unroll
  for (int i = 0; i < 8; ++i) {
    int m = m0 + i;
#pragma unroll
    for (int j4 = 0; j4 < 2; ++j4) {
      *(float4*)&u_s[m * 256 + n0 + j4 * 4] =
          relu4(acc2[i][j4 * 4 + 0], acc2[i][j4 * 4 + 1], acc2[i][j4 * 4 + 2], acc2[i][j4 * 4 + 3]);
    }
  }
  __syncthreads();
  float run = 0.f;
  int curg = -2;
  for (int m = 0; m < 64; ++m) {
    int g = batch_s[m];
    if (g != curg) {
      if (curg >= 0) atomicAdd(&pool[curg * 256 + tid], run);
      run = 0.f; curg = g;
    }
    if (g >= 0) run += u_s[m * 256 + tid];
  }
  if (curg >= 0) atomicAdd(&pool[curg * 256 + tid], run);
}

__global__ __launch_bounds__(256) void count_nodes(const int* __restrict__ batch,
                                                   float* __restrict__ counts) {
  int i = blockIdx.x * 256 + threadIdx.x;
  if (i < NN) atomicAdd(&counts[batch[i]], 1.0f);
}

// ---------------------------------------------------------------------------
// Readout: g = pool/cnt -> ReLU(128) -> ReLU(64) -> 3 heads
// ---------------------------------------------------------------------------
__global__ __launch_bounds__(128) void head_kernel(
    const float* __restrict__ pool, const float* __restrict__ counts,
    const float* __restrict__ l1w, const float* __restrict__ l1b,
    const float* __restrict__ l2w, const float* __restrict__ l2b,
    const float* __restrict__ hs_w, const float* __restrict__ hs_b,
    const float* __restrict__ hp_w, const float* __restrict__ hp_b,
    const float* __restrict__ hn_w, const float* __restrict__ hn_b,
    float* __restrict__ out) {
  const int g = blockIdx.x, tid = threadIdx.x;
  __shared__ float g_s[256], g1_s[128], g2_s[64];
  float cnt = fmaxf(counts[g], 1.0f);
  g_s[tid] = pool[g * 256 + tid] / cnt;
  g_s[tid + 128] = pool[g * 256 + tid + 128] / cnt;
  __syncthreads();
  float s = l1b[tid];
  for (int k = 0; k < 256; ++k) s = fmaf(g_s[k], l1w[k * 128 + tid], s);
  g1_s[tid] = fmaxf(s, 0.f);
  __syncthreads();
  if (tid < 64) {
    float s2 = l2b[tid];
    for (int k = 0; k < 128; ++k) s2 = fmaf(g1_s[k], l2w[k * 64 + tid], s2);
    g2_s[tid] = fmaxf(s2, 0.f);
  }
  __syncthreads();
  if (tid < 64) {
    float v = g2_s[tid];
    float a = v * hs_w[tid], b = v * hp_w[tid], c = v * hn_w[tid];
    for (int off = 32; off > 0; off >>= 1) {
      a += __shfl_down(a, off, 64);
      b += __shfl_down(b, off, 64);
      c += __shfl_down(c, off, 64);
    }
    if (tid == 0) {
      out[g]        = a + hs_b[0];
      out[64 + g]   = b + hp_b[0];
      out[128 + g]  = c + hn_b[0];
    }
  }
}

extern "C" void kernel_launch(void* const* d_in, const int* in_sizes, int n_in,
                              void* d_out, int out_size, void* d_ws, size_t ws_size,
                              hipStream_t stream) {
  (void)in_sizes; (void)n_in; (void)out_size; (void)ws_size;
  const float* x         = (const float*)d_in[0];
  const int*   eidx      = (const int*)d_in[1];
  const int*   batch     = (const int*)d_in[2];
  const float* edge_attr = (const float*)d_in[3];
  const float* ew1  = (const float*)d_in[4];
  const float* eb1  = (const float*)d_in[5];
  const float* ew2  = (const float*)d_in[6];
  const float* eb2  = (const float*)d_in[7];
  const float* le1w = (const float*)d_in[8];
  const float* le1b = (const float*)d_in[9];
  const float* le2w = (const float*)d_in[10];
  const float* le2b = (const float*)d_in[11];
  const float* n1w1 = (const float*)d_in[12];
  const float* n1b1 = (const float*)d_in[13];
  const float* n1w2 = (const float*)d_in[14];
  const float* n1b2 = (const float*)d_in[15];
  const float* n2w1 = (const float*)d_in[16];
  const float* n2b1 = (const float*)d_in[17];
  const float* n2w2 = (const float*)d_in[18];
  const float* n2b2 = (const float*)d_in[19];
  const float* l1w  = (const float*)d_in[20];
  const float* l1b  = (const float*)d_in[21];
  const float* l2w  = (const float*)d_in[22];
  const float* l2b  = (const float*)d_in[23];
  const float* hs_w = (const float*)d_in[24];
  const float* hs_b = (const float*)d_in[25];
  const float* hp_w = (const float*)d_in[26];
  const float* hp_b = (const float*)d_in[27];
  const float* hn_w = (const float*)d_in[28];
  const float* hn_b = (const float*)d_in[29];

  float* ws    = (float*)d_ws;
  float* W1c   = ws + OFF_W1C;
  float* b1c   = ws + OFF_B1C;
  float* W2c   = ws + OFF_W2C;
  float* b2c   = ws + OFF_B2C;
  float* aggr1 = ws + OFF_AGGR1;
  float* aggr2 = ws + OFF_AGGR2;
  float* h1    = ws + OFF_H1;
  float* pool  = ws + OFF_POOL;
  float* cnts  = ws + OFF_CNT;
  int*   cursor= (int*)ws + OFF_CURSOR;
  int*   rowptr= (int*)ws + OFF_ROWPTR;
  int*   perm  = (int*)ws + OFF_PERM;
  float* out   = (float*)d_out;

  hipMemsetAsync(aggr1, 0, (size_t)NN * 64 * 4, stream);
  hipMemsetAsync(aggr2, 0, (size_t)NN * 256 * 4, stream);
  hipMemsetAsync(pool, 0, (size_t)NG * 256 * 4, stream);
  hipMemsetAsync(cnts, 0, (size_t)NG * 4, stream);
  hipMemsetAsync(cursor, 0, (size_t)NN * 4, stream);

  prep_weights<<<322, 256, 0, stream>>>(ew2, eb2, le1w, le1b, le2w, le2b, W1c, b1c, W2c, b2c);
  count_nodes<<<(NN + 255) / 256, 256, 0, stream>>>(batch, cnts);

  // CSR build (dst-sorted edge permutation, deterministic)
  count_deg<<<(NE + 255) / 256, 256, 0, stream>>>(eidx, cursor);
  scan_rowptr<<<1, 256, 0, stream>>>(cursor, rowptr);
  scatter_perm<<<(NE + 255) / 256, 256, 0, stream>>>(eidx, cursor, perm);
  sort_segments<<<(NN + 255) / 256, 256, 0, stream>>>(rowptr, perm);

  edge_conv<64><<<NE / 64, 256, 0, stream>>>(edge_attr, eidx, perm, ew1, eb1, W1c, b1c, x, aggr1);
  node_mlp1<<<(NN + 63) / 64, 256, 0, stream>>>(x, aggr1, n1w1, n1b1, n1w2, n1b2, h1);
  edge_conv<256><<<NE / 64, 256, 0, stream>>>(edge_attr, eidx, perm, ew1, eb1, W2c, b2c, h1, aggr2);
  node_mlp2<<<(NN + 63) / 64, 256, 0, stream>>>(h1, aggr2, n2w1, n2b1, n2w2, n2b2, batch, pool);
  head_kernel<<<NG, 128, 0, stream>>>(pool, cnts, l1w, l1b, l2w, l2b,
                                      hs_w, hs_b, hp_w, hp_b, hn_w, hn_b, out);
}

// Round 3
// 874.823 us; speedup vs baseline: 3.4824x; 1.4823x over previous
//
#include <hip/hip_runtime.h>

constexpr int NN  = 20000;   // nodes
constexpr int NE  = 320000;  // edges
constexpr int NG  = 64;      // graphs

typedef _Float16 f16x8v __attribute__((ext_vector_type(8)));
typedef float    f32x4v __attribute__((ext_vector_type(4)));

// workspace layout (in 4-byte units)
constexpr size_t OFF_W1C    = 0;                          // 256*64
constexpr size_t OFF_B1C    = 16384;                      // 64
constexpr size_t OFF_W2C    = 16448;                      // 256*256
constexpr size_t OFF_B2C    = 81984;                      // 256
constexpr size_t OFF_AGGR1  = 82240;                      // 20000*64
constexpr size_t OFF_AGGR2  = 1362240;                    // 20000*256
constexpr size_t OFF_H1     = 6482240;                    // 20000*256
constexpr size_t OFF_POOL   = 11602240;                   // 64*256
constexpr size_t OFF_CNT    = 11618624;                   // 64
constexpr size_t OFF_CURSOR = 11618688;                   // 20000 ints (deg, then cursor)
constexpr size_t OFF_ROWPTR = 11638688;                   // 20001 ints
constexpr size_t OFF_PERM   = 11658689;                   // 320000 ints
constexpr size_t OFF_BP1    = 11978752;                   // f16 frag-packed W1c: 16384 halves
constexpr size_t OFF_BP2    = 11986944;                   // f16 frag-packed W2c: 65536 halves

__device__ __forceinline__ float4 relu4(float a, float b, float c, float d) {
  float4 r; r.x = fmaxf(a, 0.f); r.y = fmaxf(b, 0.f); r.z = fmaxf(c, 0.f); r.w = fmaxf(d, 0.f);
  return r;
}

// ---------------------------------------------------------------------------
// fp32 register-tiled GEMM (kept for node MLPs)
// ---------------------------------------------------------------------------
template <int TM, int TN, int K, int NOUT>
__device__ __forceinline__ void tile_gemm(const float* __restrict__ As,
                                          const float* __restrict__ B,
                                          float (&acc)[TM][TN], int m0, int n0) {
  const float4* A4 = (const float4*)As;
  constexpr int KW = K / 4;
  for (int k = 0; k < K; k += 4) {
    float4 a[TM];
#pragma unroll
    for (int i = 0; i < TM; ++i) {
      int m = m0 + i;
      a[i] = A4[m * KW + ((k >> 2) ^ ((m >> 2) & 7))];
    }
#pragma unroll
    for (int kk = 0; kk < 4; ++kk) {
      float bv[TN];
#pragma unroll
      for (int j4 = 0; j4 < TN / 4; ++j4) {
        float4 w = *(const float4*)&B[(size_t)(k + kk) * NOUT + n0 + j4 * 4];
        bv[j4 * 4 + 0] = w.x; bv[j4 * 4 + 1] = w.y; bv[j4 * 4 + 2] = w.z; bv[j4 * 4 + 3] = w.w;
      }
#pragma unroll
      for (int i = 0; i < TM; ++i) {
        float av = (kk == 0) ? a[i].x : (kk == 1) ? a[i].y : (kk == 2) ? a[i].z : a[i].w;
#pragma unroll
        for (int j = 0; j < TN; ++j) acc[i][j] = fmaf(av, bv[j], acc[i][j]);
      }
    }
  }
}

// ---------------------------------------------------------------------------
// Fold edge-MLP second layer into the GINE edge projections (fp32)
// ---------------------------------------------------------------------------
__global__ __launch_bounds__(256) void prep_weights(
    const float* __restrict__ ew2, const float* __restrict__ eb2,
    const float* __restrict__ le1_w, const float* __restrict__ le1_b,
    const float* __restrict__ le2_w, const float* __restrict__ le2_b,
    float* __restrict__ W1c, float* __restrict__ b1c,
    float* __restrict__ W2c, float* __restrict__ b2c) {
  int idx = blockIdx.x * 256 + threadIdx.x;
  if (idx < 16384) {
    int i = idx >> 6, j = idx & 63;
    float s = 0.f;
    for (int k = 0; k < 256; ++k) s = fmaf(ew2[i * 256 + k], le1_w[k * 64 + j], s);
    W1c[idx] = s;
  } else if (idx < 16384 + 65536) {
    int t = idx - 16384;
    int i = t >> 8, j = t & 255;
    float s = 0.f;
    for (int k = 0; k < 256; ++k) s = fmaf(ew2[i * 256 + k], le2_w[k * 256 + j], s);
    W2c[t] = s;
  } else if (idx < 16384 + 65536 + 64) {
    int j = idx - 16384 - 65536;
    float s = le1_b[j];
    for (int k = 0; k < 256; ++k) s = fmaf(eb2[k], le1_w[k * 64 + j], s);
    b1c[j] = s;
  } else if (idx < 16384 + 65536 + 64 + 256) {
    int j = idx - 16384 - 65536 - 64;
    float s = le2_b[j];
    for (int k = 0; k < 256; ++k) s = fmaf(eb2[k], le2_w[k * 256 + j], s);
    b2c[j] = s;
  }
}

// ---------------------------------------------------------------------------
// Pack Wc (K=256 x nout fp32) into MFMA B-fragment-ordered f16:
// Bp[((ng*8+s)*64+lane)*8 + e] = Wc[32s + 8*(lane>>4) + e][16*ng + (lane&15)]
// Same k-map (8g+e) is used when reading A-frags -> layout-consistent matmul.
// ---------------------------------------------------------------------------
__global__ __launch_bounds__(256) void pack_frags(const float* __restrict__ Wc,
                                                  _Float16* __restrict__ Bp,
                                                  int ntiles, int nout) {
  int idx = blockIdx.x * 256 + threadIdx.x;
  if (idx >= ntiles * 8 * 64) return;
  int lane = idx & 63;
  int s = (idx >> 6) & 7;
  int ng = idx >> 9;
  int kbase = 32 * s + 8 * (lane >> 4);
  int col = 16 * ng + (lane & 15);
  f16x8v v;
#pragma unroll
  for (int e = 0; e < 8; ++e) v[e] = (_Float16)Wc[(size_t)(kbase + e) * nout + col];
  *(f16x8v*)&Bp[(size_t)idx * 8] = v;
}

// ---------------------------------------------------------------------------
// CSR build: count degrees, scan, scatter slots, per-node sort (determinism)
// ---------------------------------------------------------------------------
__global__ __launch_bounds__(256) void count_deg(const int* __restrict__ eidx,
                                                 int* __restrict__ deg) {
  int e = blockIdx.x * 256 + threadIdx.x;
  if (e < NE) atomicAdd(&deg[eidx[NE + e]], 1);
}

__global__ __launch_bounds__(256) void scan_rowptr(int* __restrict__ degcur,
                                                   int* __restrict__ rowptr) {
  __shared__ int wsum[4];
  const int tid = threadIdx.x, lane = tid & 63, w = tid >> 6;
  int base = 0;
  for (int c0 = 0; c0 < NN; c0 += 256) {
    int i = c0 + tid;
    int v = (i < NN) ? degcur[i] : 0;
    int x = v;
#pragma unroll
    for (int off = 1; off < 64; off <<= 1) {
      int y = __shfl_up(x, off, 64);
      if (lane >= off) x += y;
    }
    if (lane == 63) wsum[w] = x;
    __syncthreads();
    int woff = 0;
    for (int k = 0; k < w; ++k) woff += wsum[k];
    int tot = wsum[0] + wsum[1] + wsum[2] + wsum[3];
    if (i < NN) {
      int ex = base + woff + x - v;
      rowptr[i] = ex;
      degcur[i] = ex;
    }
    base += tot;
    __syncthreads();
  }
  if (tid == 0) rowptr[NN] = base;
}

__global__ __launch_bounds__(256) void scatter_perm(const int* __restrict__ eidx,
                                                    int* __restrict__ cursor,
                                                    int* __restrict__ perm) {
  int e = blockIdx.x * 256 + threadIdx.x;
  if (e < NE) {
    int d = eidx[NE + e];
    int slot = atomicAdd(&cursor[d], 1);
    perm[slot] = e;
  }
}

__global__ __launch_bounds__(256) void sort_segments(const int* __restrict__ rowptr,
                                                     int* __restrict__ perm) {
  int n = blockIdx.x * 256 + threadIdx.x;
  if (n < NN) {
    int s = rowptr[n], t = rowptr[n + 1];
    for (int i = s + 1; i < t; ++i) {
      int key = perm[i], j = i - 1;
      while (j >= s && perm[j] > key) { perm[j + 1] = perm[j]; --j; }
      perm[j + 1] = key;
    }
  }
}

// ---------------------------------------------------------------------------
// MFMA edge conv over dst-sorted edges. Per 64-edge block:
//   t = ReLU(ea@ew1+eb1) fp32 -> f16, XOR-swizzled LDS  [64 x 256]
//   p = t @ Wc + bc  via mfma_f32_16x16x32_f16 (A from LDS, B frag-packed)
//   msg = ReLU(gat[src] + p); per-lane run-merged atomics over sorted dst
// Wave w owns cols [64w, 64w+64); lane holds rows {16m + 4(lane>>4) + r}.
// ---------------------------------------------------------------------------
template <int NOUT>
__global__ __launch_bounds__(256, 4) void edge_conv_mfma(
    const float* __restrict__ edge_attr, const int* __restrict__ eidx,
    const int* __restrict__ perm,
    const float* __restrict__ ew1, const float* __restrict__ eb1,
    const _Float16* __restrict__ Bp, const float* __restrict__ bc,
    const float* __restrict__ gat, float* __restrict__ aggr) {
  constexpr int NTW = NOUT / 64;  // n-tiles per wave (1 or 4)
  __shared__ float ea_s[64 * 16];
  __shared__ _Float16 t_h[64 * 256];
  __shared__ int perm_s[64], src_s[64], dst_s[64];
  const int tid = threadIdx.x;
  const int e0 = blockIdx.x * 64;
  const int lane = tid & 63, w = tid >> 6;
  const int q = lane >> 4, li = lane & 15;

  if (tid < 64) {
    int p = perm[e0 + tid];
    perm_s[tid] = p;
    src_s[tid] = eidx[p];
    dst_s[tid] = eidx[NE + p];
  }
  __syncthreads();
  {
    int r = tid >> 2, c4 = tid & 3;
    *(float4*)&ea_s[r * 16 + c4 * 4] =
        *(const float4*)&edge_attr[(size_t)perm_s[r] * 16 + c4 * 4];
  }
  __syncthreads();

  // t-phase: column tid for all 64 edges, fp32 math, f16 swizzled store
  float wcol[16];
#pragma unroll
  for (int k = 0; k < 16; ++k) wcol[k] = ew1[k * 256 + tid];
  const float bias = eb1[tid];
  const float4* ea4 = (const float4*)ea_s;
  const int gw = tid >> 3, el = tid & 7;
  for (int m = 0; m < 64; ++m) {
    float4 a0 = ea4[m * 4 + 0], a1 = ea4[m * 4 + 1], a2 = ea4[m * 4 + 2], a3 = ea4[m * 4 + 3];
    float s = bias;
    s = fmaf(a0.x, wcol[0], s);  s = fmaf(a0.y, wcol[1], s);
    s = fmaf(a0.z, wcol[2], s);  s = fmaf(a0.w, wcol[3], s);
    s = fmaf(a1.x, wcol[4], s);  s = fmaf(a1.y, wcol[5], s);
    s = fmaf(a1.z, wcol[6], s);  s = fmaf(a1.w, wcol[7], s);
    s = fmaf(a2.x, wcol[8], s);  s = fmaf(a2.y, wcol[9], s);
    s = fmaf(a2.z, wcol[10], s); s = fmaf(a2.w, wcol[11], s);
    s = fmaf(a3.x, wcol[12], s); s = fmaf(a3.y, wcol[13], s);
    s = fmaf(a3.z, wcol[14], s); s = fmaf(a3.w, wcol[15], s);
    t_h[m * 256 + ((gw ^ (m & 7)) << 3) + el] = (_Float16)fmaxf(s, 0.f);
  }

  // bias-init accumulators (C/D layout: col=lane&15, row=4*(lane>>4)+reg)
  f32x4v acc[4][NTW];
#pragma unroll
  for (int nl = 0; nl < NTW; ++nl) {
    float bv = bc[(w * NTW + nl) * 16 + li];
#pragma unroll
    for (int m = 0; m < 4; ++m) { f32x4v t = {bv, bv, bv, bv}; acc[m][nl] = t; }
  }
  __syncthreads();

  // main GEMM: 8 k-steps of 32
  for (int s8 = 0; s8 < 8; ++s8) {
    f16x8v af[4];
#pragma unroll
    for (int m = 0; m < 4; ++m) {
      int r = 16 * m + li;
      int gl = 4 * s8 + q;
      af[m] = *(const f16x8v*)&t_h[r * 256 + ((gl ^ (r & 7)) << 3)];
    }
#pragma unroll
    for (int nl = 0; nl < NTW; ++nl) {
      int ng = w * NTW + nl;
      f16x8v bf = *(const f16x8v*)&Bp[(size_t)((ng * 8 + s8) * 64 + lane) * 8];
#pragma unroll
      for (int m = 0; m < 4; ++m)
        acc[m][nl] = __builtin_amdgcn_mfma_f32_16x16x32_f16(af[m], bf, acc[m][nl], 0, 0, 0);
    }
  }

  // epilogue: gather + ReLU + per-lane run-merged scatter (dst sorted)
#pragma unroll
  for (int nl = 0; nl < NTW; ++nl) {
    const int col = (w * NTW + nl) * 16 + li;
    float run = 0.f;
    int cur = dst_s[4 * q];
#pragma unroll
    for (int m = 0; m < 4; ++m) {
#pragma unroll
      for (int r = 0; r < 4; ++r) {
        int row = 16 * m + 4 * q + r;
        int d = dst_s[row];
        if (d != cur) {
          atomicAdd(&aggr[(size_t)cur * NOUT + col], run);
          run = 0.f; cur = d;
        }
        float xv = gat[(size_t)src_s[row] * NOUT + col];
        run += fmaxf(xv + acc[m][nl][r], 0.f);
      }
    }
    atomicAdd(&aggr[(size_t)cur * NOUT + col], run);
  }
}

// ---------------------------------------------------------------------------
// Node MLP 1: h1 = ReLU(ReLU((x + aggr1) @ w1 + b1) @ w2 + b2)
// ---------------------------------------------------------------------------
__global__ __launch_bounds__(256, 2) void node_mlp1(
    const float* __restrict__ x, const float* __restrict__ aggr1,
    const float* __restrict__ w1, const float* __restrict__ b1,
    const float* __restrict__ w2, const float* __restrict__ b2,
    float* __restrict__ h1) {
  __shared__ float u_s[64 * 64];
  __shared__ float v_s[64 * 256];
  const int tid = threadIdx.x;
  const int i0 = blockIdx.x * 64;
#pragma unroll
  for (int r = 0; r < 4; ++r) {
    int idx4 = tid + r * 256;
    int m = idx4 >> 4, k = (idx4 & 15) * 4;
    int node = i0 + m;
    float4 v = make_float4(0.f, 0.f, 0.f, 0.f);
    if (node < NN) {
      float4 a = *(const float4*)&x[(size_t)node * 64 + k];
      float4 b = *(const float4*)&aggr1[(size_t)node * 64 + k];
      v = make_float4(a.x + b.x, a.y + b.y, a.z + b.z, a.w + b.w);
    }
    *(float4*)&u_s[m * 64 + (k ^ (((m >> 2) & 7) << 2))] = v;
  }
  __syncthreads();
  const int eg = tid / 32, cg = tid % 32;
  const int m0 = eg * 8, n0 = cg * 8;
  float acc[8][8];
#pragma unroll
  for (int j4 = 0; j4 < 2; ++j4) {
    float4 b = *(const float4*)&b1[n0 + j4 * 4];
#pragma unroll
    for (int i = 0; i < 8; ++i) {
      acc[i][j4 * 4 + 0] = b.x; acc[i][j4 * 4 + 1] = b.y;
      acc[i][j4 * 4 + 2] = b.z; acc[i][j4 * 4 + 3] = b.w;
    }
  }
  tile_gemm<8, 8, 64, 256>(u_s, w1, acc, m0, n0);
#pragma unroll
  for (int i = 0; i < 8; ++i) {
    int m = m0 + i, key = ((m >> 2) & 7) << 2;
#pragma unroll
    for (int j4 = 0; j4 < 2; ++j4) {
      *(float4*)&v_s[m * 256 + ((n0 + j4 * 4) ^ key)] =
          relu4(acc[i][j4 * 4 + 0], acc[i][j4 * 4 + 1], acc[i][j4 * 4 + 2], acc[i][j4 * 4 + 3]);
    }
  }
  __syncthreads();
  float acc2[8][8];
#pragma unroll
  for (int j4 = 0; j4 < 2; ++j4) {
    float4 b = *(const float4*)&b2[n0 + j4 * 4];
#pragma unroll
    for (int i = 0; i < 8; ++i) {
      acc2[i][j4 * 4 + 0] = b.x; acc2[i][j4 * 4 + 1] = b.y;
      acc2[i][j4 * 4 + 2] = b.z; acc2[i][j4 * 4 + 3] = b.w;
    }
  }
  tile_gemm<8, 8, 256, 256>(v_s, w2, acc2, m0, n0);
#pragma unroll
  for (int i = 0; i < 8; ++i) {
    int node = i0 + m0 + i;
    if (node < NN) {
#pragma unroll
      for (int j4 = 0; j4 < 2; ++j4) {
        *(float4*)&h1[(size_t)node * 256 + n0 + j4 * 4] =
            relu4(acc2[i][j4 * 4 + 0], acc2[i][j4 * 4 + 1], acc2[i][j4 * 4 + 2], acc2[i][j4 * 4 + 3]);
      }
    }
  }
}

// ---------------------------------------------------------------------------
// Node MLP 2 + fused mean-pool numerator
// ---------------------------------------------------------------------------
__global__ __launch_bounds__(256) void node_mlp2(
    const float* __restrict__ h1, const float* __restrict__ aggr2,
    const float* __restrict__ w1, const float* __restrict__ b1,
    const float* __restrict__ w2, const float* __restrict__ b2,
    const int* __restrict__ batch, float* __restrict__ pool) {
  __shared__ float u_s[64 * 256];
  __shared__ float v_s[64 * 256];
  __shared__ int batch_s[64];
  const int tid = threadIdx.x;
  const int i0 = blockIdx.x * 64;
  if (tid < 64) batch_s[tid] = (i0 + tid < NN) ? batch[i0 + tid] : -1;
#pragma unroll 4
  for (int r = 0; r < 16; ++r) {
    int idx4 = tid + r * 256;
    int m = idx4 >> 6, k = (idx4 & 63) * 4;
    int node = i0 + m;
    float4 v = make_float4(0.f, 0.f, 0.f, 0.f);
    if (node < NN) {
      float4 a = *(const float4*)&h1[(size_t)node * 256 + k];
      float4 b = *(const float4*)&aggr2[(size_t)node * 256 + k];
      v = make_float4(a.x + b.x, a.y + b.y, a.z + b.z, a.w + b.w);
    }
    *(float4*)&u_s[m * 256 + (k ^ (((m >> 2) & 7) << 2))] = v;
  }
  __syncthreads();
  const int eg = tid / 32, cg = tid % 32;
  const int m0 = eg * 8, n0 = cg * 8;
  float acc[8][8];
#pragma unroll
  for (int j4 = 0; j4 < 2; ++j4) {
    float4 b = *(const float4*)&b1[n0 + j4 * 4];
#pragma unroll
    for (int i = 0; i < 8; ++i) {
      acc[i][j4 * 4 + 0] = b.x; acc[i][j4 * 4 + 1] = b.y;
      acc[i][j4 * 4 + 2] = b.z; acc[i][j4 * 4 + 3] = b.w;
    }
  }
  tile_gemm<8, 8, 256, 256>(u_s, w1, acc, m0, n0);
#pragma unroll
  for (int i = 0; i < 8; ++i) {
    int m = m0 + i, key = ((m >> 2) & 7) << 2;
#pragma unroll
    for (int j4 = 0; j4 < 2; ++j4) {
      *(float4*)&v_s[m * 256 + ((n0 + j4 * 4) ^ key)] =
          relu4(acc[i][j4 * 4 + 0], acc[i][j4 * 4 + 1], acc[i][j4 * 4 + 2], acc[i][j4 * 4 + 3]);
    }
  }
  __syncthreads();
  float acc2[8][8];
#pragma unroll
  for (int j4 = 0; j4 < 2; ++j4) {
    float4 b = *(const float4*)&b2[n0 + j4 * 4];
#pragma unroll
    for (int i = 0; i < 8; ++i) {
      acc2[i][j4 * 4 + 0] = b.x; acc2[i][j4 * 4 + 1] = b.y;
      acc2[i][j4 * 4 + 2] = b.z; acc2[i][j4 * 4 + 3] = b.w;
    }
  }
  tile_gemm<8, 8, 256, 256>(v_s, w2, acc2, m0, n0);
#pragma unroll
  for (int i = 0; i < 8; ++i) {
    int m = m0 + i;
#pragma unroll
    for (int j4 = 0; j4 < 2; ++j4) {
      *(float4*)&u_s[m * 256 + n0 + j4 * 4] =
          relu4(acc2[i][j4 * 4 + 0], acc2[i][j4 * 4 + 1], acc2[i][j4 * 4 + 2], acc2[i][j4 * 4 + 3]);
    }
  }
  __syncthreads();
  float run = 0.f;
  int curg = -2;
  for (int m = 0; m < 64; ++m) {
    int g = batch_s[m];
    if (g != curg) {
      if (curg >= 0) atomicAdd(&pool[curg * 256 + tid], run);
      run = 0.f; curg = g;
    }
    if (g >= 0) run += u_s[m * 256 + tid];
  }
  if (curg >= 0) atomicAdd(&pool[curg * 256 + tid], run);
}

__global__ __launch_bounds__(256) void count_nodes(const int* __restrict__ batch,
                                                   float* __restrict__ counts) {
  int i = blockIdx.x * 256 + threadIdx.x;
  if (i < NN) atomicAdd(&counts[batch[i]], 1.0f);
}

// ---------------------------------------------------------------------------
// Readout: g = pool/cnt -> ReLU(128) -> ReLU(64) -> 3 heads
// ---------------------------------------------------------------------------
__global__ __launch_bounds__(128) void head_kernel(
    const float* __restrict__ pool, const float* __restrict__ counts,
    const float* __restrict__ l1w, const float* __restrict__ l1b,
    const float* __restrict__ l2w, const float* __restrict__ l2b,
    const float* __restrict__ hs_w, const float* __restrict__ hs_b,
    const float* __restrict__ hp_w, const float* __restrict__ hp_b,
    const float* __restrict__ hn_w, const float* __restrict__ hn_b,
    float* __restrict__ out) {
  const int g = blockIdx.x, tid = threadIdx.x;
  __shared__ float g_s[256], g1_s[128], g2_s[64];
  float cnt = fmaxf(counts[g], 1.0f);
  g_s[tid] = pool[g * 256 + tid] / cnt;
  g_s[tid + 128] = pool[g * 256 + tid + 128] / cnt;
  __syncthreads();
  float s = l1b[tid];
  for (int k = 0; k < 256; ++k) s = fmaf(g_s[k], l1w[k * 128 + tid], s);
  g1_s[tid] = fmaxf(s, 0.f);
  __syncthreads();
  if (tid < 64) {
    float s2 = l2b[tid];
    for (int k = 0; k < 128; ++k) s2 = fmaf(g1_s[k], l2w[k * 64 + tid], s2);
    g2_s[tid] = fmaxf(s2, 0.f);
  }
  __syncthreads();
  if (tid < 64) {
    float v = g2_s[tid];
    float a = v * hs_w[tid], b = v * hp_w[tid], c = v * hn_w[tid];
    for (int off = 32; off > 0; off >>= 1) {
      a += __shfl_down(a, off, 64);
      b += __shfl_down(b, off, 64);
      c += __shfl_down(c, off, 64);
    }
    if (tid == 0) {
      out[g]        = a + hs_b[0];
      out[64 + g]   = b + hp_b[0];
      out[128 + g]  = c + hn_b[0];
    }
  }
}

extern "C" void kernel_launch(void* const* d_in, const int* in_sizes, int n_in,
                              void* d_out, int out_size, void* d_ws, size_t ws_size,
                              hipStream_t stream) {
  (void)in_sizes; (void)n_in; (void)out_size; (void)ws_size;
  const float* x         = (const float*)d_in[0];
  const int*   eidx      = (const int*)d_in[1];
  const int*   batch     = (const int*)d_in[2];
  const float* edge_attr = (const float*)d_in[3];
  const float* ew1  = (const float*)d_in[4];
  const float* eb1  = (const float*)d_in[5];
  const float* ew2  = (const float*)d_in[6];
  const float* eb2  = (const float*)d_in[7];
  const float* le1w = (const float*)d_in[8];
  const float* le1b = (const float*)d_in[9];
  const float* le2w = (const float*)d_in[10];
  const float* le2b = (const float*)d_in[11];
  const float* n1w1 = (const float*)d_in[12];
  const float* n1b1 = (const float*)d_in[13];
  const float* n1w2 = (const float*)d_in[14];
  const float* n1b2 = (const float*)d_in[15];
  const float* n2w1 = (const float*)d_in[16];
  const float* n2b1 = (const float*)d_in[17];
  const float* n2w2 = (const float*)d_in[18];
  const float* n2b2 = (const float*)d_in[19];
  const float* l1w  = (const float*)d_in[20];
  const float* l1b  = (const float*)d_in[21];
  const float* l2w  = (const float*)d_in[22];
  const float* l2b  = (const float*)d_in[23];
  const float* hs_w = (const float*)d_in[24];
  const float* hs_b = (const float*)d_in[25];
  const float* hp_w = (const float*)d_in[26];
  const float* hp_b = (const float*)d_in[27];
  const float* hn_w = (const float*)d_in[28];
  const float* hn_b = (const float*)d_in[29];

  float* ws    = (float*)d_ws;
  float* W1c   = ws + OFF_W1C;
  float* b1c   = ws + OFF_B1C;
  float* W2c   = ws + OFF_W2C;
  float* b2c   = ws + OFF_B2C;
  float* aggr1 = ws + OFF_AGGR1;
  float* aggr2 = ws + OFF_AGGR2;
  float* h1    = ws + OFF_H1;
  float* pool  = ws + OFF_POOL;
  float* cnts  = ws + OFF_CNT;
  int*   cursor= (int*)ws + OFF_CURSOR;
  int*   rowptr= (int*)ws + OFF_ROWPTR;
  int*   perm  = (int*)ws + OFF_PERM;
  _Float16* Bp1 = (_Float16*)(ws + OFF_BP1);
  _Float16* Bp2 = (_Float16*)(ws + OFF_BP2);
  float* out   = (float*)d_out;

  hipMemsetAsync(aggr1, 0, (size_t)NN * 64 * 4, stream);
  hipMemsetAsync(aggr2, 0, (size_t)NN * 256 * 4, stream);
  hipMemsetAsync(pool, 0, (size_t)NG * 256 * 4, stream);
  hipMemsetAsync(cnts, 0, (size_t)NG * 4, stream);
  hipMemsetAsync(cursor, 0, (size_t)NN * 4, stream);

  prep_weights<<<322, 256, 0, stream>>>(ew2, eb2, le1w, le1b, le2w, le2b, W1c, b1c, W2c, b2c);
  pack_frags<<<8, 256, 0, stream>>>(W1c, Bp1, 4, 64);
  pack_frags<<<32, 256, 0, stream>>>(W2c, Bp2, 16, 256);
  count_nodes<<<(NN + 255) / 256, 256, 0, stream>>>(batch, cnts);

  count_deg<<<(NE + 255) / 256, 256, 0, stream>>>(eidx, cursor);
  scan_rowptr<<<1, 256, 0, stream>>>(cursor, rowptr);
  scatter_perm<<<(NE + 255) / 256, 256, 0, stream>>>(eidx, cursor, perm);
  sort_segments<<<(NN + 255) / 256, 256, 0, stream>>>(rowptr, perm);

  edge_conv_mfma<64><<<NE / 64, 256, 0, stream>>>(edge_attr, eidx, perm, ew1, eb1,
                                                  Bp1, b1c, x, aggr1);
  node_mlp1<<<(NN + 63) / 64, 256, 0, stream>>>(x, aggr1, n1w1, n1b1, n1w2, n1b2, h1);
  edge_conv_mfma<256><<<NE / 64, 256, 0, stream>>>(edge_attr, eidx, perm, ew1, eb1,
                                                   Bp2, b2c, h1, aggr2);
  node_mlp2<<<(NN + 63) / 64, 256, 0, stream>>>(h1, aggr2, n2w1, n2b1, n2w2, n2b2, batch, pool);
  head_kernel<<<NG, 128, 0, stream>>>(pool, cnts, l1w, l1b, l2w, l2b,
                                      hs_w, hs_b, hp_w, hp_b, hn_w, hn_b, out);
}

// Round 4
// 689.185 us; speedup vs baseline: 4.4204x; 1.2694x over previous
//
#include <hip/hip_runtime.h>

constexpr int NN  = 20000;   // nodes
constexpr int NE  = 320000;  // edges
constexpr int NG  = 64;      // graphs

typedef _Float16 f16x8v __attribute__((ext_vector_type(8)));
typedef _Float16 f16x4v __attribute__((ext_vector_type(4)));
typedef float    f32x4v __attribute__((ext_vector_type(4)));

// workspace layout (in 4-byte units)
constexpr size_t OFF_W1C    = 0;                          // 256*64
constexpr size_t OFF_B1C    = 16384;                      // 64
constexpr size_t OFF_W2C    = 16448;                      // 256*256
constexpr size_t OFF_B2C    = 81984;                      // 256
constexpr size_t OFF_AGGR1  = 82240;                      // 20000*64 fp32
constexpr size_t OFF_AGGR2  = 1362240;                    // 20000*256 fp32 (xh aliased here pre-conv2)
constexpr size_t OFF_H1H    = 6482240;                    // 20000*256 f16 (2.56M floats)
constexpr size_t OFF_POOL   = 11602240;                   // 64*256
constexpr size_t OFF_CNT    = 11618624;                   // 64
constexpr size_t OFF_CURSOR = 11618688;                   // 20000 ints
constexpr size_t OFF_ROWPTR = 11638688;                   // 20001 ints
constexpr size_t OFF_PERM   = 11658689;                   // 320000 ints
constexpr size_t OFF_BP1    = 11978752;                   // f16 frag-packed W1c
constexpr size_t OFF_BP2    = 11986944;                   // f16 frag-packed W2c

__device__ __forceinline__ float4 relu4(float a, float b, float c, float d) {
  float4 r; r.x = fmaxf(a, 0.f); r.y = fmaxf(b, 0.f); r.z = fmaxf(c, 0.f); r.w = fmaxf(d, 0.f);
  return r;
}

// fp32 register-tiled GEMM (node MLPs)
template <int TM, int TN, int K, int NOUT>
__device__ __forceinline__ void tile_gemm(const float* __restrict__ As,
                                          const float* __restrict__ B,
                                          float (&acc)[TM][TN], int m0, int n0) {
  const float4* A4 = (const float4*)As;
  constexpr int KW = K / 4;
  for (int k = 0; k < K; k += 4) {
    float4 a[TM];
#pragma unroll
    for (int i = 0; i < TM; ++i) {
      int m = m0 + i;
      a[i] = A4[m * KW + ((k >> 2) ^ ((m >> 2) & 7))];
    }
#pragma unroll
    for (int kk = 0; kk < 4; ++kk) {
      float bv[TN];
#pragma unroll
      for (int j4 = 0; j4 < TN / 4; ++j4) {
        float4 w = *(const float4*)&B[(size_t)(k + kk) * NOUT + n0 + j4 * 4];
        bv[j4 * 4 + 0] = w.x; bv[j4 * 4 + 1] = w.y; bv[j4 * 4 + 2] = w.z; bv[j4 * 4 + 3] = w.w;
      }
#pragma unroll
      for (int i = 0; i < TM; ++i) {
        float av = (kk == 0) ? a[i].x : (kk == 1) ? a[i].y : (kk == 2) ? a[i].z : a[i].w;
#pragma unroll
        for (int j = 0; j < TN; ++j) acc[i][j] = fmaf(av, bv[j], acc[i][j]);
      }
    }
  }
}

__global__ __launch_bounds__(256) void prep_weights(
    const float* __restrict__ ew2, const float* __restrict__ eb2,
    const float* __restrict__ le1_w, const float* __restrict__ le1_b,
    const float* __restrict__ le2_w, const float* __restrict__ le2_b,
    float* __restrict__ W1c, float* __restrict__ b1c,
    float* __restrict__ W2c, float* __restrict__ b2c) {
  int idx = blockIdx.x * 256 + threadIdx.x;
  if (idx < 16384) {
    int i = idx >> 6, j = idx & 63;
    float s = 0.f;
    for (int k = 0; k < 256; ++k) s = fmaf(ew2[i * 256 + k], le1_w[k * 64 + j], s);
    W1c[idx] = s;
  } else if (idx < 16384 + 65536) {
    int t = idx - 16384;
    int i = t >> 8, j = t & 255;
    float s = 0.f;
    for (int k = 0; k < 256; ++k) s = fmaf(ew2[i * 256 + k], le2_w[k * 256 + j], s);
    W2c[t] = s;
  } else if (idx < 16384 + 65536 + 64) {
    int j = idx - 16384 - 65536;
    float s = le1_b[j];
    for (int k = 0; k < 256; ++k) s = fmaf(eb2[k], le1_w[k * 64 + j], s);
    b1c[j] = s;
  } else if (idx < 16384 + 65536 + 64 + 256) {
    int j = idx - 16384 - 65536 - 64;
    float s = le2_b[j];
    for (int k = 0; k < 256; ++k) s = fmaf(eb2[k], le2_w[k * 256 + j], s);
    b2c[j] = s;
  }
}

// Pack Wc (256 x nout fp32) into MFMA B-fragment order (k-map 8q+e)
__global__ __launch_bounds__(256) void pack_frags(const float* __restrict__ Wc,
                                                  _Float16* __restrict__ Bp,
                                                  int ntiles, int nout) {
  int idx = blockIdx.x * 256 + threadIdx.x;
  if (idx >= ntiles * 8 * 64) return;
  int lane = idx & 63;
  int s = (idx >> 6) & 7;
  int ng = idx >> 9;
  int kbase = 32 * s + 8 * (lane >> 4);
  int col = 16 * ng + (lane & 15);
  f16x8v v;
#pragma unroll
  for (int e = 0; e < 8; ++e) v[e] = (_Float16)Wc[(size_t)(kbase + e) * nout + col];
  *(f16x8v*)&Bp[(size_t)idx * 8] = v;
}

__global__ __launch_bounds__(256) void cast_xh(const float* __restrict__ x,
                                               _Float16* __restrict__ xh) {
  int idx = blockIdx.x * 256 + threadIdx.x;   // 8 elems each
  if (idx * 8 < NN * 64) {
    float4 a = *(const float4*)&x[idx * 8];
    float4 b = *(const float4*)&x[idx * 8 + 4];
    f16x8v v;
    v[0] = (_Float16)a.x; v[1] = (_Float16)a.y; v[2] = (_Float16)a.z; v[3] = (_Float16)a.w;
    v[4] = (_Float16)b.x; v[5] = (_Float16)b.y; v[6] = (_Float16)b.z; v[7] = (_Float16)b.w;
    *(f16x8v*)&xh[idx * 8] = v;
  }
}

// ----------------------- CSR build (deterministic) -------------------------
__global__ __launch_bounds__(256) void count_deg(const int* __restrict__ eidx,
                                                 int* __restrict__ deg) {
  int e = blockIdx.x * 256 + threadIdx.x;
  if (e < NE) atomicAdd(&deg[eidx[NE + e]], 1);
}

__global__ __launch_bounds__(1024) void scan_rowptr(int* __restrict__ degcur,
                                                    int* __restrict__ rowptr) {
  __shared__ int wsum[16];
  const int tid = threadIdx.x, lane = tid & 63, w = tid >> 6;
  int base = 0;
  for (int c0 = 0; c0 < NN; c0 += 1024) {
    int i = c0 + tid;
    int v = (i < NN) ? degcur[i] : 0;
    int x = v;
#pragma unroll
    for (int off = 1; off < 64; off <<= 1) {
      int y = __shfl_up(x, off, 64);
      if (lane >= off) x += y;
    }
    if (lane == 63) wsum[w] = x;
    __syncthreads();
    int woff = 0;
    for (int k = 0; k < w; ++k) woff += wsum[k];
    int tot = 0;
    for (int k = 0; k < 16; ++k) tot += wsum[k];
    if (i < NN) {
      int ex = base + woff + x - v;
      rowptr[i] = ex;
      degcur[i] = ex;
    }
    base += tot;
    __syncthreads();
  }
  if (tid == 0) rowptr[NN] = base;
}

__global__ __launch_bounds__(256) void scatter_perm(const int* __restrict__ eidx,
                                                    int* __restrict__ cursor,
                                                    int* __restrict__ perm) {
  int e = blockIdx.x * 256 + threadIdx.x;
  if (e < NE) {
    int d = eidx[NE + e];
    int slot = atomicAdd(&cursor[d], 1);
    perm[slot] = e;
  }
}

__global__ __launch_bounds__(256) void sort_segments(const int* __restrict__ rowptr,
                                                     int* __restrict__ perm) {
  int n = blockIdx.x * 256 + threadIdx.x;
  if (n < NN) {
    int s = rowptr[n], t = rowptr[n + 1];
    for (int i = s + 1; i < t; ++i) {
      int key = perm[i], j = i - 1;
      while (j >= s && perm[j] > key) { perm[j + 1] = perm[j]; --j; }
      perm[j + 1] = key;
    }
  }
}

// ---------------------------------------------------------------------------
// MFMA edge conv, dst-sorted edges, sigma row permutation:
//   MFMA row R=16m+4q+r holds edge sigma(R)=16q+4m+r, so each lane owns 16
//   CONSECUTIVE sorted edges -> long run-merge before atomics.
//   Gather staged into LDS post-MFMA with f16x8 vector loads.
// ---------------------------------------------------------------------------
template <int NOUT>
__global__ __launch_bounds__(256, 4) void edge_conv_mfma(
    const float* __restrict__ edge_attr, const int* __restrict__ eidx,
    const int* __restrict__ perm,
    const float* __restrict__ ew1, const float* __restrict__ eb1,
    const _Float16* __restrict__ Bp, const float* __restrict__ bc,
    const _Float16* __restrict__ gat, float* __restrict__ aggr) {
  constexpr int NTW = NOUT / 64;   // n-tiles per wave
  constexpr int NG8 = NOUT / 8;    // 8-col groups per row
  __shared__ float ea_s[64 * 16];
  __shared__ _Float16 t_h[64 * 256];
  __shared__ int perm_s[64], src_s[64], dst_s[64];
  const int tid = threadIdx.x;
  const int e0 = blockIdx.x * 64;
  const int lane = tid & 63, w = tid >> 6;
  const int q = lane >> 4, li = lane & 15;

  if (tid < 64) {
    int p = perm[e0 + tid];
    perm_s[tid] = p;
    src_s[tid] = eidx[p];
    dst_s[tid] = eidx[NE + p];
  }
  __syncthreads();
  {
    int r = tid >> 2, c4 = tid & 3;
    *(float4*)&ea_s[r * 16 + c4 * 4] =
        *(const float4*)&edge_attr[(size_t)perm_s[r] * 16 + c4 * 4];
  }
  __syncthreads();

  // t-phase: column tid for all 64 edges; store edge m at physical row sigma(m)
  float wcol[16];
#pragma unroll
  for (int k = 0; k < 16; ++k) wcol[k] = ew1[k * 256 + tid];
  const float bias = eb1[tid];
  const float4* ea4 = (const float4*)ea_s;
  const int gw = tid >> 3, el = tid & 7;
  for (int m = 0; m < 64; ++m) {
    float4 a0 = ea4[m * 4 + 0], a1 = ea4[m * 4 + 1], a2 = ea4[m * 4 + 2], a3 = ea4[m * 4 + 3];
    float s = bias;
    s = fmaf(a0.x, wcol[0], s);  s = fmaf(a0.y, wcol[1], s);
    s = fmaf(a0.z, wcol[2], s);  s = fmaf(a0.w, wcol[3], s);
    s = fmaf(a1.x, wcol[4], s);  s = fmaf(a1.y, wcol[5], s);
    s = fmaf(a1.z, wcol[6], s);  s = fmaf(a1.w, wcol[7], s);
    s = fmaf(a2.x, wcol[8], s);  s = fmaf(a2.y, wcol[9], s);
    s = fmaf(a2.z, wcol[10], s); s = fmaf(a2.w, wcol[11], s);
    s = fmaf(a3.x, wcol[12], s); s = fmaf(a3.y, wcol[13], s);
    s = fmaf(a3.z, wcol[14], s); s = fmaf(a3.w, wcol[15], s);
    int p = (((m >> 2) & 3) << 4) | ((m >> 4) << 2) | (m & 3);   // sigma(m)
    t_h[p * 256 + ((gw ^ (p & 7)) << 3) + el] = (_Float16)fmaxf(s, 0.f);
  }

  // bias-init accumulators (C/D: col=lane&15, row=4*(lane>>4)+reg)
  f32x4v acc[4][NTW];
#pragma unroll
  for (int nl = 0; nl < NTW; ++nl) {
    float bv = bc[(w * NTW + nl) * 16 + li];
#pragma unroll
    for (int m = 0; m < 4; ++m) { f32x4v t = {bv, bv, bv, bv}; acc[m][nl] = t; }
  }
  __syncthreads();

  // main GEMM: 8 k-steps of 32
  for (int s8 = 0; s8 < 8; ++s8) {
    f16x8v af[4];
#pragma unroll
    for (int m = 0; m < 4; ++m) {
      int r = 16 * m + li;
      int gl = 4 * s8 + q;
      af[m] = *(const f16x8v*)&t_h[r * 256 + ((gl ^ (r & 7)) << 3)];
    }
#pragma unroll
    for (int nl = 0; nl < NTW; ++nl) {
      int ng = w * NTW + nl;
      f16x8v bf = *(const f16x8v*)&Bp[(size_t)((ng * 8 + s8) * 64 + lane) * 8];
#pragma unroll
      for (int m = 0; m < 4; ++m)
        acc[m][nl] = __builtin_amdgcn_mfma_f32_16x16x32_f16(af[m], bf, acc[m][nl], 0, 0, 0);
    }
  }
  __syncthreads();

  // stage gather rows gat[src[e]] into t_h (reuse), bank-rotated by (g+2*(e>>4))&7
  for (int c = tid; c < 64 * NG8; c += 256) {
    int e = c / NG8, g = c % NG8;
    f16x8v v = *(const f16x8v*)&gat[(size_t)src_s[e] * NOUT + g * 8];
    int pg = (g & ~7) | ((g + 2 * (e >> 4)) & 7);
    *(f16x8v*)&t_h[e * NOUT + pg * 8] = v;
  }
  __syncthreads();

  // epilogue: lane owns edges [16q, 16q+16) for its col; run-merged atomics
#pragma unroll
  for (int nl = 0; nl < NTW; ++nl) {
    const int col = (w * NTW + nl) * 16 + li;
    const int gl2 = col >> 3;
    const int pg = (gl2 & ~7) | ((gl2 + 2 * q) & 7);
    const int loff = pg * 8 + (col & 7);
    float run = 0.f;
    int cur = dst_s[16 * q];
#pragma unroll
    for (int m = 0; m < 4; ++m) {
#pragma unroll
      for (int r = 0; r < 4; ++r) {
        int e = 16 * q + 4 * m + r;          // edge sigma(R), consecutive in e
        int d = dst_s[e];
        if (d != cur) {
          atomicAdd(&aggr[(size_t)cur * NOUT + col], run);
          run = 0.f; cur = d;
        }
        float xv = (float)t_h[e * NOUT + loff];
        run += fmaxf(xv + acc[m][nl][r], 0.f);
      }
    }
    atomicAdd(&aggr[(size_t)cur * NOUT + col], run);
  }
}

// ---------------------------------------------------------------------------
// Node MLP 1: h1h = f16(ReLU(ReLU((x + aggr1) @ w1 + b1) @ w2 + b2))
// ---------------------------------------------------------------------------
__global__ __launch_bounds__(256, 2) void node_mlp1(
    const float* __restrict__ x, const float* __restrict__ aggr1,
    const float* __restrict__ w1, const float* __restrict__ b1,
    const float* __restrict__ w2, const float* __restrict__ b2,
    _Float16* __restrict__ h1h) {
  __shared__ float u_s[64 * 64];
  __shared__ float v_s[64 * 256];
  const int tid = threadIdx.x;
  const int i0 = blockIdx.x * 64;
#pragma unroll
  for (int r = 0; r < 4; ++r) {
    int idx4 = tid + r * 256;
    int m = idx4 >> 4, k = (idx4 & 15) * 4;
    int node = i0 + m;
    float4 v = make_float4(0.f, 0.f, 0.f, 0.f);
    if (node < NN) {
      float4 a = *(const float4*)&x[(size_t)node * 64 + k];
      float4 b = *(const float4*)&aggr1[(size_t)node * 64 + k];
      v = make_float4(a.x + b.x, a.y + b.y, a.z + b.z, a.w + b.w);
    }
    *(float4*)&u_s[m * 64 + (k ^ (((m >> 2) & 7) << 2))] = v;
  }
  __syncthreads();
  const int eg = tid / 32, cg = tid % 32;
  const int m0 = eg * 8, n0 = cg * 8;
  float acc[8][8];
#pragma unroll
  for (int j4 = 0; j4 < 2; ++j4) {
    float4 b = *(const float4*)&b1[n0 + j4 * 4];
#pragma unroll
    for (int i = 0; i < 8; ++i) {
      acc[i][j4 * 4 + 0] = b.x; acc[i][j4 * 4 + 1] = b.y;
      acc[i][j4 * 4 + 2] = b.z; acc[i][j4 * 4 + 3] = b.w;
    }
  }
  tile_gemm<8, 8, 64, 256>(u_s, w1, acc, m0, n0);
#pragma unroll
  for (int i = 0; i < 8; ++i) {
    int m = m0 + i, key = ((m >> 2) & 7) << 2;
#pragma unroll
    for (int j4 = 0; j4 < 2; ++j4) {
      *(float4*)&v_s[m * 256 + ((n0 + j4 * 4) ^ key)] =
          relu4(acc[i][j4 * 4 + 0], acc[i][j4 * 4 + 1], acc[i][j4 * 4 + 2], acc[i][j4 * 4 + 3]);
    }
  }
  __syncthreads();
  float acc2[8][8];
#pragma unroll
  for (int j4 = 0; j4 < 2; ++j4) {
    float4 b = *(const float4*)&b2[n0 + j4 * 4];
#pragma unroll
    for (int i = 0; i < 8; ++i) {
      acc2[i][j4 * 4 + 0] = b.x; acc2[i][j4 * 4 + 1] = b.y;
      acc2[i][j4 * 4 + 2] = b.z; acc2[i][j4 * 4 + 3] = b.w;
    }
  }
  tile_gemm<8, 8, 256, 256>(v_s, w2, acc2, m0, n0);
#pragma unroll
  for (int i = 0; i < 8; ++i) {
    int node = i0 + m0 + i;
    if (node < NN) {
      f16x8v h;
#pragma unroll
      for (int j = 0; j < 8; ++j) h[j] = (_Float16)fmaxf(acc2[i][j], 0.f);
      *(f16x8v*)&h1h[(size_t)node * 256 + n0] = h;
    }
  }
}

// ---------------------------------------------------------------------------
// Node MLP 2 + fused mean-pool numerator (reads h1 as f16)
// ---------------------------------------------------------------------------
__global__ __launch_bounds__(256) void node_mlp2(
    const _Float16* __restrict__ h1h, const float* __restrict__ aggr2,
    const float* __restrict__ w1, const float* __restrict__ b1,
    const float* __restrict__ w2, const float* __restrict__ b2,
    const int* __restrict__ batch, float* __restrict__ pool) {
  __shared__ float u_s[64 * 256];
  __shared__ float v_s[64 * 256];
  __shared__ int batch_s[64];
  const int tid = threadIdx.x;
  const int i0 = blockIdx.x * 64;
  if (tid < 64) batch_s[tid] = (i0 + tid < NN) ? batch[i0 + tid] : -1;
#pragma unroll 4
  for (int r = 0; r < 16; ++r) {
    int idx4 = tid + r * 256;
    int m = idx4 >> 6, k = (idx4 & 63) * 4;
    int node = i0 + m;
    float4 v = make_float4(0.f, 0.f, 0.f, 0.f);
    if (node < NN) {
      f16x4v a = *(const f16x4v*)&h1h[(size_t)node * 256 + k];
      float4 b = *(const float4*)&aggr2[(size_t)node * 256 + k];
      v = make_float4((float)a[0] + b.x, (float)a[1] + b.y,
                      (float)a[2] + b.z, (float)a[3] + b.w);
    }
    *(float4*)&u_s[m * 256 + (k ^ (((m >> 2) & 7) << 2))] = v;
  }
  __syncthreads();
  const int eg = tid / 32, cg = tid % 32;
  const int m0 = eg * 8, n0 = cg * 8;
  float acc[8][8];
#pragma unroll
  for (int j4 = 0; j4 < 2; ++j4) {
    float4 b = *(const float4*)&b1[n0 + j4 * 4];
#pragma unroll
    for (int i = 0; i < 8; ++i) {
      acc[i][j4 * 4 + 0] = b.x; acc[i][j4 * 4 + 1] = b.y;
      acc[i][j4 * 4 + 2] = b.z; acc[i][j4 * 4 + 3] = b.w;
    }
  }
  tile_gemm<8, 8, 256, 256>(u_s, w1, acc, m0, n0);
#pragma unroll
  for (int i = 0; i < 8; ++i) {
    int m = m0 + i, key = ((m >> 2) & 7) << 2;
#pragma unroll
    for (int j4 = 0; j4 < 2; ++j4) {
      *(float4*)&v_s[m * 256 + ((n0 + j4 * 4) ^ key)] =
          relu4(acc[i][j4 * 4 + 0], acc[i][j4 * 4 + 1], acc[i][j4 * 4 + 2], acc[i][j4 * 4 + 3]);
    }
  }
  __syncthreads();
  float acc2[8][8];
#pragma unroll
  for (int j4 = 0; j4 < 2; ++j4) {
    float4 b = *(const float4*)&b2[n0 + j4 * 4];
#pragma unroll
    for (int i = 0; i < 8; ++i) {
      acc2[i][j4 * 4 + 0] = b.x; acc2[i][j4 * 4 + 1] = b.y;
      acc2[i][j4 * 4 + 2] = b.z; acc2[i][j4 * 4 + 3] = b.w;
    }
  }
  tile_gemm<8, 8, 256, 256>(v_s, w2, acc2, m0, n0);
#pragma unroll
  for (int i = 0; i < 8; ++i) {
    int m = m0 + i;
#pragma unroll
    for (int j4 = 0; j4 < 2; ++j4) {
      *(float4*)&u_s[m * 256 + n0 + j4 * 4] =
          relu4(acc2[i][j4 * 4 + 0], acc2[i][j4 * 4 + 1], acc2[i][j4 * 4 + 2], acc2[i][j4 * 4 + 3]);
    }
  }
  __syncthreads();
  float run = 0.f;
  int curg = -2;
  for (int m = 0; m < 64; ++m) {
    int g = batch_s[m];
    if (g != curg) {
      if (curg >= 0) atomicAdd(&pool[curg * 256 + tid], run);
      run = 0.f; curg = g;
    }
    if (g >= 0) run += u_s[m * 256 + tid];
  }
  if (curg >= 0) atomicAdd(&pool[curg * 256 + tid], run);
}

__global__ __launch_bounds__(256) void count_nodes(const int* __restrict__ batch,
                                                   float* __restrict__ counts) {
  int i = blockIdx.x * 256 + threadIdx.x;
  if (i < NN) atomicAdd(&counts[batch[i]], 1.0f);
}

__global__ __launch_bounds__(128) void head_kernel(
    const float* __restrict__ pool, const float* __restrict__ counts,
    const float* __restrict__ l1w, const float* __restrict__ l1b,
    const float* __restrict__ l2w, const float* __restrict__ l2b,
    const float* __restrict__ hs_w, const float* __restrict__ hs_b,
    const float* __restrict__ hp_w, const float* __restrict__ hp_b,
    const float* __restrict__ hn_w, const float* __restrict__ hn_b,
    float* __restrict__ out) {
  const int g = blockIdx.x, tid = threadIdx.x;
  __shared__ float g_s[256], g1_s[128], g2_s[64];
  float cnt = fmaxf(counts[g], 1.0f);
  g_s[tid] = pool[g * 256 + tid] / cnt;
  g_s[tid + 128] = pool[g * 256 + tid + 128] / cnt;
  __syncthreads();
  float s = l1b[tid];
  for (int k = 0; k < 256; ++k) s = fmaf(g_s[k], l1w[k * 128 + tid], s);
  g1_s[tid] = fmaxf(s, 0.f);
  __syncthreads();
  if (tid < 64) {
    float s2 = l2b[tid];
    for (int k = 0; k < 128; ++k) s2 = fmaf(g1_s[k], l2w[k * 64 + tid], s2);
    g2_s[tid] = fmaxf(s2, 0.f);
  }
  __syncthreads();
  if (tid < 64) {
    float v = g2_s[tid];
    float a = v * hs_w[tid], b = v * hp_w[tid], c = v * hn_w[tid];
    for (int off = 32; off > 0; off >>= 1) {
      a += __shfl_down(a, off, 64);
      b += __shfl_down(b, off, 64);
      c += __shfl_down(c, off, 64);
    }
    if (tid == 0) {
      out[g]        = a + hs_b[0];
      out[64 + g]   = b + hp_b[0];
      out[128 + g]  = c + hn_b[0];
    }
  }
}

extern "C" void kernel_launch(void* const* d_in, const int* in_sizes, int n_in,
                              void* d_out, int out_size, void* d_ws, size_t ws_size,
                              hipStream_t stream) {
  (void)in_sizes; (void)n_in; (void)out_size; (void)ws_size;
  const float* x         = (const float*)d_in[0];
  const int*   eidx      = (const int*)d_in[1];
  const int*   batch     = (const int*)d_in[2];
  const float* edge_attr = (const float*)d_in[3];
  const float* ew1  = (const float*)d_in[4];
  const float* eb1  = (const float*)d_in[5];
  const float* ew2  = (const float*)d_in[6];
  const float* eb2  = (const float*)d_in[7];
  const float* le1w = (const float*)d_in[8];
  const float* le1b = (const float*)d_in[9];
  const float* le2w = (const float*)d_in[10];
  const float* le2b = (const float*)d_in[11];
  const float* n1w1 = (const float*)d_in[12];
  const float* n1b1 = (const float*)d_in[13];
  const float* n1w2 = (const float*)d_in[14];
  const float* n1b2 = (const float*)d_in[15];
  const float* n2w1 = (const float*)d_in[16];
  const float* n2b1 = (const float*)d_in[17];
  const float* n2w2 = (const float*)d_in[18];
  const float* n2b2 = (const float*)d_in[19];
  const float* l1w  = (const float*)d_in[20];
  const float* l1b  = (const float*)d_in[21];
  const float* l2w  = (const float*)d_in[22];
  const float* l2b  = (const float*)d_in[23];
  const float* hs_w = (const float*)d_in[24];
  const float* hs_b = (const float*)d_in[25];
  const float* hp_w = (const float*)d_in[26];
  const float* hp_b = (const float*)d_in[27];
  const float* hn_w = (const float*)d_in[28];
  const float* hn_b = (const float*)d_in[29];

  float* ws    = (float*)d_ws;
  float* W1c   = ws + OFF_W1C;
  float* b1c   = ws + OFF_B1C;
  float* W2c   = ws + OFF_W2C;
  float* b2c   = ws + OFF_B2C;
  float* aggr1 = ws + OFF_AGGR1;
  float* aggr2 = ws + OFF_AGGR2;
  _Float16* xh = (_Float16*)aggr2;            // alias: dead before conv2's memset
  _Float16* h1h = (_Float16*)(ws + OFF_H1H);
  float* pool  = ws + OFF_POOL;
  float* cnts  = ws + OFF_CNT;
  int*   cursor= (int*)ws + OFF_CURSOR;
  int*   rowptr= (int*)ws + OFF_ROWPTR;
  int*   perm  = (int*)ws + OFF_PERM;
  _Float16* Bp1 = (_Float16*)(ws + OFF_BP1);
  _Float16* Bp2 = (_Float16*)(ws + OFF_BP2);
  float* out   = (float*)d_out;

  hipMemsetAsync(aggr1, 0, (size_t)NN * 64 * 4, stream);
  hipMemsetAsync(pool, 0, (size_t)NG * 256 * 4, stream);
  hipMemsetAsync(cnts, 0, (size_t)NG * 4, stream);
  hipMemsetAsync(cursor, 0, (size_t)NN * 4, stream);

  prep_weights<<<322, 256, 0, stream>>>(ew2, eb2, le1w, le1b, le2w, le2b, W1c, b1c, W2c, b2c);
  pack_frags<<<8, 256, 0, stream>>>(W1c, Bp1, 4, 64);
  pack_frags<<<32, 256, 0, stream>>>(W2c, Bp2, 16, 256);
  cast_xh<<<625, 256, 0, stream>>>(x, xh);
  count_nodes<<<(NN + 255) / 256, 256, 0, stream>>>(batch, cnts);

  count_deg<<<(NE + 255) / 256, 256, 0, stream>>>(eidx, cursor);
  scan_rowptr<<<1, 1024, 0, stream>>>(cursor, rowptr);
  scatter_perm<<<(NE + 255) / 256, 256, 0, stream>>>(eidx, cursor, perm);
  sort_segments<<<(NN + 255) / 256, 256, 0, stream>>>(rowptr, perm);

  edge_conv_mfma<64><<<NE / 64, 256, 0, stream>>>(edge_attr, eidx, perm, ew1, eb1,
                                                  Bp1, b1c, xh, aggr1);
  node_mlp1<<<(NN + 63) / 64, 256, 0, stream>>>(x, aggr1, n1w1, n1b1, n1w2, n1b2, h1h);
  hipMemsetAsync(aggr2, 0, (size_t)NN * 256 * 4, stream);   // xh dead from here
  edge_conv_mfma<256><<<NE / 64, 256, 0, stream>>>(edge_attr, eidx, perm, ew1, eb1,
                                                   Bp2, b2c, h1h, aggr2);
  node_mlp2<<<(NN + 63) / 64, 256, 0, stream>>>(h1h, aggr2, n2w1, n2b1, n2w2, n2b2, batch, pool);
  head_kernel<<<NG, 128, 0, stream>>>(pool, cnts, l1w, l1b, l2w, l2b,
                                      hs_w, hs_b, hp_w, hp_b, hn_w, hn_b, out);
}

// Round 5
// 530.042 us; speedup vs baseline: 5.7476x; 1.3002x over previous
//
#include <hip/hip_runtime.h>

constexpr int NN  = 20000;   // nodes
constexpr int NE  = 320000;  // edges
constexpr int NG  = 64;      // graphs

typedef _Float16 f16x8v __attribute__((ext_vector_type(8)));
typedef _Float16 f16x4v __attribute__((ext_vector_type(4)));
typedef float    f32x4v __attribute__((ext_vector_type(4)));

// workspace layout (in 4-byte units)
constexpr size_t OFF_W1C    = 0;                          // 256*64
constexpr size_t OFF_B1C    = 16384;                      // 64
constexpr size_t OFF_W2C    = 16448;                      // 256*256
constexpr size_t OFF_B2C    = 81984;                      // 256
constexpr size_t OFF_AGGR1  = 82240;                      // 20000*64 fp32
constexpr size_t OFF_AGGR2  = 1362240;                    // 20000*256 fp32 (xh aliased pre-conv2)
constexpr size_t OFF_H1H    = 6482240;                    // 20000*256 f16 (2.56M floats)
constexpr size_t OFF_BN1A   = 9042240;                    // n1w1 packed (K=64):  16384 halves
constexpr size_t OFF_BN1B   = 9050432;                    // n1w2 packed: 65536 halves
constexpr size_t OFF_BN2A   = 9083200;                    // n2w1 packed: 65536 halves
constexpr size_t OFF_BN2B   = 9115968;                    // n2w2 packed: 65536 halves
constexpr size_t OFF_POOL   = 11602240;                   // 64*256
constexpr size_t OFF_CNT    = 11618624;                   // 64
constexpr size_t OFF_CURSOR = 11618688;                   // 20000 ints
constexpr size_t OFF_ROWPTR = 11638688;                   // 20001 ints
constexpr size_t OFF_PERM   = 11658689;                   // 320000 ints
constexpr size_t OFF_BP1    = 11978752;                   // f16 frag-packed W1c
constexpr size_t OFF_BP2    = 11986944;                   // f16 frag-packed W2c

// ---------------------------------------------------------------------------
// Shared MFMA 64-row GEMM: A = f16 LDS [64][KIN] swizzled, B = frag-packed.
// k-map on both sides: k = 32*s8 + 8*q + e.
// ---------------------------------------------------------------------------
template <int KIN, int NOUT>
__device__ __forceinline__ void mfma_gemm64(const _Float16* t_h,
                                            const _Float16* __restrict__ Bp,
                                            f32x4v (&acc)[4][NOUT / 64],
                                            int w, int lane) {
  const int q = lane >> 4, li = lane & 15;
  constexpr int KSTEPS = KIN / 32;
  constexpr int NTW = NOUT / 64;
  for (int s8 = 0; s8 < KSTEPS; ++s8) {
    f16x8v af[4];
#pragma unroll
    for (int m = 0; m < 4; ++m) {
      int r = 16 * m + li;
      int gl = 4 * s8 + q;
      af[m] = *(const f16x8v*)&t_h[r * KIN + ((gl ^ (r & 7)) << 3)];
    }
#pragma unroll
    for (int nl = 0; nl < NTW; ++nl) {
      int ng = w * NTW + nl;
      f16x8v bf = *(const f16x8v*)&Bp[(size_t)((ng * KSTEPS + s8) * 64 + lane) * 8];
#pragma unroll
      for (int m = 0; m < 4; ++m)
        acc[m][nl] = __builtin_amdgcn_mfma_f32_16x16x32_f16(af[m], bf, acc[m][nl], 0, 0, 0);
    }
  }
}

template <int NTW>
__device__ __forceinline__ void bias_init(f32x4v (&acc)[4][NTW],
                                          const float* __restrict__ b, int w, int li) {
#pragma unroll
  for (int nl = 0; nl < NTW; ++nl) {
    float bv = b[(w * NTW + nl) * 16 + li];
#pragma unroll
    for (int m = 0; m < 4; ++m) { f32x4v t = {bv, bv, bv, bv}; acc[m][nl] = t; }
  }
}

__global__ __launch_bounds__(256) void prep_weights(
    const float* __restrict__ ew2, const float* __restrict__ eb2,
    const float* __restrict__ le1_w, const float* __restrict__ le1_b,
    const float* __restrict__ le2_w, const float* __restrict__ le2_b,
    float* __restrict__ W1c, float* __restrict__ b1c,
    float* __restrict__ W2c, float* __restrict__ b2c) {
  int idx = blockIdx.x * 256 + threadIdx.x;
  if (idx < 16384) {
    int i = idx >> 6, j = idx & 63;
    float s = 0.f;
    for (int k = 0; k < 256; ++k) s = fmaf(ew2[i * 256 + k], le1_w[k * 64 + j], s);
    W1c[idx] = s;
  } else if (idx < 16384 + 65536) {
    int t = idx - 16384;
    int i = t >> 8, j = t & 255;
    float s = 0.f;
    for (int k = 0; k < 256; ++k) s = fmaf(ew2[i * 256 + k], le2_w[k * 256 + j], s);
    W2c[t] = s;
  } else if (idx < 16384 + 65536 + 64) {
    int j = idx - 16384 - 65536;
    float s = le1_b[j];
    for (int k = 0; k < 256; ++k) s = fmaf(eb2[k], le1_w[k * 64 + j], s);
    b1c[j] = s;
  } else if (idx < 16384 + 65536 + 64 + 256) {
    int j = idx - 16384 - 65536 - 64;
    float s = le2_b[j];
    for (int k = 0; k < 256; ++k) s = fmaf(eb2[k], le2_w[k * 256 + j], s);
    b2c[j] = s;
  }
}

// Pack W (KIN x nout fp32, row-major) into MFMA B-frag order; ksteps = KIN/32
__global__ __launch_bounds__(256) void pack_frags(const float* __restrict__ Wc,
                                                  _Float16* __restrict__ Bp,
                                                  int ksteps, int nout) {
  int idx = blockIdx.x * 256 + threadIdx.x;
  if (idx >= (nout / 16) * ksteps * 64) return;
  int lane = idx & 63;
  int s = (idx >> 6) % ksteps;
  int ng = idx / (64 * ksteps);
  int kbase = 32 * s + 8 * (lane >> 4);
  int col = 16 * ng + (lane & 15);
  f16x8v v;
#pragma unroll
  for (int e = 0; e < 8; ++e) v[e] = (_Float16)Wc[(size_t)(kbase + e) * nout + col];
  *(f16x8v*)&Bp[(size_t)idx * 8] = v;
}

__global__ __launch_bounds__(256) void cast_xh(const float* __restrict__ x,
                                               _Float16* __restrict__ xh) {
  int idx = blockIdx.x * 256 + threadIdx.x;
  if (idx * 8 < NN * 64) {
    float4 a = *(const float4*)&x[idx * 8];
    float4 b = *(const float4*)&x[idx * 8 + 4];
    f16x8v v;
    v[0] = (_Float16)a.x; v[1] = (_Float16)a.y; v[2] = (_Float16)a.z; v[3] = (_Float16)a.w;
    v[4] = (_Float16)b.x; v[5] = (_Float16)b.y; v[6] = (_Float16)b.z; v[7] = (_Float16)b.w;
    *(f16x8v*)&xh[idx * 8] = v;
  }
}

// ----------------------- CSR build (deterministic) -------------------------
__global__ __launch_bounds__(256) void count_deg(const int* __restrict__ eidx,
                                                 int* __restrict__ deg) {
  int e = blockIdx.x * 256 + threadIdx.x;
  if (e < NE) atomicAdd(&deg[eidx[NE + e]], 1);
}

__global__ __launch_bounds__(1024) void scan_rowptr(int* __restrict__ degcur,
                                                    int* __restrict__ rowptr) {
  __shared__ int wsum[16];
  const int tid = threadIdx.x, lane = tid & 63, w = tid >> 6;
  int base = 0;
  for (int c0 = 0; c0 < NN; c0 += 1024) {
    int i = c0 + tid;
    int v = (i < NN) ? degcur[i] : 0;
    int x = v;
#pragma unroll
    for (int off = 1; off < 64; off <<= 1) {
      int y = __shfl_up(x, off, 64);
      if (lane >= off) x += y;
    }
    if (lane == 63) wsum[w] = x;
    __syncthreads();
    int woff = 0;
    for (int k = 0; k < w; ++k) woff += wsum[k];
    int tot = 0;
    for (int k = 0; k < 16; ++k) tot += wsum[k];
    if (i < NN) {
      int ex = base + woff + x - v;
      rowptr[i] = ex;
      degcur[i] = ex;
    }
    base += tot;
    __syncthreads();
  }
  if (tid == 0) rowptr[NN] = base;
}

__global__ __launch_bounds__(256) void scatter_perm(const int* __restrict__ eidx,
                                                    int* __restrict__ cursor,
                                                    int* __restrict__ perm) {
  int e = blockIdx.x * 256 + threadIdx.x;
  if (e < NE) {
    int d = eidx[NE + e];
    int slot = atomicAdd(&cursor[d], 1);
    perm[slot] = e;
  }
}

__global__ __launch_bounds__(256) void sort_segments(const int* __restrict__ rowptr,
                                                     int* __restrict__ perm) {
  int n = blockIdx.x * 256 + threadIdx.x;
  if (n < NN) {
    int s = rowptr[n], t = rowptr[n + 1];
    for (int i = s + 1; i < t; ++i) {
      int key = perm[i], j = i - 1;
      while (j >= s && perm[j] > key) { perm[j + 1] = perm[j]; --j; }
      perm[j + 1] = key;
    }
  }
}

// ---------------------------------------------------------------------------
// MFMA edge conv (unchanged from R3, proven)
// ---------------------------------------------------------------------------
template <int NOUT>
__global__ __launch_bounds__(256, 4) void edge_conv_mfma(
    const float* __restrict__ edge_attr, const int* __restrict__ eidx,
    const int* __restrict__ perm,
    const float* __restrict__ ew1, const float* __restrict__ eb1,
    const _Float16* __restrict__ Bp, const float* __restrict__ bc,
    const _Float16* __restrict__ gat, float* __restrict__ aggr) {
  constexpr int NTW = NOUT / 64;
  constexpr int NG8 = NOUT / 8;
  __shared__ float ea_s[64 * 16];
  __shared__ _Float16 t_h[64 * 256];
  __shared__ int perm_s[64], src_s[64], dst_s[64];
  const int tid = threadIdx.x;
  const int e0 = blockIdx.x * 64;
  const int lane = tid & 63, w = tid >> 6;
  const int q = lane >> 4, li = lane & 15;

  if (tid < 64) {
    int p = perm[e0 + tid];
    perm_s[tid] = p;
    src_s[tid] = eidx[p];
    dst_s[tid] = eidx[NE + p];
  }
  __syncthreads();
  {
    int r = tid >> 2, c4 = tid & 3;
    *(float4*)&ea_s[r * 16 + c4 * 4] =
        *(const float4*)&edge_attr[(size_t)perm_s[r] * 16 + c4 * 4];
  }
  __syncthreads();

  float wcol[16];
#pragma unroll
  for (int k = 0; k < 16; ++k) wcol[k] = ew1[k * 256 + tid];
  const float bias = eb1[tid];
  const float4* ea4 = (const float4*)ea_s;
  const int gw = tid >> 3, el = tid & 7;
  for (int m = 0; m < 64; ++m) {
    float4 a0 = ea4[m * 4 + 0], a1 = ea4[m * 4 + 1], a2 = ea4[m * 4 + 2], a3 = ea4[m * 4 + 3];
    float s = bias;
    s = fmaf(a0.x, wcol[0], s);  s = fmaf(a0.y, wcol[1], s);
    s = fmaf(a0.z, wcol[2], s);  s = fmaf(a0.w, wcol[3], s);
    s = fmaf(a1.x, wcol[4], s);  s = fmaf(a1.y, wcol[5], s);
    s = fmaf(a1.z, wcol[6], s);  s = fmaf(a1.w, wcol[7], s);
    s = fmaf(a2.x, wcol[8], s);  s = fmaf(a2.y, wcol[9], s);
    s = fmaf(a2.z, wcol[10], s); s = fmaf(a2.w, wcol[11], s);
    s = fmaf(a3.x, wcol[12], s); s = fmaf(a3.y, wcol[13], s);
    s = fmaf(a3.z, wcol[14], s); s = fmaf(a3.w, wcol[15], s);
    int p = (((m >> 2) & 3) << 4) | ((m >> 4) << 2) | (m & 3);   // sigma(m)
    t_h[p * 256 + ((gw ^ (p & 7)) << 3) + el] = (_Float16)fmaxf(s, 0.f);
  }

  f32x4v acc[4][NTW];
  bias_init<NTW>(acc, bc, w, li);
  __syncthreads();

  for (int s8 = 0; s8 < 8; ++s8) {
    f16x8v af[4];
#pragma unroll
    for (int m = 0; m < 4; ++m) {
      int r = 16 * m + li;
      int gl = 4 * s8 + q;
      af[m] = *(const f16x8v*)&t_h[r * 256 + ((gl ^ (r & 7)) << 3)];
    }
#pragma unroll
    for (int nl = 0; nl < NTW; ++nl) {
      int ng = w * NTW + nl;
      f16x8v bf = *(const f16x8v*)&Bp[(size_t)((ng * 8 + s8) * 64 + lane) * 8];
#pragma unroll
      for (int m = 0; m < 4; ++m)
        acc[m][nl] = __builtin_amdgcn_mfma_f32_16x16x32_f16(af[m], bf, acc[m][nl], 0, 0, 0);
    }
  }
  __syncthreads();

  for (int c = tid; c < 64 * NG8; c += 256) {
    int e = c / NG8, g = c % NG8;
    f16x8v v = *(const f16x8v*)&gat[(size_t)src_s[e] * NOUT + g * 8];
    int pg = (g & ~7) | ((g + 2 * (e >> 4)) & 7);
    *(f16x8v*)&t_h[e * NOUT + pg * 8] = v;
  }
  __syncthreads();

#pragma unroll
  for (int nl = 0; nl < NTW; ++nl) {
    const int col = (w * NTW + nl) * 16 + li;
    const int gl2 = col >> 3;
    const int pg = (gl2 & ~7) | ((gl2 + 2 * q) & 7);
    const int loff = pg * 8 + (col & 7);
    float run = 0.f;
    int cur = dst_s[16 * q];
#pragma unroll
    for (int m = 0; m < 4; ++m) {
#pragma unroll
      for (int r = 0; r < 4; ++r) {
        int e = 16 * q + 4 * m + r;
        int d = dst_s[e];
        if (d != cur) {
          atomicAdd(&aggr[(size_t)cur * NOUT + col], run);
          run = 0.f; cur = d;
        }
        float xv = (float)t_h[e * NOUT + loff];
        run += fmaxf(xv + acc[m][nl][r], 0.f);
      }
    }
    atomicAdd(&aggr[(size_t)cur * NOUT + col], run);
  }
}

// ---------------------------------------------------------------------------
// MFMA node MLP 1: h1h = f16(ReLU(ReLU((x+aggr1)@w1+b1)@w2+b2)), 64 nodes/block
// Single 32KB LDS buffer reused (barrier-separated) for u, v, and output.
// ---------------------------------------------------------------------------
__global__ __launch_bounds__(256, 3) void node_mlp1_mfma(
    const float* __restrict__ x, const float* __restrict__ aggr1,
    const _Float16* __restrict__ BpA, const float* __restrict__ b1,
    const _Float16* __restrict__ BpB, const float* __restrict__ b2,
    _Float16* __restrict__ h1h) {
  __shared__ _Float16 t_h[64 * 256];
  const int tid = threadIdx.x;
  const int i0 = blockIdx.x * 64;
  const int lane = tid & 63, w = tid >> 6;
  const int q = lane >> 4, li = lane & 15;

  // stage u = f16(x + aggr1)  [64 x 64] swizzled
#pragma unroll
  for (int r2 = 0; r2 < 2; ++r2) {
    int idx = tid + r2 * 256;
    int e = idx >> 3, g = idx & 7;
    int node = i0 + e;
    f16x8v v;
#pragma unroll
    for (int j = 0; j < 8; ++j) v[j] = (_Float16)0.f;
    if (node < NN) {
      float4 a0 = *(const float4*)&x[(size_t)node * 64 + g * 8];
      float4 a1 = *(const float4*)&x[(size_t)node * 64 + g * 8 + 4];
      float4 c0 = *(const float4*)&aggr1[(size_t)node * 64 + g * 8];
      float4 c1 = *(const float4*)&aggr1[(size_t)node * 64 + g * 8 + 4];
      v[0] = (_Float16)(a0.x + c0.x); v[1] = (_Float16)(a0.y + c0.y);
      v[2] = (_Float16)(a0.z + c0.z); v[3] = (_Float16)(a0.w + c0.w);
      v[4] = (_Float16)(a1.x + c1.x); v[5] = (_Float16)(a1.y + c1.y);
      v[6] = (_Float16)(a1.z + c1.z); v[7] = (_Float16)(a1.w + c1.w);
    }
    *(f16x8v*)&t_h[e * 64 + ((g ^ (e & 7)) << 3)] = v;
  }
  __syncthreads();

  f32x4v acc[4][4];
  bias_init<4>(acc, b1, w, li);
  mfma_gemm64<64, 256>(t_h, BpA, acc, w, lane);
  __syncthreads();   // all u reads done

  // v = f16(ReLU(acc)) swizzled [64 x 256]
#pragma unroll
  for (int m = 0; m < 4; ++m)
#pragma unroll
    for (int nl = 0; nl < 4; ++nl)
#pragma unroll
      for (int r = 0; r < 4; ++r) {
        int row = 16 * m + 4 * q + r;
        int col = (w * 4 + nl) * 16 + li;
        int g = col >> 3;
        t_h[row * 256 + ((g ^ (row & 7)) << 3) + (col & 7)] =
            (_Float16)fmaxf(acc[m][nl][r], 0.f);
      }
  __syncthreads();

  bias_init<4>(acc, b2, w, li);
  mfma_gemm64<256, 256>(t_h, BpB, acc, w, lane);
  __syncthreads();   // all v reads done

  // h2 plain layout
#pragma unroll
  for (int m = 0; m < 4; ++m)
#pragma unroll
    for (int nl = 0; nl < 4; ++nl)
#pragma unroll
      for (int r = 0; r < 4; ++r) {
        int row = 16 * m + 4 * q + r;
        int col = (w * 4 + nl) * 16 + li;
        t_h[row * 256 + col] = (_Float16)fmaxf(acc[m][nl][r], 0.f);
      }
  __syncthreads();

  // coalesced global store
#pragma unroll
  for (int r8 = 0; r8 < 8; ++r8) {
    int idx = tid + r8 * 256;
    int e = idx >> 5, g = idx & 31;
    int node = i0 + e;
    if (node < NN)
      *(f16x8v*)&h1h[(size_t)node * 256 + g * 8] = *(const f16x8v*)&t_h[e * 256 + g * 8];
  }
}

// ---------------------------------------------------------------------------
// MFMA node MLP 2 + fused mean-pool numerator
// ---------------------------------------------------------------------------
__global__ __launch_bounds__(256, 3) void node_mlp2_mfma(
    const _Float16* __restrict__ h1h, const float* __restrict__ aggr2,
    const _Float16* __restrict__ BpA, const float* __restrict__ b1,
    const _Float16* __restrict__ BpB, const float* __restrict__ b2,
    const int* __restrict__ batch, float* __restrict__ pool) {
  __shared__ _Float16 t_h[64 * 256];
  __shared__ int batch_s[64];
  const int tid = threadIdx.x;
  const int i0 = blockIdx.x * 64;
  const int lane = tid & 63, w = tid >> 6;
  const int q = lane >> 4, li = lane & 15;

  if (tid < 64) batch_s[tid] = (i0 + tid < NN) ? batch[i0 + tid] : -1;

  // stage u = f16(h1 + aggr2)  [64 x 256] swizzled
#pragma unroll
  for (int r8 = 0; r8 < 8; ++r8) {
    int idx = tid + r8 * 256;
    int e = idx >> 5, g = idx & 31;
    int node = i0 + e;
    f16x8v v;
#pragma unroll
    for (int j = 0; j < 8; ++j) v[j] = (_Float16)0.f;
    if (node < NN) {
      f16x8v a = *(const f16x8v*)&h1h[(size_t)node * 256 + g * 8];
      float4 c0 = *(const float4*)&aggr2[(size_t)node * 256 + g * 8];
      float4 c1 = *(const float4*)&aggr2[(size_t)node * 256 + g * 8 + 4];
      v[0] = (_Float16)((float)a[0] + c0.x); v[1] = (_Float16)((float)a[1] + c0.y);
      v[2] = (_Float16)((float)a[2] + c0.z); v[3] = (_Float16)((float)a[3] + c0.w);
      v[4] = (_Float16)((float)a[4] + c1.x); v[5] = (_Float16)((float)a[5] + c1.y);
      v[6] = (_Float16)((float)a[6] + c1.z); v[7] = (_Float16)((float)a[7] + c1.w);
    }
    *(f16x8v*)&t_h[e * 256 + ((g ^ (e & 7)) << 3)] = v;
  }
  __syncthreads();

  f32x4v acc[4][4];
  bias_init<4>(acc, b1, w, li);
  mfma_gemm64<256, 256>(t_h, BpA, acc, w, lane);
  __syncthreads();

#pragma unroll
  for (int m = 0; m < 4; ++m)
#pragma unroll
    for (int nl = 0; nl < 4; ++nl)
#pragma unroll
      for (int r = 0; r < 4; ++r) {
        int row = 16 * m + 4 * q + r;
        int col = (w * 4 + nl) * 16 + li;
        int g = col >> 3;
        t_h[row * 256 + ((g ^ (row & 7)) << 3) + (col & 7)] =
            (_Float16)fmaxf(acc[m][nl][r], 0.f);
      }
  __syncthreads();

  bias_init<4>(acc, b2, w, li);
  mfma_gemm64<256, 256>(t_h, BpB, acc, w, lane);
  __syncthreads();

  // h2 plain layout
#pragma unroll
  for (int m = 0; m < 4; ++m)
#pragma unroll
    for (int nl = 0; nl < 4; ++nl)
#pragma unroll
      for (int r = 0; r < 4; ++r) {
        int row = 16 * m + 4 * q + r;
        int col = (w * 4 + nl) * 16 + li;
        t_h[row * 256 + col] = (_Float16)fmaxf(acc[m][nl][r], 0.f);
      }
  __syncthreads();

  // segmented pool over sorted batch: column tid, fp32 run
  float run = 0.f;
  int curg = -2;
  for (int m = 0; m < 64; ++m) {
    int g = batch_s[m];
    if (g != curg) {
      if (curg >= 0) atomicAdd(&pool[curg * 256 + tid], run);
      run = 0.f; curg = g;
    }
    if (g >= 0) run += (float)t_h[m * 256 + tid];
  }
  if (curg >= 0) atomicAdd(&pool[curg * 256 + tid], run);
}

__global__ __launch_bounds__(256) void count_nodes(const int* __restrict__ batch,
                                                   float* __restrict__ counts) {
  int i = blockIdx.x * 256 + threadIdx.x;
  if (i < NN) atomicAdd(&counts[batch[i]], 1.0f);
}

__global__ __launch_bounds__(128) void head_kernel(
    const float* __restrict__ pool, const float* __restrict__ counts,
    const float* __restrict__ l1w, const float* __restrict__ l1b,
    const float* __restrict__ l2w, const float* __restrict__ l2b,
    const float* __restrict__ hs_w, const float* __restrict__ hs_b,
    const float* __restrict__ hp_w, const float* __restrict__ hp_b,
    const float* __restrict__ hn_w, const float* __restrict__ hn_b,
    float* __restrict__ out) {
  const int g = blockIdx.x, tid = threadIdx.x;
  __shared__ float g_s[256], g1_s[128], g2_s[64];
  float cnt = fmaxf(counts[g], 1.0f);
  g_s[tid] = pool[g * 256 + tid] / cnt;
  g_s[tid + 128] = pool[g * 256 + tid + 128] / cnt;
  __syncthreads();
  float s = l1b[tid];
  for (int k = 0; k < 256; ++k) s = fmaf(g_s[k], l1w[k * 128 + tid], s);
  g1_s[tid] = fmaxf(s, 0.f);
  __syncthreads();
  if (tid < 64) {
    float s2 = l2b[tid];
    for (int k = 0; k < 128; ++k) s2 = fmaf(g1_s[k], l2w[k * 64 + tid], s2);
    g2_s[tid] = fmaxf(s2, 0.f);
  }
  __syncthreads();
  if (tid < 64) {
    float v = g2_s[tid];
    float a = v * hs_w[tid], b = v * hp_w[tid], c = v * hn_w[tid];
    for (int off = 32; off > 0; off >>= 1) {
      a += __shfl_down(a, off, 64);
      b += __shfl_down(b, off, 64);
      c += __shfl_down(c, off, 64);
    }
    if (tid == 0) {
      out[g]        = a + hs_b[0];
      out[64 + g]   = b + hp_b[0];
      out[128 + g]  = c + hn_b[0];
    }
  }
}

extern "C" void kernel_launch(void* const* d_in, const int* in_sizes, int n_in,
                              void* d_out, int out_size, void* d_ws, size_t ws_size,
                              hipStream_t stream) {
  (void)in_sizes; (void)n_in; (void)out_size; (void)ws_size;
  const float* x         = (const float*)d_in[0];
  const int*   eidx      = (const int*)d_in[1];
  const int*   batch     = (const int*)d_in[2];
  const float* edge_attr = (const float*)d_in[3];
  const float* ew1  = (const float*)d_in[4];
  const float* eb1  = (const float*)d_in[5];
  const float* ew2  = (const float*)d_in[6];
  const float* eb2  = (const float*)d_in[7];
  const float* le1w = (const float*)d_in[8];
  const float* le1b = (const float*)d_in[9];
  const float* le2w = (const float*)d_in[10];
  const float* le2b = (const float*)d_in[11];
  const float* n1w1 = (const float*)d_in[12];
  const float* n1b1 = (const float*)d_in[13];
  const float* n1w2 = (const float*)d_in[14];
  const float* n1b2 = (const float*)d_in[15];
  const float* n2w1 = (const float*)d_in[16];
  const float* n2b1 = (const float*)d_in[17];
  const float* n2w2 = (const float*)d_in[18];
  const float* n2b2 = (const float*)d_in[19];
  const float* l1w  = (const float*)d_in[20];
  const float* l1b  = (const float*)d_in[21];
  const float* l2w  = (const float*)d_in[22];
  const float* l2b  = (const float*)d_in[23];
  const float* hs_w = (const float*)d_in[24];
  const float* hs_b = (const float*)d_in[25];
  const float* hp_w = (const float*)d_in[26];
  const float* hp_b = (const float*)d_in[27];
  const float* hn_w = (const float*)d_in[28];
  const float* hn_b = (const float*)d_in[29];

  float* ws    = (float*)d_ws;
  float* W1c   = ws + OFF_W1C;
  float* b1c   = ws + OFF_B1C;
  float* W2c   = ws + OFF_W2C;
  float* b2c   = ws + OFF_B2C;
  float* aggr1 = ws + OFF_AGGR1;
  float* aggr2 = ws + OFF_AGGR2;
  _Float16* xh = (_Float16*)aggr2;            // alias: dead before conv2's memset
  _Float16* h1h = (_Float16*)(ws + OFF_H1H);
  float* pool  = ws + OFF_POOL;
  float* cnts  = ws + OFF_CNT;
  int*   cursor= (int*)ws + OFF_CURSOR;
  int*   rowptr= (int*)ws + OFF_ROWPTR;
  int*   perm  = (int*)ws + OFF_PERM;
  _Float16* Bp1  = (_Float16*)(ws + OFF_BP1);
  _Float16* Bp2  = (_Float16*)(ws + OFF_BP2);
  _Float16* BpN1a = (_Float16*)(ws + OFF_BN1A);
  _Float16* BpN1b = (_Float16*)(ws + OFF_BN1B);
  _Float16* BpN2a = (_Float16*)(ws + OFF_BN2A);
  _Float16* BpN2b = (_Float16*)(ws + OFF_BN2B);
  float* out   = (float*)d_out;

  hipMemsetAsync(aggr1, 0, (size_t)NN * 64 * 4, stream);
  hipMemsetAsync(pool, 0, (size_t)NG * 256 * 4, stream);
  hipMemsetAsync(cnts, 0, (size_t)NG * 4, stream);
  hipMemsetAsync(cursor, 0, (size_t)NN * 4, stream);

  prep_weights<<<322, 256, 0, stream>>>(ew2, eb2, le1w, le1b, le2w, le2b, W1c, b1c, W2c, b2c);
  pack_frags<<<8, 256, 0, stream>>>(W1c, Bp1, 8, 64);
  pack_frags<<<32, 256, 0, stream>>>(W2c, Bp2, 8, 256);
  pack_frags<<<8, 256, 0, stream>>>(n1w1, BpN1a, 2, 256);
  pack_frags<<<32, 256, 0, stream>>>(n1w2, BpN1b, 8, 256);
  pack_frags<<<32, 256, 0, stream>>>(n2w1, BpN2a, 8, 256);
  pack_frags<<<32, 256, 0, stream>>>(n2w2, BpN2b, 8, 256);
  cast_xh<<<625, 256, 0, stream>>>(x, xh);
  count_nodes<<<(NN + 255) / 256, 256, 0, stream>>>(batch, cnts);

  count_deg<<<(NE + 255) / 256, 256, 0, stream>>>(eidx, cursor);
  scan_rowptr<<<1, 1024, 0, stream>>>(cursor, rowptr);
  scatter_perm<<<(NE + 255) / 256, 256, 0, stream>>>(eidx, cursor, perm);
  sort_segments<<<(NN + 255) / 256, 256, 0, stream>>>(rowptr, perm);

  edge_conv_mfma<64><<<NE / 64, 256, 0, stream>>>(edge_attr, eidx, perm, ew1, eb1,
                                                  Bp1, b1c, xh, aggr1);
  node_mlp1_mfma<<<(NN + 63) / 64, 256, 0, stream>>>(x, aggr1, BpN1a, n1b1, BpN1b, n1b2, h1h);
  hipMemsetAsync(aggr2, 0, (size_t)NN * 256 * 4, stream);   // xh dead from here
  edge_conv_mfma<256><<<NE / 64, 256, 0, stream>>>(edge_attr, eidx, perm, ew1, eb1,
                                                   Bp2, b2c, h1h, aggr2);
  node_mlp2_mfma<<<(NN + 63) / 64, 256, 0, stream>>>(h1h, aggr2, BpN2a, n2b1, BpN2b, n2b2,
                                                     batch, pool);
  head_kernel<<<NG, 128, 0, stream>>>(pool, cnts, l1w, l1b, l2w, l2b,
                                      hs_w, hs_b, hp_w, hp_b, hn_w, hn_b, out);
}

// Round 6
// 482.514 us; speedup vs baseline: 6.3137x; 1.0985x over previous
//
#include <hip/hip_runtime.h>

constexpr int NN  = 20000;   // nodes
constexpr int NE  = 320000;  // edges
constexpr int NG  = 64;      // graphs

typedef _Float16 f16x8v __attribute__((ext_vector_type(8)));
typedef _Float16 f16x4v __attribute__((ext_vector_type(4)));
typedef float    f32x4v __attribute__((ext_vector_type(4)));

// workspace layout (in 4-byte units)
constexpr size_t OFF_W1C    = 0;                          // 256*64
constexpr size_t OFF_B1C    = 16384;                      // 64
constexpr size_t OFF_W2C    = 16448;                      // 256*256
constexpr size_t OFF_B2C    = 81984;                      // 256
constexpr size_t OFF_AGGR1  = 82240;                      // 20000*64 fp32
constexpr size_t OFF_AGGR2  = 1362240;                    // 20000*256 fp32 (xh aliased pre-conv2)
constexpr size_t OFF_H1H    = 6482240;                    // 20000*256 f16
constexpr size_t OFF_BN1A   = 9042240;                    // n1w1 packed (K=64)
constexpr size_t OFF_BN1B   = 9050432;                    // n1w2 packed
constexpr size_t OFF_BN2A   = 9083200;                    // n2w1 packed
constexpr size_t OFF_BN2B   = 9115968;                    // n2w2 packed
constexpr size_t OFF_BPE    = 9148736;                    // ew1 packed (K=16 pad 32): 8192 halves
constexpr size_t OFF_POOL   = 11602240;                   // 64*256
constexpr size_t OFF_CNT    = 11618624;                   // 64
constexpr size_t OFF_CURSOR = 11618688;                   // 20000 ints
constexpr size_t OFF_ROWPTR = 11638688;                   // 20001 ints
constexpr size_t OFF_PERM   = 11658689;                   // 320000 ints
constexpr size_t OFF_BP1    = 11978752;                   // f16 frag-packed W1c
constexpr size_t OFF_BP2    = 11986944;                   // f16 frag-packed W2c

// ---------------------------------------------------------------------------
// Shared MFMA 64-row GEMM: A = f16 LDS [64][KIN] swizzled, B = frag-packed.
// k-map on both sides: k = 32*s8 + 8*q + e.
// ---------------------------------------------------------------------------
template <int KIN, int NOUT>
__device__ __forceinline__ void mfma_gemm64(const _Float16* t_h,
                                            const _Float16* __restrict__ Bp,
                                            f32x4v (&acc)[4][NOUT / 64],
                                            int w, int lane) {
  const int q = lane >> 4, li = lane & 15;
  constexpr int KSTEPS = KIN / 32;
  constexpr int NTW = NOUT / 64;
  for (int s8 = 0; s8 < KSTEPS; ++s8) {
    f16x8v af[4];
#pragma unroll
    for (int m = 0; m < 4; ++m) {
      int r = 16 * m + li;
      int gl = 4 * s8 + q;
      af[m] = *(const f16x8v*)&t_h[r * KIN + ((gl ^ (r & 7)) << 3)];
    }
#pragma unroll
    for (int nl = 0; nl < NTW; ++nl) {
      int ng = w * NTW + nl;
      f16x8v bf = *(const f16x8v*)&Bp[(size_t)((ng * KSTEPS + s8) * 64 + lane) * 8];
#pragma unroll
      for (int m = 0; m < 4; ++m)
        acc[m][nl] = __builtin_amdgcn_mfma_f32_16x16x32_f16(af[m], bf, acc[m][nl], 0, 0, 0);
    }
  }
}

template <int NTW>
__device__ __forceinline__ void bias_init(f32x4v (&acc)[4][NTW],
                                          const float* __restrict__ b, int w, int li) {
#pragma unroll
  for (int nl = 0; nl < NTW; ++nl) {
    float bv = b[(w * NTW + nl) * 16 + li];
#pragma unroll
    for (int m = 0; m < 4; ++m) { f32x4v t = {bv, bv, bv, bv}; acc[m][nl] = t; }
  }
}

__global__ __launch_bounds__(256) void prep_weights(
    const float* __restrict__ ew2, const float* __restrict__ eb2,
    const float* __restrict__ le1_w, const float* __restrict__ le1_b,
    const float* __restrict__ le2_w, const float* __restrict__ le2_b,
    float* __restrict__ W1c, float* __restrict__ b1c,
    float* __restrict__ W2c, float* __restrict__ b2c) {
  int idx = blockIdx.x * 256 + threadIdx.x;
  if (idx < 16384) {
    int i = idx >> 6, j = idx & 63;
    float s = 0.f;
    for (int k = 0; k < 256; ++k) s = fmaf(ew2[i * 256 + k], le1_w[k * 64 + j], s);
    W1c[idx] = s;
  } else if (idx < 16384 + 65536) {
    int t = idx - 16384;
    int i = t >> 8, j = t & 255;
    float s = 0.f;
    for (int k = 0; k < 256; ++k) s = fmaf(ew2[i * 256 + k], le2_w[k * 256 + j], s);
    W2c[t] = s;
  } else if (idx < 16384 + 65536 + 64) {
    int j = idx - 16384 - 65536;
    float s = le1_b[j];
    for (int k = 0; k < 256; ++k) s = fmaf(eb2[k], le1_w[k * 64 + j], s);
    b1c[j] = s;
  } else if (idx < 16384 + 65536 + 64 + 256) {
    int j = idx - 16384 - 65536 - 64;
    float s = le2_b[j];
    for (int k = 0; k < 256; ++k) s = fmaf(eb2[k], le2_w[k * 256 + j], s);
    b2c[j] = s;
  }
}

// Pack W (kreal x nout fp32, row-major) into MFMA B-frag order, K padded to
// ksteps*32 with zeros; k-map 32*s + 8*q + e matches the A-side reads.
__global__ __launch_bounds__(256) void pack_frags(const float* __restrict__ Wc,
                                                  _Float16* __restrict__ Bp,
                                                  int ksteps, int nout, int kreal) {
  int idx = blockIdx.x * 256 + threadIdx.x;
  if (idx >= (nout / 16) * ksteps * 64) return;
  int lane = idx & 63;
  int s = (idx >> 6) % ksteps;
  int ng = idx / (64 * ksteps);
  int kbase = 32 * s + 8 * (lane >> 4);
  int col = 16 * ng + (lane & 15);
  f16x8v v;
#pragma unroll
  for (int e = 0; e < 8; ++e)
    v[e] = (kbase + e < kreal) ? (_Float16)Wc[(size_t)(kbase + e) * nout + col]
                               : (_Float16)0.f;
  *(f16x8v*)&Bp[(size_t)idx * 8] = v;
}

__global__ __launch_bounds__(256) void cast_xh(const float* __restrict__ x,
                                               _Float16* __restrict__ xh) {
  int idx = blockIdx.x * 256 + threadIdx.x;
  if (idx * 8 < NN * 64) {
    float4 a = *(const float4*)&x[idx * 8];
    float4 b = *(const float4*)&x[idx * 8 + 4];
    f16x8v v;
    v[0] = (_Float16)a.x; v[1] = (_Float16)a.y; v[2] = (_Float16)a.z; v[3] = (_Float16)a.w;
    v[4] = (_Float16)b.x; v[5] = (_Float16)b.y; v[6] = (_Float16)b.z; v[7] = (_Float16)b.w;
    *(f16x8v*)&xh[idx * 8] = v;
  }
}

// ----------------------- CSR build (deterministic) -------------------------
__global__ __launch_bounds__(256) void count_deg(const int* __restrict__ eidx,
                                                 int* __restrict__ deg) {
  int e = blockIdx.x * 256 + threadIdx.x;
  if (e < NE) atomicAdd(&deg[eidx[NE + e]], 1);
}

__global__ __launch_bounds__(1024) void scan_rowptr(int* __restrict__ degcur,
                                                    int* __restrict__ rowptr) {
  __shared__ int wsum[16];
  const int tid = threadIdx.x, lane = tid & 63, w = tid >> 6;
  int base = 0;
  for (int c0 = 0; c0 < NN; c0 += 1024) {
    int i = c0 + tid;
    int v = (i < NN) ? degcur[i] : 0;
    int x = v;
#pragma unroll
    for (int off = 1; off < 64; off <<= 1) {
      int y = __shfl_up(x, off, 64);
      if (lane >= off) x += y;
    }
    if (lane == 63) wsum[w] = x;
    __syncthreads();
    int woff = 0;
    for (int k = 0; k < w; ++k) woff += wsum[k];
    int tot = 0;
    for (int k = 0; k < 16; ++k) tot += wsum[k];
    if (i < NN) {
      int ex = base + woff + x - v;
      rowptr[i] = ex;
      degcur[i] = ex;
    }
    base += tot;
    __syncthreads();
  }
  if (tid == 0) rowptr[NN] = base;
}

__global__ __launch_bounds__(256) void scatter_perm(const int* __restrict__ eidx,
                                                    int* __restrict__ cursor,
                                                    int* __restrict__ perm) {
  int e = blockIdx.x * 256 + threadIdx.x;
  if (e < NE) {
    int d = eidx[NE + e];
    int slot = atomicAdd(&cursor[d], 1);
    perm[slot] = e;
  }
}

__global__ __launch_bounds__(256) void sort_segments(const int* __restrict__ rowptr,
                                                     int* __restrict__ perm) {
  int n = blockIdx.x * 256 + threadIdx.x;
  if (n < NN) {
    int s = rowptr[n], t = rowptr[n + 1];
    for (int i = s + 1; i < t; ++i) {
      int key = perm[i], j = i - 1;
      while (j >= s && perm[j] > key) { perm[j + 1] = perm[j]; --j; }
      perm[j + 1] = key;
    }
  }
}

// ---------------------------------------------------------------------------
// MFMA edge conv, dst-sorted, sigma row permutation. t-phase now MFMA too:
//   ea f16 [64][40-pad] LDS (cols 16-31 zero), ew1 frag-packed K=32 (kreal=16)
//   -> 16 MFMA/wave produce t = ReLU(ea@ew1+eb1), stored sigma+swizzled.
// ---------------------------------------------------------------------------
template <int NOUT>
__global__ __launch_bounds__(256, 4) void edge_conv_mfma(
    const float* __restrict__ edge_attr, const int* __restrict__ eidx,
    const int* __restrict__ perm,
    const _Float16* __restrict__ Bpe, const float* __restrict__ eb1,
    const _Float16* __restrict__ Bp, const float* __restrict__ bc,
    const _Float16* __restrict__ gat, float* __restrict__ aggr) {
  constexpr int NTW = NOUT / 64;
  constexpr int NG8 = NOUT / 8;
  __shared__ _Float16 ea_h[64 * 40];
  __shared__ _Float16 t_h[64 * 256];
  __shared__ int perm_s[64], src_s[64], dst_s[64];
  const int tid = threadIdx.x;
  const int e0 = blockIdx.x * 64;
  const int lane = tid & 63, w = tid >> 6;
  const int q = lane >> 4, li = lane & 15;

  if (tid < 64) {
    int p = perm[e0 + tid];
    perm_s[tid] = p;
    src_s[tid] = eidx[p];
    dst_s[tid] = eidx[NE + p];
  }
  __syncthreads();
  {
    int e2 = (tid & 127) >> 1, gq = tid & 1;
    if (tid < 128) {
      const float* src = &edge_attr[(size_t)perm_s[e2] * 16 + gq * 8];
      float4 a = *(const float4*)src;
      float4 b = *(const float4*)(src + 4);
      f16x8v v;
      v[0] = (_Float16)a.x; v[1] = (_Float16)a.y; v[2] = (_Float16)a.z; v[3] = (_Float16)a.w;
      v[4] = (_Float16)b.x; v[5] = (_Float16)b.y; v[6] = (_Float16)b.z; v[7] = (_Float16)b.w;
      *(f16x8v*)&ea_h[e2 * 40 + gq * 8] = v;
    } else {
      f16x8v z = {};
      *(f16x8v*)&ea_h[e2 * 40 + 16 + gq * 8] = z;   // zero pad k=16..31
    }
  }

  // t-phase accumulators (bias eb1), then MFMA over padded K=32
  f32x4v acct[4][4];
  bias_init<4>(acct, eb1, w, li);
  __syncthreads();
  {
    f16x8v afe[4];
#pragma unroll
    for (int m = 0; m < 4; ++m)
      afe[m] = *(const f16x8v*)&ea_h[(16 * m + li) * 40 + 8 * q];
#pragma unroll
    for (int nl = 0; nl < 4; ++nl) {
      f16x8v bf = *(const f16x8v*)&Bpe[(size_t)((w * 4 + nl) * 64 + lane) * 8];
#pragma unroll
      for (int m = 0; m < 4; ++m)
        acct[m][nl] = __builtin_amdgcn_mfma_f32_16x16x32_f16(afe[m], bf, acct[m][nl], 0, 0, 0);
    }
    // store t with sigma row-permutation + XOR swizzle (ReLU applied)
#pragma unroll
    for (int m = 0; m < 4; ++m)
#pragma unroll
      for (int nl = 0; nl < 4; ++nl)
#pragma unroll
        for (int r = 0; r < 4; ++r) {
          int E = 16 * m + 4 * q + r;                                   // edge = D row
          int p = (((E >> 2) & 3) << 4) | ((E >> 4) << 2) | (E & 3);    // sigma(E)
          int col = (w * 4 + nl) * 16 + li;
          int g = col >> 3;
          t_h[p * 256 + ((g ^ (p & 7)) << 3) + (col & 7)] =
              (_Float16)fmaxf(acct[m][nl][r], 0.f);
        }
  }

  f32x4v acc[4][NTW];
  bias_init<NTW>(acc, bc, w, li);
  __syncthreads();

  // main GEMM: 8 k-steps of 32
  for (int s8 = 0; s8 < 8; ++s8) {
    f16x8v af[4];
#pragma unroll
    for (int m = 0; m < 4; ++m) {
      int r = 16 * m + li;
      int gl = 4 * s8 + q;
      af[m] = *(const f16x8v*)&t_h[r * 256 + ((gl ^ (r & 7)) << 3)];
    }
#pragma unroll
    for (int nl = 0; nl < NTW; ++nl) {
      int ng = w * NTW + nl;
      f16x8v bf = *(const f16x8v*)&Bp[(size_t)((ng * 8 + s8) * 64 + lane) * 8];
#pragma unroll
      for (int m = 0; m < 4; ++m)
        acc[m][nl] = __builtin_amdgcn_mfma_f32_16x16x32_f16(af[m], bf, acc[m][nl], 0, 0, 0);
    }
  }
  __syncthreads();

  // stage gather rows gat[src[e]] into t_h (reuse), bank-rotated
  for (int c = tid; c < 64 * NG8; c += 256) {
    int e = c / NG8, g = c % NG8;
    f16x8v v = *(const f16x8v*)&gat[(size_t)src_s[e] * NOUT + g * 8];
    int pg = (g & ~7) | ((g + 2 * (e >> 4)) & 7);
    *(f16x8v*)&t_h[e * NOUT + pg * 8] = v;
  }
  __syncthreads();

  // epilogue: lane owns edges [16q,16q+16); run-merged atomics over sorted dst
#pragma unroll
  for (int nl = 0; nl < NTW; ++nl) {
    const int col = (w * NTW + nl) * 16 + li;
    const int gl2 = col >> 3;
    const int pg = (gl2 & ~7) | ((gl2 + 2 * q) & 7);
    const int loff = pg * 8 + (col & 7);
    float run = 0.f;
    int cur = dst_s[16 * q];
#pragma unroll
    for (int m = 0; m < 4; ++m) {
#pragma unroll
      for (int r = 0; r < 4; ++r) {
        int e = 16 * q + 4 * m + r;
        int d = dst_s[e];
        if (d != cur) {
          atomicAdd(&aggr[(size_t)cur * NOUT + col], run);
          run = 0.f; cur = d;
        }
        float xv = (float)t_h[e * NOUT + loff];
        run += fmaxf(xv + acc[m][nl][r], 0.f);
      }
    }
    atomicAdd(&aggr[(size_t)cur * NOUT + col], run);
  }
}

// ---------------------------------------------------------------------------
// MFMA node MLP 1
// ---------------------------------------------------------------------------
__global__ __launch_bounds__(256, 3) void node_mlp1_mfma(
    const float* __restrict__ x, const float* __restrict__ aggr1,
    const _Float16* __restrict__ BpA, const float* __restrict__ b1,
    const _Float16* __restrict__ BpB, const float* __restrict__ b2,
    _Float16* __restrict__ h1h) {
  __shared__ _Float16 t_h[64 * 256];
  const int tid = threadIdx.x;
  const int i0 = blockIdx.x * 64;
  const int lane = tid & 63, w = tid >> 6;
  const int q = lane >> 4, li = lane & 15;

#pragma unroll
  for (int r2 = 0; r2 < 2; ++r2) {
    int idx = tid + r2 * 256;
    int e = idx >> 3, g = idx & 7;
    int node = i0 + e;
    f16x8v v;
#pragma unroll
    for (int j = 0; j < 8; ++j) v[j] = (_Float16)0.f;
    if (node < NN) {
      float4 a0 = *(const float4*)&x[(size_t)node * 64 + g * 8];
      float4 a1 = *(const float4*)&x[(size_t)node * 64 + g * 8 + 4];
      float4 c0 = *(const float4*)&aggr1[(size_t)node * 64 + g * 8];
      float4 c1 = *(const float4*)&aggr1[(size_t)node * 64 + g * 8 + 4];
      v[0] = (_Float16)(a0.x + c0.x); v[1] = (_Float16)(a0.y + c0.y);
      v[2] = (_Float16)(a0.z + c0.z); v[3] = (_Float16)(a0.w + c0.w);
      v[4] = (_Float16)(a1.x + c1.x); v[5] = (_Float16)(a1.y + c1.y);
      v[6] = (_Float16)(a1.z + c1.z); v[7] = (_Float16)(a1.w + c1.w);
    }
    *(f16x8v*)&t_h[e * 64 + ((g ^ (e & 7)) << 3)] = v;
  }
  __syncthreads();

  f32x4v acc[4][4];
  bias_init<4>(acc, b1, w, li);
  mfma_gemm64<64, 256>(t_h, BpA, acc, w, lane);
  __syncthreads();

#pragma unroll
  for (int m = 0; m < 4; ++m)
#pragma unroll
    for (int nl = 0; nl < 4; ++nl)
#pragma unroll
      for (int r = 0; r < 4; ++r) {
        int row = 16 * m + 4 * q + r;
        int col = (w * 4 + nl) * 16 + li;
        int g = col >> 3;
        t_h[row * 256 + ((g ^ (row & 7)) << 3) + (col & 7)] =
            (_Float16)fmaxf(acc[m][nl][r], 0.f);
      }
  __syncthreads();

  bias_init<4>(acc, b2, w, li);
  mfma_gemm64<256, 256>(t_h, BpB, acc, w, lane);
  __syncthreads();

#pragma unroll
  for (int m = 0; m < 4; ++m)
#pragma unroll
    for (int nl = 0; nl < 4; ++nl)
#pragma unroll
      for (int r = 0; r < 4; ++r) {
        int row = 16 * m + 4 * q + r;
        int col = (w * 4 + nl) * 16 + li;
        t_h[row * 256 + col] = (_Float16)fmaxf(acc[m][nl][r], 0.f);
      }
  __syncthreads();

#pragma unroll
  for (int r8 = 0; r8 < 8; ++r8) {
    int idx = tid + r8 * 256;
    int e = idx >> 5, g = idx & 31;
    int node = i0 + e;
    if (node < NN)
      *(f16x8v*)&h1h[(size_t)node * 256 + g * 8] = *(const f16x8v*)&t_h[e * 256 + g * 8];
  }
}

// ---------------------------------------------------------------------------
// MFMA node MLP 2 + fused mean-pool numerator
// ---------------------------------------------------------------------------
__global__ __launch_bounds__(256, 3) void node_mlp2_mfma(
    const _Float16* __restrict__ h1h, const float* __restrict__ aggr2,
    const _Float16* __restrict__ BpA, const float* __restrict__ b1,
    const _Float16* __restrict__ BpB, const float* __restrict__ b2,
    const int* __restrict__ batch, float* __restrict__ pool) {
  __shared__ _Float16 t_h[64 * 256];
  __shared__ int batch_s[64];
  const int tid = threadIdx.x;
  const int i0 = blockIdx.x * 64;
  const int lane = tid & 63, w = tid >> 6;
  const int q = lane >> 4, li = lane & 15;

  if (tid < 64) batch_s[tid] = (i0 + tid < NN) ? batch[i0 + tid] : -1;

#pragma unroll
  for (int r8 = 0; r8 < 8; ++r8) {
    int idx = tid + r8 * 256;
    int e = idx >> 5, g = idx & 31;
    int node = i0 + e;
    f16x8v v;
#pragma unroll
    for (int j = 0; j < 8; ++j) v[j] = (_Float16)0.f;
    if (node < NN) {
      f16x8v a = *(const f16x8v*)&h1h[(size_t)node * 256 + g * 8];
      float4 c0 = *(const float4*)&aggr2[(size_t)node * 256 + g * 8];
      float4 c1 = *(const float4*)&aggr2[(size_t)node * 256 + g * 8 + 4];
      v[0] = (_Float16)((float)a[0] + c0.x); v[1] = (_Float16)((float)a[1] + c0.y);
      v[2] = (_Float16)((float)a[2] + c0.z); v[3] = (_Float16)((float)a[3] + c0.w);
      v[4] = (_Float16)((float)a[4] + c1.x); v[5] = (_Float16)((float)a[5] + c1.y);
      v[6] = (_Float16)((float)a[6] + c1.z); v[7] = (_Float16)((float)a[7] + c1.w);
    }
    *(f16x8v*)&t_h[e * 256 + ((g ^ (e & 7)) << 3)] = v;
  }
  __syncthreads();

  f32x4v acc[4][4];
  bias_init<4>(acc, b1, w, li);
  mfma_gemm64<256, 256>(t_h, BpA, acc, w, lane);
  __syncthreads();

#pragma unroll
  for (int m = 0; m < 4; ++m)
#pragma unroll
    for (int nl = 0; nl < 4; ++nl)
#pragma unroll
      for (int r = 0; r < 4; ++r) {
        int row = 16 * m + 4 * q + r;
        int col = (w * 4 + nl) * 16 + li;
        int g = col >> 3;
        t_h[row * 256 + ((g ^ (row & 7)) << 3) + (col & 7)] =
            (_Float16)fmaxf(acc[m][nl][r], 0.f);
      }
  __syncthreads();

  bias_init<4>(acc, b2, w, li);
  mfma_gemm64<256, 256>(t_h, BpB, acc, w, lane);
  __syncthreads();

#pragma unroll
  for (int m = 0; m < 4; ++m)
#pragma unroll
    for (int nl = 0; nl < 4; ++nl)
#pragma unroll
      for (int r = 0; r < 4; ++r) {
        int row = 16 * m + 4 * q + r;
        int col = (w * 4 + nl) * 16 + li;
        t_h[row * 256 + col] = (_Float16)fmaxf(acc[m][nl][r], 0.f);
      }
  __syncthreads();

  float run = 0.f;
  int curg = -2;
  for (int m = 0; m < 64; ++m) {
    int g = batch_s[m];
    if (g != curg) {
      if (curg >= 0) atomicAdd(&pool[curg * 256 + tid], run);
      run = 0.f; curg = g;
    }
    if (g >= 0) run += (float)t_h[m * 256 + tid];
  }
  if (curg >= 0) atomicAdd(&pool[curg * 256 + tid], run);
}

__global__ __launch_bounds__(256) void count_nodes(const int* __restrict__ batch,
                                                   float* __restrict__ counts) {
  int i = blockIdx.x * 256 + threadIdx.x;
  if (i < NN) atomicAdd(&counts[batch[i]], 1.0f);
}

__global__ __launch_bounds__(128) void head_kernel(
    const float* __restrict__ pool, const float* __restrict__ counts,
    const float* __restrict__ l1w, const float* __restrict__ l1b,
    const float* __restrict__ l2w, const float* __restrict__ l2b,
    const float* __restrict__ hs_w, const float* __restrict__ hs_b,
    const float* __restrict__ hp_w, const float* __restrict__ hp_b,
    const float* __restrict__ hn_w, const float* __restrict__ hn_b,
    float* __restrict__ out) {
  const int g = blockIdx.x, tid = threadIdx.x;
  __shared__ float g_s[256], g1_s[128], g2_s[64];
  float cnt = fmaxf(counts[g], 1.0f);
  g_s[tid] = pool[g * 256 + tid] / cnt;
  g_s[tid + 128] = pool[g * 256 + tid + 128] / cnt;
  __syncthreads();
  float s = l1b[tid];
  for (int k = 0; k < 256; ++k) s = fmaf(g_s[k], l1w[k * 128 + tid], s);
  g1_s[tid] = fmaxf(s, 0.f);
  __syncthreads();
  if (tid < 64) {
    float s2 = l2b[tid];
    for (int k = 0; k < 128; ++k) s2 = fmaf(g1_s[k], l2w[k * 64 + tid], s2);
    g2_s[tid] = fmaxf(s2, 0.f);
  }
  __syncthreads();
  if (tid < 64) {
    float v = g2_s[tid];
    float a = v * hs_w[tid], b = v * hp_w[tid], c = v * hn_w[tid];
    for (int off = 32; off > 0; off >>= 1) {
      a += __shfl_down(a, off, 64);
      b += __shfl_down(b, off, 64);
      c += __shfl_down(c, off, 64);
    }
    if (tid == 0) {
      out[g]        = a + hs_b[0];
      out[64 + g]   = b + hp_b[0];
      out[128 + g]  = c + hn_b[0];
    }
  }
}

extern "C" void kernel_launch(void* const* d_in, const int* in_sizes, int n_in,
                              void* d_out, int out_size, void* d_ws, size_t ws_size,
                              hipStream_t stream) {
  (void)in_sizes; (void)n_in; (void)out_size; (void)ws_size;
  const float* x         = (const float*)d_in[0];
  const int*   eidx      = (const int*)d_in[1];
  const int*   batch     = (const int*)d_in[2];
  const float* edge_attr = (const float*)d_in[3];
  const float* ew1  = (const float*)d_in[4];
  const float* eb1  = (const float*)d_in[5];
  const float* ew2  = (const float*)d_in[6];
  const float* eb2  = (const float*)d_in[7];
  const float* le1w = (const float*)d_in[8];
  const float* le1b = (const float*)d_in[9];
  const float* le2w = (const float*)d_in[10];
  const float* le2b = (const float*)d_in[11];
  const float* n1w1 = (const float*)d_in[12];
  const float* n1b1 = (const float*)d_in[13];
  const float* n1w2 = (const float*)d_in[14];
  const float* n1b2 = (const float*)d_in[15];
  const float* n2w1 = (const float*)d_in[16];
  const float* n2b1 = (const float*)d_in[17];
  const float* n2w2 = (const float*)d_in[18];
  const float* n2b2 = (const float*)d_in[19];
  const float* l1w  = (const float*)d_in[20];
  const float* l1b  = (const float*)d_in[21];
  const float* l2w  = (const float*)d_in[22];
  const float* l2b  = (const float*)d_in[23];
  const float* hs_w = (const float*)d_in[24];
  const float* hs_b = (const float*)d_in[25];
  const float* hp_w = (const float*)d_in[26];
  const float* hp_b = (const float*)d_in[27];
  const float* hn_w = (const float*)d_in[28];
  const float* hn_b = (const float*)d_in[29];

  float* ws    = (float*)d_ws;
  float* W1c   = ws + OFF_W1C;
  float* b1c   = ws + OFF_B1C;
  float* W2c   = ws + OFF_W2C;
  float* b2c   = ws + OFF_B2C;
  float* aggr1 = ws + OFF_AGGR1;
  float* aggr2 = ws + OFF_AGGR2;
  _Float16* xh = (_Float16*)aggr2;            // alias: dead before conv2's memset
  _Float16* h1h = (_Float16*)(ws + OFF_H1H);
  float* pool  = ws + OFF_POOL;
  float* cnts  = ws + OFF_CNT;
  int*   cursor= (int*)ws + OFF_CURSOR;
  int*   rowptr= (int*)ws + OFF_ROWPTR;
  int*   perm  = (int*)ws + OFF_PERM;
  _Float16* Bp1  = (_Float16*)(ws + OFF_BP1);
  _Float16* Bp2  = (_Float16*)(ws + OFF_BP2);
  _Float16* BpN1a = (_Float16*)(ws + OFF_BN1A);
  _Float16* BpN1b = (_Float16*)(ws + OFF_BN1B);
  _Float16* BpN2a = (_Float16*)(ws + OFF_BN2A);
  _Float16* BpN2b = (_Float16*)(ws + OFF_BN2B);
  _Float16* Bpe  = (_Float16*)(ws + OFF_BPE);
  float* out   = (float*)d_out;

  hipMemsetAsync(aggr1, 0, (size_t)NN * 64 * 4, stream);
  hipMemsetAsync(pool, 0, (size_t)NG * 256 * 4, stream);
  hipMemsetAsync(cnts, 0, (size_t)NG * 4, stream);
  hipMemsetAsync(cursor, 0, (size_t)NN * 4, stream);

  prep_weights<<<322, 256, 0, stream>>>(ew2, eb2, le1w, le1b, le2w, le2b, W1c, b1c, W2c, b2c);
  pack_frags<<<8, 256, 0, stream>>>(W1c, Bp1, 8, 64, 256);
  pack_frags<<<32, 256, 0, stream>>>(W2c, Bp2, 8, 256, 256);
  pack_frags<<<8, 256, 0, stream>>>(n1w1, BpN1a, 2, 256, 64);
  pack_frags<<<32, 256, 0, stream>>>(n1w2, BpN1b, 8, 256, 256);
  pack_frags<<<32, 256, 0, stream>>>(n2w1, BpN2a, 8, 256, 256);
  pack_frags<<<32, 256, 0, stream>>>(n2w2, BpN2b, 8, 256, 256);
  pack_frags<<<4, 256, 0, stream>>>(ew1, Bpe, 1, 256, 16);
  cast_xh<<<625, 256, 0, stream>>>(x, xh);
  count_nodes<<<(NN + 255) / 256, 256, 0, stream>>>(batch, cnts);

  count_deg<<<(NE + 255) / 256, 256, 0, stream>>>(eidx, cursor);
  scan_rowptr<<<1, 1024, 0, stream>>>(cursor, rowptr);
  scatter_perm<<<(NE + 255) / 256, 256, 0, stream>>>(eidx, cursor, perm);
  sort_segments<<<(NN + 255) / 256, 256, 0, stream>>>(rowptr, perm);

  edge_conv_mfma<64><<<NE / 64, 256, 0, stream>>>(edge_attr, eidx, perm, Bpe, eb1,
                                                  Bp1, b1c, xh, aggr1);
  node_mlp1_mfma<<<(NN + 63) / 64, 256, 0, stream>>>(x, aggr1, BpN1a, n1b1, BpN1b, n1b2, h1h);
  hipMemsetAsync(aggr2, 0, (size_t)NN * 256 * 4, stream);   // xh dead from here
  edge_conv_mfma<256><<<NE / 64, 256, 0, stream>>>(edge_attr, eidx, perm, Bpe, eb1,
                                                   Bp2, b2c, h1h, aggr2);
  node_mlp2_mfma<<<(NN + 63) / 64, 256, 0, stream>>>(h1h, aggr2, BpN2a, n2b1, BpN2b, n2b2,
                                                     batch, pool);
  head_kernel<<<NG, 128, 0, stream>>>(pool, cnts, l1w, l1b, l2w, l2b,
                                      hs_w, hs_b, hp_w, hp_b, hn_w, hn_b, out);
}

// Round 7
// 364.912 us; speedup vs baseline: 8.3485x; 1.3223x over previous
//
#include <hip/hip_runtime.h>

constexpr int NN  = 20000;   // nodes
constexpr int NE  = 320000;  // edges
constexpr int NG  = 64;      // graphs

typedef _Float16 f16x8v __attribute__((ext_vector_type(8)));
typedef _Float16 f16x4v __attribute__((ext_vector_type(4)));
typedef float    f32x4v __attribute__((ext_vector_type(4)));

// workspace layout (in 4-byte units)
constexpr size_t OFF_W1C    = 0;                          // 256*64
constexpr size_t OFF_B1C    = 16384;                      // 64
constexpr size_t OFF_W2C    = 16448;                      // 256*256
constexpr size_t OFF_B2C    = 81984;                      // 256
constexpr size_t OFF_AGGR1  = 82240;                      // 20000*64 fp32
constexpr size_t OFF_AGGR2  = 1362240;                    // 20000*256 fp32 (xh aliased pre-conv2)
constexpr size_t OFF_H1H    = 6482240;                    // 20000*256 f16
constexpr size_t OFF_BN1A   = 9042240;                    // n1w1 packed (K=64)
constexpr size_t OFF_BN1B   = 9050432;                    // n1w2 packed
constexpr size_t OFF_BN2A   = 9083200;                    // n2w1 packed
constexpr size_t OFF_BN2B   = 9115968;                    // n2w2 packed
constexpr size_t OFF_BPE    = 9148736;                    // ew1 packed (K=16 pad 32)
constexpr size_t OFF_POOL   = 11602240;                   // 64*256
constexpr size_t OFF_CNT    = 11618624;                   // 64
constexpr size_t OFF_CURSOR = 11618688;                   // 20000 ints
constexpr size_t OFF_ROWPTR = 11638688;                   // 20001 ints
constexpr size_t OFF_PERM   = 11658689;                   // 320000 ints
constexpr size_t OFF_BP1    = 11978752;                   // f16 frag-packed W1c
constexpr size_t OFF_BP2    = 11986944;                   // f16 frag-packed W2c

// ---------------------------------------------------------------------------
// Shared MFMA 64-row GEMM: A = f16 LDS [64][KIN] swizzled, B = frag-packed.
// k-map on both sides: k = 32*s8 + 8*q + e.
// ---------------------------------------------------------------------------
template <int KIN, int NOUT>
__device__ __forceinline__ void mfma_gemm64(const _Float16* t_h,
                                            const _Float16* __restrict__ Bp,
                                            f32x4v (&acc)[4][NOUT / 64],
                                            int w, int lane) {
  const int q = lane >> 4, li = lane & 15;
  constexpr int KSTEPS = KIN / 32;
  constexpr int NTW = NOUT / 64;
  for (int s8 = 0; s8 < KSTEPS; ++s8) {
    f16x8v af[4];
#pragma unroll
    for (int m = 0; m < 4; ++m) {
      int r = 16 * m + li;
      int gl = 4 * s8 + q;
      af[m] = *(const f16x8v*)&t_h[r * KIN + ((gl ^ (r & 7)) << 3)];
    }
#pragma unroll
    for (int nl = 0; nl < NTW; ++nl) {
      int ng = w * NTW + nl;
      f16x8v bf = *(const f16x8v*)&Bp[(size_t)((ng * KSTEPS + s8) * 64 + lane) * 8];
#pragma unroll
      for (int m = 0; m < 4; ++m)
        acc[m][nl] = __builtin_amdgcn_mfma_f32_16x16x32_f16(af[m], bf, acc[m][nl], 0, 0, 0);
    }
  }
}

template <int NTW>
__device__ __forceinline__ void bias_init(f32x4v (&acc)[4][NTW],
                                          const float* __restrict__ b, int w, int li) {
#pragma unroll
  for (int nl = 0; nl < NTW; ++nl) {
    float bv = b[(w * NTW + nl) * 16 + li];
#pragma unroll
    for (int m = 0; m < 4; ++m) { f32x4v t = {bv, bv, bv, bv}; acc[m][nl] = t; }
  }
}

__global__ __launch_bounds__(256) void prep_weights(
    const float* __restrict__ ew2, const float* __restrict__ eb2,
    const float* __restrict__ le1_w, const float* __restrict__ le1_b,
    const float* __restrict__ le2_w, const float* __restrict__ le2_b,
    float* __restrict__ W1c, float* __restrict__ b1c,
    float* __restrict__ W2c, float* __restrict__ b2c) {
  int idx = blockIdx.x * 256 + threadIdx.x;
  if (idx < 16384) {
    int i = idx >> 6, j = idx & 63;
    float s = 0.f;
    for (int k = 0; k < 256; ++k) s = fmaf(ew2[i * 256 + k], le1_w[k * 64 + j], s);
    W1c[idx] = s;
  } else if (idx < 16384 + 65536) {
    int t = idx - 16384;
    int i = t >> 8, j = t & 255;
    float s = 0.f;
    for (int k = 0; k < 256; ++k) s = fmaf(ew2[i * 256 + k], le2_w[k * 256 + j], s);
    W2c[t] = s;
  } else if (idx < 16384 + 65536 + 64) {
    int j = idx - 16384 - 65536;
    float s = le1_b[j];
    for (int k = 0; k < 256; ++k) s = fmaf(eb2[k], le1_w[k * 64 + j], s);
    b1c[j] = s;
  } else if (idx < 16384 + 65536 + 64 + 256) {
    int j = idx - 16384 - 65536 - 64;
    float s = le2_b[j];
    for (int k = 0; k < 256; ++k) s = fmaf(eb2[k], le2_w[k * 256 + j], s);
    b2c[j] = s;
  }
}

// Pack W (kreal x nout fp32, row-major) into MFMA B-frag order, K padded to
// ksteps*32 with zeros; k-map 32*s + 8*q + e matches the A-side reads.
__global__ __launch_bounds__(256) void pack_frags(const float* __restrict__ Wc,
                                                  _Float16* __restrict__ Bp,
                                                  int ksteps, int nout, int kreal) {
  int idx = blockIdx.x * 256 + threadIdx.x;
  if (idx >= (nout / 16) * ksteps * 64) return;
  int lane = idx & 63;
  int s = (idx >> 6) % ksteps;
  int ng = idx / (64 * ksteps);
  int kbase = 32 * s + 8 * (lane >> 4);
  int col = 16 * ng + (lane & 15);
  f16x8v v;
#pragma unroll
  for (int e = 0; e < 8; ++e)
    v[e] = (kbase + e < kreal) ? (_Float16)Wc[(size_t)(kbase + e) * nout + col]
                               : (_Float16)0.f;
  *(f16x8v*)&Bp[(size_t)idx * 8] = v;
}

__global__ __launch_bounds__(256) void cast_xh(const float* __restrict__ x,
                                               _Float16* __restrict__ xh) {
  int idx = blockIdx.x * 256 + threadIdx.x;
  if (idx * 8 < NN * 64) {
    float4 a = *(const float4*)&x[idx * 8];
    float4 b = *(const float4*)&x[idx * 8 + 4];
    f16x8v v;
    v[0] = (_Float16)a.x; v[1] = (_Float16)a.y; v[2] = (_Float16)a.z; v[3] = (_Float16)a.w;
    v[4] = (_Float16)b.x; v[5] = (_Float16)b.y; v[6] = (_Float16)b.z; v[7] = (_Float16)b.w;
    *(f16x8v*)&xh[idx * 8] = v;
  }
}

// ----------------------- CSR build (deterministic) -------------------------
__global__ __launch_bounds__(256) void count_deg(const int* __restrict__ eidx,
                                                 int* __restrict__ deg) {
  int e = blockIdx.x * 256 + threadIdx.x;
  if (e < NE) atomicAdd(&deg[eidx[NE + e]], 1);
}

__global__ __launch_bounds__(1024) void scan_rowptr(int* __restrict__ degcur,
                                                    int* __restrict__ rowptr) {
  __shared__ int wsum[16];
  const int tid = threadIdx.x, lane = tid & 63, w = tid >> 6;
  int base = 0;
  for (int c0 = 0; c0 < NN; c0 += 1024) {
    int i = c0 + tid;
    int v = (i < NN) ? degcur[i] : 0;
    int x = v;
#pragma unroll
    for (int off = 1; off < 64; off <<= 1) {
      int y = __shfl_up(x, off, 64);
      if (lane >= off) x += y;
    }
    if (lane == 63) wsum[w] = x;
    __syncthreads();
    int woff = 0;
    for (int k = 0; k < w; ++k) woff += wsum[k];
    int tot = 0;
    for (int k = 0; k < 16; ++k) tot += wsum[k];
    if (i < NN) {
      int ex = base + woff + x - v;
      rowptr[i] = ex;
      degcur[i] = ex;
    }
    base += tot;
    __syncthreads();
  }
  if (tid == 0) rowptr[NN] = base;
}

__global__ __launch_bounds__(256) void scatter_perm(const int* __restrict__ eidx,
                                                    int* __restrict__ cursor,
                                                    int* __restrict__ perm) {
  int e = blockIdx.x * 256 + threadIdx.x;
  if (e < NE) {
    int d = eidx[NE + e];
    int slot = atomicAdd(&cursor[d], 1);
    perm[slot] = e;
  }
}

__global__ __launch_bounds__(256) void sort_segments(const int* __restrict__ rowptr,
                                                     int* __restrict__ perm) {
  int n = blockIdx.x * 256 + threadIdx.x;
  if (n < NN) {
    int s = rowptr[n], t = rowptr[n + 1];
    for (int i = s + 1; i < t; ++i) {
      int key = perm[i], j = i - 1;
      while (j >= s && perm[j] > key) { perm[j + 1] = perm[j]; --j; }
      perm[j + 1] = key;
    }
  }
}

// ---------------------------------------------------------------------------
// MFMA edge conv, dst-sorted, sigma row permutation; MFMA t-phase (K=16 pad 32)
// ---------------------------------------------------------------------------
template <int NOUT>
__global__ __launch_bounds__(256, 4) void edge_conv_mfma(
    const float* __restrict__ edge_attr, const int* __restrict__ eidx,
    const int* __restrict__ perm,
    const _Float16* __restrict__ Bpe, const float* __restrict__ eb1,
    const _Float16* __restrict__ Bp, const float* __restrict__ bc,
    const _Float16* __restrict__ gat, float* __restrict__ aggr) {
  constexpr int NTW = NOUT / 64;
  constexpr int NG8 = NOUT / 8;
  __shared__ _Float16 ea_h[64 * 40];
  __shared__ _Float16 t_h[64 * 256];
  __shared__ int perm_s[64], src_s[64], dst_s[64];
  const int tid = threadIdx.x;
  const int e0 = blockIdx.x * 64;
  const int lane = tid & 63, w = tid >> 6;
  const int q = lane >> 4, li = lane & 15;

  if (tid < 64) {
    int p = perm[e0 + tid];
    perm_s[tid] = p;
    src_s[tid] = eidx[p];
    dst_s[tid] = eidx[NE + p];
  }
  __syncthreads();
  {
    int e2 = (tid & 127) >> 1, gq = tid & 1;
    if (tid < 128) {
      const float* src = &edge_attr[(size_t)perm_s[e2] * 16 + gq * 8];
      float4 a = *(const float4*)src;
      float4 b = *(const float4*)(src + 4);
      f16x8v v;
      v[0] = (_Float16)a.x; v[1] = (_Float16)a.y; v[2] = (_Float16)a.z; v[3] = (_Float16)a.w;
      v[4] = (_Float16)b.x; v[5] = (_Float16)b.y; v[6] = (_Float16)b.z; v[7] = (_Float16)b.w;
      *(f16x8v*)&ea_h[e2 * 40 + gq * 8] = v;
    } else {
      f16x8v z = {};
      *(f16x8v*)&ea_h[e2 * 40 + 16 + gq * 8] = z;   // zero pad k=16..31
    }
  }

  f32x4v acct[4][4];
  bias_init<4>(acct, eb1, w, li);
  __syncthreads();
  {
    f16x8v afe[4];
#pragma unroll
    for (int m = 0; m < 4; ++m)
      afe[m] = *(const f16x8v*)&ea_h[(16 * m + li) * 40 + 8 * q];
#pragma unroll
    for (int nl = 0; nl < 4; ++nl) {
      f16x8v bf = *(const f16x8v*)&Bpe[(size_t)((w * 4 + nl) * 64 + lane) * 8];
#pragma unroll
      for (int m = 0; m < 4; ++m)
        acct[m][nl] = __builtin_amdgcn_mfma_f32_16x16x32_f16(afe[m], bf, acct[m][nl], 0, 0, 0);
    }
#pragma unroll
    for (int m = 0; m < 4; ++m)
#pragma unroll
      for (int nl = 0; nl < 4; ++nl)
#pragma unroll
        for (int r = 0; r < 4; ++r) {
          int E = 16 * m + 4 * q + r;                                   // edge = D row
          int p = (((E >> 2) & 3) << 4) | ((E >> 4) << 2) | (E & 3);    // sigma(E)
          int col = (w * 4 + nl) * 16 + li;
          int g = col >> 3;
          t_h[p * 256 + ((g ^ (p & 7)) << 3) + (col & 7)] =
              (_Float16)fmaxf(acct[m][nl][r], 0.f);
        }
  }

  f32x4v acc[4][NTW];
  bias_init<NTW>(acc, bc, w, li);
  __syncthreads();

  for (int s8 = 0; s8 < 8; ++s8) {
    f16x8v af[4];
#pragma unroll
    for (int m = 0; m < 4; ++m) {
      int r = 16 * m + li;
      int gl = 4 * s8 + q;
      af[m] = *(const f16x8v*)&t_h[r * 256 + ((gl ^ (r & 7)) << 3)];
    }
#pragma unroll
    for (int nl = 0; nl < NTW; ++nl) {
      int ng = w * NTW + nl;
      f16x8v bf = *(const f16x8v*)&Bp[(size_t)((ng * 8 + s8) * 64 + lane) * 8];
#pragma unroll
      for (int m = 0; m < 4; ++m)
        acc[m][nl] = __builtin_amdgcn_mfma_f32_16x16x32_f16(af[m], bf, acc[m][nl], 0, 0, 0);
    }
  }
  __syncthreads();

  for (int c = tid; c < 64 * NG8; c += 256) {
    int e = c / NG8, g = c % NG8;
    f16x8v v = *(const f16x8v*)&gat[(size_t)src_s[e] * NOUT + g * 8];
    int pg = (g & ~7) | ((g + 2 * (e >> 4)) & 7);
    *(f16x8v*)&t_h[e * NOUT + pg * 8] = v;
  }
  __syncthreads();

#pragma unroll
  for (int nl = 0; nl < NTW; ++nl) {
    const int col = (w * NTW + nl) * 16 + li;
    const int gl2 = col >> 3;
    const int pg = (gl2 & ~7) | ((gl2 + 2 * q) & 7);
    const int loff = pg * 8 + (col & 7);
    float run = 0.f;
    int cur = dst_s[16 * q];
#pragma unroll
    for (int m = 0; m < 4; ++m) {
#pragma unroll
      for (int r = 0; r < 4; ++r) {
        int e = 16 * q + 4 * m + r;
        int d = dst_s[e];
        if (d != cur) {
          atomicAdd(&aggr[(size_t)cur * NOUT + col], run);
          run = 0.f; cur = d;
        }
        float xv = (float)t_h[e * NOUT + loff];
        run += fmaxf(xv + acc[m][nl][r], 0.f);
      }
    }
    atomicAdd(&aggr[(size_t)cur * NOUT + col], run);
  }
}

// ---------------------------------------------------------------------------
// MFMA node MLP 1
// ---------------------------------------------------------------------------
__global__ __launch_bounds__(256, 3) void node_mlp1_mfma(
    const float* __restrict__ x, const float* __restrict__ aggr1,
    const _Float16* __restrict__ BpA, const float* __restrict__ b1,
    const _Float16* __restrict__ BpB, const float* __restrict__ b2,
    _Float16* __restrict__ h1h) {
  __shared__ _Float16 t_h[64 * 256];
  const int tid = threadIdx.x;
  const int i0 = blockIdx.x * 64;
  const int lane = tid & 63, w = tid >> 6;
  const int q = lane >> 4, li = lane & 15;

#pragma unroll
  for (int r2 = 0; r2 < 2; ++r2) {
    int idx = tid + r2 * 256;
    int e = idx >> 3, g = idx & 7;
    int node = i0 + e;
    f16x8v v;
#pragma unroll
    for (int j = 0; j < 8; ++j) v[j] = (_Float16)0.f;
    if (node < NN) {
      float4 a0 = *(const float4*)&x[(size_t)node * 64 + g * 8];
      float4 a1 = *(const float4*)&x[(size_t)node * 64 + g * 8 + 4];
      float4 c0 = *(const float4*)&aggr1[(size_t)node * 64 + g * 8];
      float4 c1 = *(const float4*)&aggr1[(size_t)node * 64 + g * 8 + 4];
      v[0] = (_Float16)(a0.x + c0.x); v[1] = (_Float16)(a0.y + c0.y);
      v[2] = (_Float16)(a0.z + c0.z); v[3] = (_Float16)(a0.w + c0.w);
      v[4] = (_Float16)(a1.x + c1.x); v[5] = (_Float16)(a1.y + c1.y);
      v[6] = (_Float16)(a1.z + c1.z); v[7] = (_Float16)(a1.w + c1.w);
    }
    *(f16x8v*)&t_h[e * 64 + ((g ^ (e & 7)) << 3)] = v;
  }
  __syncthreads();

  f32x4v acc[4][4];
  bias_init<4>(acc, b1, w, li);
  mfma_gemm64<64, 256>(t_h, BpA, acc, w, lane);
  __syncthreads();

#pragma unroll
  for (int m = 0; m < 4; ++m)
#pragma unroll
    for (int nl = 0; nl < 4; ++nl)
#pragma unroll
      for (int r = 0; r < 4; ++r) {
        int row = 16 * m + 4 * q + r;
        int col = (w * 4 + nl) * 16 + li;
        int g = col >> 3;
        t_h[row * 256 + ((g ^ (row & 7)) << 3) + (col & 7)] =
            (_Float16)fmaxf(acc[m][nl][r], 0.f);
      }
  __syncthreads();

  bias_init<4>(acc, b2, w, li);
  mfma_gemm64<256, 256>(t_h, BpB, acc, w, lane);
  __syncthreads();

#pragma unroll
  for (int m = 0; m < 4; ++m)
#pragma unroll
    for (int nl = 0; nl < 4; ++nl)
#pragma unroll
      for (int r = 0; r < 4; ++r) {
        int row = 16 * m + 4 * q + r;
        int col = (w * 4 + nl) * 16 + li;
        t_h[row * 256 + col] = (_Float16)fmaxf(acc[m][nl][r], 0.f);
      }
  __syncthreads();

#pragma unroll
  for (int r8 = 0; r8 < 8; ++r8) {
    int idx = tid + r8 * 256;
    int e = idx >> 5, g = idx & 31;
    int node = i0 + e;
    if (node < NN)
      *(f16x8v*)&h1h[(size_t)node * 256 + g * 8] = *(const f16x8v*)&t_h[e * 256 + g * 8];
  }
}

// ---------------------------------------------------------------------------
// MFMA node MLP 2 + fused mean-pool numerator
// ---------------------------------------------------------------------------
__global__ __launch_bounds__(256, 3) void node_mlp2_mfma(
    const _Float16* __restrict__ h1h, const float* __restrict__ aggr2,
    const _Float16* __restrict__ BpA, const float* __restrict__ b1,
    const _Float16* __restrict__ BpB, const float* __restrict__ b2,
    const int* __restrict__ batch, float* __restrict__ pool) {
  __shared__ _Float16 t_h[64 * 256];
  __shared__ int batch_s[64];
  const int tid = threadIdx.x;
  const int i0 = blockIdx.x * 64;
  const int lane = tid & 63, w = tid >> 6;
  const int q = lane >> 4, li = lane & 15;

  if (tid < 64) batch_s[tid] = (i0 + tid < NN) ? batch[i0 + tid] : -1;

#pragma unroll
  for (int r8 = 0; r8 < 8; ++r8) {
    int idx = tid + r8 * 256;
    int e = idx >> 5, g = idx & 31;
    int node = i0 + e;
    f16x8v v;
#pragma unroll
    for (int j = 0; j < 8; ++j) v[j] = (_Float16)0.f;
    if (node < NN) {
      f16x8v a = *(const f16x8v*)&h1h[(size_t)node * 256 + g * 8];
      float4 c0 = *(const float4*)&aggr2[(size_t)node * 256 + g * 8];
      float4 c1 = *(const float4*)&aggr2[(size_t)node * 256 + g * 8 + 4];
      v[0] = (_Float16)((float)a[0] + c0.x); v[1] = (_Float16)((float)a[1] + c0.y);
      v[2] = (_Float16)((float)a[2] + c0.z); v[3] = (_Float16)((float)a[3] + c0.w);
      v[4] = (_Float16)((float)a[4] + c1.x); v[5] = (_Float16)((float)a[5] + c1.y);
      v[6] = (_Float16)((float)a[6] + c1.z); v[7] = (_Float16)((float)a[7] + c1.w);
    }
    *(f16x8v*)&t_h[e * 256 + ((g ^ (e & 7)) << 3)] = v;
  }
  __syncthreads();

  f32x4v acc[4][4];
  bias_init<4>(acc, b1, w, li);
  mfma_gemm64<256, 256>(t_h, BpA, acc, w, lane);
  __syncthreads();

#pragma unroll
  for (int m = 0; m < 4; ++m)
#pragma unroll
    for (int nl = 0; nl < 4; ++nl)
#pragma unroll
      for (int r = 0; r < 4; ++r) {
        int row = 16 * m + 4 * q + r;
        int col = (w * 4 + nl) * 16 + li;
        int g = col >> 3;
        t_h[row * 256 + ((g ^ (row & 7)) << 3) + (col & 7)] =
            (_Float16)fmaxf(acc[m][nl][r], 0.f);
      }
  __syncthreads();

  bias_init<4>(acc, b2, w, li);
  mfma_gemm64<256, 256>(t_h, BpB, acc, w, lane);
  __syncthreads();

#pragma unroll
  for (int m = 0; m < 4; ++m)
#pragma unroll
    for (int nl = 0; nl < 4; ++nl)
#pragma unroll
      for (int r = 0; r < 4; ++r) {
        int row = 16 * m + 4 * q + r;
        int col = (w * 4 + nl) * 16 + li;
        t_h[row * 256 + col] = (_Float16)fmaxf(acc[m][nl][r], 0.f);
      }
  __syncthreads();

  float run = 0.f;
  int curg = -2;
  for (int m = 0; m < 64; ++m) {
    int g = batch_s[m];
    if (g != curg) {
      if (curg >= 0) atomicAdd(&pool[curg * 256 + tid], run);
      run = 0.f; curg = g;
    }
    if (g >= 0) run += (float)t_h[m * 256 + tid];
  }
  if (curg >= 0) atomicAdd(&pool[curg * 256 + tid], run);
}

// counts via binary search over sorted batch (no atomics, no contention)
__global__ __launch_bounds__(64) void count_nodes_bs(const int* __restrict__ batch,
                                                     float* __restrict__ counts) {
  int g = threadIdx.x;
  int lo = 0, hi = NN;
  while (lo < hi) { int mid = (lo + hi) >> 1; if (batch[mid] < g) lo = mid + 1; else hi = mid; }
  int start = lo;
  lo = 0; hi = NN;
  while (lo < hi) { int mid = (lo + hi) >> 1; if (batch[mid] <= g) lo = mid + 1; else hi = mid; }
  counts[g] = (float)(lo - start);
}

__global__ __launch_bounds__(128) void head_kernel(
    const float* __restrict__ pool, const float* __restrict__ counts,
    const float* __restrict__ l1w, const float* __restrict__ l1b,
    const float* __restrict__ l2w, const float* __restrict__ l2b,
    const float* __restrict__ hs_w, const float* __restrict__ hs_b,
    const float* __restrict__ hp_w, const float* __restrict__ hp_b,
    const float* __restrict__ hn_w, const float* __restrict__ hn_b,
    float* __restrict__ out) {
  const int g = blockIdx.x, tid = threadIdx.x;
  __shared__ float g_s[256], g1_s[128], g2_s[64];
  float cnt = fmaxf(counts[g], 1.0f);
  g_s[tid] = pool[g * 256 + tid] / cnt;
  g_s[tid + 128] = pool[g * 256 + tid + 128] / cnt;
  __syncthreads();
  float s = l1b[tid];
  for (int k = 0; k < 256; ++k) s = fmaf(g_s[k], l1w[k * 128 + tid], s);
  g1_s[tid] = fmaxf(s, 0.f);
  __syncthreads();
  if (tid < 64) {
    float s2 = l2b[tid];
    for (int k = 0; k < 128; ++k) s2 = fmaf(g1_s[k], l2w[k * 64 + tid], s2);
    g2_s[tid] = fmaxf(s2, 0.f);
  }
  __syncthreads();
  if (tid < 64) {
    float v = g2_s[tid];
    float a = v * hs_w[tid], b = v * hp_w[tid], c = v * hn_w[tid];
    for (int off = 32; off > 0; off >>= 1) {
      a += __shfl_down(a, off, 64);
      b += __shfl_down(b, off, 64);
      c += __shfl_down(c, off, 64);
    }
    if (tid == 0) {
      out[g]        = a + hs_b[0];
      out[64 + g]   = b + hp_b[0];
      out[128 + g]  = c + hn_b[0];
    }
  }
}

extern "C" void kernel_launch(void* const* d_in, const int* in_sizes, int n_in,
                              void* d_out, int out_size, void* d_ws, size_t ws_size,
                              hipStream_t stream) {
  (void)in_sizes; (void)n_in; (void)out_size; (void)ws_size;
  const float* x         = (const float*)d_in[0];
  const int*   eidx      = (const int*)d_in[1];
  const int*   batch     = (const int*)d_in[2];
  const float* edge_attr = (const float*)d_in[3];
  const float* ew1  = (const float*)d_in[4];
  const float* eb1  = (const float*)d_in[5];
  const float* ew2  = (const float*)d_in[6];
  const float* eb2  = (const float*)d_in[7];
  const float* le1w = (const float*)d_in[8];
  const float* le1b = (const float*)d_in[9];
  const float* le2w = (const float*)d_in[10];
  const float* le2b = (const float*)d_in[11];
  const float* n1w1 = (const float*)d_in[12];
  const float* n1b1 = (const float*)d_in[13];
  const float* n1w2 = (const float*)d_in[14];
  const float* n1b2 = (const float*)d_in[15];
  const float* n2w1 = (const float*)d_in[16];
  const float* n2b1 = (const float*)d_in[17];
  const float* n2w2 = (const float*)d_in[18];
  const float* n2b2 = (const float*)d_in[19];
  const float* l1w  = (const float*)d_in[20];
  const float* l1b  = (const float*)d_in[21];
  const float* l2w  = (const float*)d_in[22];
  const float* l2b  = (const float*)d_in[23];
  const float* hs_w = (const float*)d_in[24];
  const float* hs_b = (const float*)d_in[25];
  const float* hp_w = (const float*)d_in[26];
  const float* hp_b = (const float*)d_in[27];
  const float* hn_w = (const float*)d_in[28];
  const float* hn_b = (const float*)d_in[29];

  float* ws    = (float*)d_ws;
  float* W1c   = ws + OFF_W1C;
  float* b1c   = ws + OFF_B1C;
  float* W2c   = ws + OFF_W2C;
  float* b2c   = ws + OFF_B2C;
  float* aggr1 = ws + OFF_AGGR1;
  float* aggr2 = ws + OFF_AGGR2;
  _Float16* xh = (_Float16*)aggr2;            // alias: dead before conv2's memset
  _Float16* h1h = (_Float16*)(ws + OFF_H1H);
  float* pool  = ws + OFF_POOL;
  float* cnts  = ws + OFF_CNT;
  int*   cursor= (int*)ws + OFF_CURSOR;
  int*   rowptr= (int*)ws + OFF_ROWPTR;
  int*   perm  = (int*)ws + OFF_PERM;
  _Float16* Bp1  = (_Float16*)(ws + OFF_BP1);
  _Float16* Bp2  = (_Float16*)(ws + OFF_BP2);
  _Float16* BpN1a = (_Float16*)(ws + OFF_BN1A);
  _Float16* BpN1b = (_Float16*)(ws + OFF_BN1B);
  _Float16* BpN2a = (_Float16*)(ws + OFF_BN2A);
  _Float16* BpN2b = (_Float16*)(ws + OFF_BN2B);
  _Float16* Bpe  = (_Float16*)(ws + OFF_BPE);
  float* out   = (float*)d_out;

  hipMemsetAsync(aggr1, 0, (size_t)NN * 64 * 4, stream);
  hipMemsetAsync(pool, 0, (size_t)NG * 256 * 4, stream);
  hipMemsetAsync(cursor, 0, (size_t)NN * 4, stream);

  prep_weights<<<322, 256, 0, stream>>>(ew2, eb2, le1w, le1b, le2w, le2b, W1c, b1c, W2c, b2c);
  pack_frags<<<8, 256, 0, stream>>>(W1c, Bp1, 8, 64, 256);
  pack_frags<<<32, 256, 0, stream>>>(W2c, Bp2, 8, 256, 256);
  pack_frags<<<8, 256, 0, stream>>>(n1w1, BpN1a, 2, 256, 64);
  pack_frags<<<32, 256, 0, stream>>>(n1w2, BpN1b, 8, 256, 256);
  pack_frags<<<32, 256, 0, stream>>>(n2w1, BpN2a, 8, 256, 256);
  pack_frags<<<32, 256, 0, stream>>>(n2w2, BpN2b, 8, 256, 256);
  pack_frags<<<4, 256, 0, stream>>>(ew1, Bpe, 1, 256, 16);
  cast_xh<<<625, 256, 0, stream>>>(x, xh);
  count_nodes_bs<<<1, 64, 0, stream>>>(batch, cnts);

  count_deg<<<(NE + 255) / 256, 256, 0, stream>>>(eidx, cursor);
  scan_rowptr<<<1, 1024, 0, stream>>>(cursor, rowptr);
  scatter_perm<<<(NE + 255) / 256, 256, 0, stream>>>(eidx, cursor, perm);
  sort_segments<<<(NN + 255) / 256, 256, 0, stream>>>(rowptr, perm);

  edge_conv_mfma<64><<<NE / 64, 256, 0, stream>>>(edge_attr, eidx, perm, Bpe, eb1,
                                                  Bp1, b1c, xh, aggr1);
  node_mlp1_mfma<<<(NN + 63) / 64, 256, 0, stream>>>(x, aggr1, BpN1a, n1b1, BpN1b, n1b2, h1h);
  hipMemsetAsync(aggr2, 0, (size_t)NN * 256 * 4, stream);   // xh dead from here
  edge_conv_mfma<256><<<NE / 64, 256, 0, stream>>>(edge_attr, eidx, perm, Bpe, eb1,
                                                   Bp2, b2c, h1h, aggr2);
  node_mlp2_mfma<<<(NN + 63) / 64, 256, 0, stream>>>(h1h, aggr2, BpN2a, n2b1, BpN2b, n2b2,
                                                     batch, pool);
  head_kernel<<<NG, 128, 0, stream>>>(pool, cnts, l1w, l1b, l2w, l2b,
                                      hs_w, hs_b, hp_w, hp_b, hn_w, hn_b, out);
}

// Round 9
// 363.089 us; speedup vs baseline: 8.3904x; 1.0050x over previous
//
#include <hip/hip_runtime.h>

constexpr int NN  = 20000;   // nodes
constexpr int NE  = 320000;  // edges
constexpr int NG  = 64;      // graphs

typedef _Float16 f16x8v __attribute__((ext_vector_type(8)));
typedef float    f32x4v __attribute__((ext_vector_type(4)));

// workspace layout (in 4-byte units)
constexpr size_t OFF_B1C    = 16384;                      // 64 fp32
constexpr size_t OFF_B2C    = 81984;                      // 256 fp32
constexpr size_t OFF_AGGR1  = 82240;                      // 20000*64 fp32
constexpr size_t OFF_AGGR2  = 1362240;                    // 20000*256 fp32
constexpr size_t OFF_H1H    = 6482240;                    // 20000*256 f16
constexpr size_t OFF_BN1A   = 9042240;                    // n1w1 packed (K=64)
constexpr size_t OFF_BN1B   = 9050432;                    // n1w2 packed
constexpr size_t OFF_BN2A   = 9083200;                    // n2w1 packed
constexpr size_t OFF_BN2B   = 9115968;                    // n2w2 packed
constexpr size_t OFF_BPE    = 9148736;                    // ew1 packed (K=16 pad 32): 8192 halves
constexpr size_t OFF_XH     = 9152832;                    // x cast f16
constexpr size_t OFF_POOL   = 11602240;                   // 64*256
constexpr size_t OFF_CNT    = 11618624;                   // 64
constexpr size_t OFF_CURSOR = 11618688;                   // 20000 ints
constexpr size_t OFF_ROWPTR = 11638688;                   // 20001 ints
constexpr size_t OFF_PERM   = 11658689;                   // 320000 ints
constexpr size_t OFF_BP1    = 11978752;                   // f16 frag-packed W1c (fold)
constexpr size_t OFF_BP2    = 11986944;                   // f16 frag-packed W2c (fold)

// ---------------------------------------------------------------------------
// Shared MFMA 64-row GEMM: A = f16 LDS [64][KIN] swizzled, B = frag-packed.
// k-map on both sides: k = 32*s8 + 8*q + e.
// ---------------------------------------------------------------------------
template <int KIN, int NOUT>
__device__ __forceinline__ void mfma_gemm64(const _Float16* t_h,
                                            const _Float16* __restrict__ Bp,
                                            f32x4v (&acc)[4][NOUT / 64],
                                            int w, int lane) {
  const int q = lane >> 4, li = lane & 15;
  constexpr int KSTEPS = KIN / 32;
  constexpr int NTW = NOUT / 64;
  for (int s8 = 0; s8 < KSTEPS; ++s8) {
    f16x8v af[4];
#pragma unroll
    for (int m = 0; m < 4; ++m) {
      int r = 16 * m + li;
      int gl = 4 * s8 + q;
      af[m] = *(const f16x8v*)&t_h[r * KIN + ((gl ^ (r & 7)) << 3)];
    }
#pragma unroll
    for (int nl = 0; nl < NTW; ++nl) {
      int ng = w * NTW + nl;
      f16x8v bf = *(const f16x8v*)&Bp[(size_t)((ng * KSTEPS + s8) * 64 + lane) * 8];
#pragma unroll
      for (int m = 0; m < 4; ++m)
        acc[m][nl] = __builtin_amdgcn_mfma_f32_16x16x32_f16(af[m], bf, acc[m][nl], 0, 0, 0);
    }
  }
}

template <int NTW>
__device__ __forceinline__ void bias_init(f32x4v (&acc)[4][NTW],
                                          const float* __restrict__ b, int w, int li) {
#pragma unroll
  for (int nl = 0; nl < NTW; ++nl) {
    float bv = b[(w * NTW + nl) * 16 + li];
#pragma unroll
    for (int m = 0; m < 4; ++m) { f32x4v t = {bv, bv, bv, bv}; acc[m][nl] = t; }
  }
}

// ---------------------------------------------------------------------------
// prep_all: one kernel for the whole prep chain. Segment sizes = exact
// guarded work counts: (nout/16)*ksteps*64 items per pack.
// ---------------------------------------------------------------------------
__device__ __forceinline__ void pack_direct(const float* __restrict__ W,
                                            _Float16* __restrict__ Bp,
                                            int t, int ksteps, int nout, int kreal) {
  int lane = t & 63;
  int s = (t >> 6) % ksteps;
  int ng = t / (64 * ksteps);
  int kbase = 32 * s + 8 * (lane >> 4);
  int col = 16 * ng + (lane & 15);
  f16x8v v;
#pragma unroll
  for (int e = 0; e < 8; ++e)
    v[e] = (kbase + e < kreal) ? (_Float16)W[(size_t)(kbase + e) * nout + col]
                               : (_Float16)0.f;
  *(f16x8v*)&Bp[(size_t)t * 8] = v;
}

__device__ __forceinline__ void pack_fold(const float* __restrict__ ew2,
                                          const float* __restrict__ lew,
                                          _Float16* __restrict__ Bp,
                                          int t, int nout) {
  int lane = t & 63;
  int s = (t >> 6) & 7;                 // ksteps = 8
  int ng = t >> 9;
  int kbase = 32 * s + 8 * (lane >> 4);
  int col = 16 * ng + (lane & 15);
  f16x8v v;
#pragma unroll
  for (int e = 0; e < 8; ++e) {
    const float* wr = &ew2[(size_t)(kbase + e) * 256];
    float sacc = 0.f;
    for (int k2 = 0; k2 < 256; ++k2) sacc = fmaf(wr[k2], lew[(size_t)k2 * nout + col], sacc);
    v[e] = (_Float16)sacc;
  }
  *(f16x8v*)&Bp[(size_t)t * 8] = v;
}

// exact work counts: BP1=(64/16)*8*64=2048, BP2=(256/16)*8*64=8192,
// N1A=(256/16)*2*64=2048, N1B/N2A/N2B=8192, BPE=(256/16)*1*64=1024
constexpr int PR_XH   = 0;                 // 160000
constexpr int PR_BP1  = PR_XH + 160000;
constexpr int PR_BP2  = PR_BP1 + 2048;
constexpr int PR_N1A  = PR_BP2 + 8192;
constexpr int PR_N1B  = PR_N1A + 2048;
constexpr int PR_N2A  = PR_N1B + 8192;
constexpr int PR_N2B  = PR_N2A + 8192;
constexpr int PR_BPE  = PR_N2B + 8192;
constexpr int PR_B1C  = PR_BPE + 1024;
constexpr int PR_B2C  = PR_B1C + 64;
constexpr int PR_CNT  = PR_B2C + 256;
constexpr int PR_END  = PR_CNT + 64;

__global__ __launch_bounds__(256) void prep_all(
    const float* __restrict__ ew1, const float* __restrict__ eb1,
    const float* __restrict__ ew2, const float* __restrict__ eb2,
    const float* __restrict__ le1w, const float* __restrict__ le1b,
    const float* __restrict__ le2w, const float* __restrict__ le2b,
    const float* __restrict__ n1w1, const float* __restrict__ n1w2,
    const float* __restrict__ n2w1, const float* __restrict__ n2w2,
    const float* __restrict__ x, const int* __restrict__ batch,
    _Float16* __restrict__ Bp1, _Float16* __restrict__ Bp2,
    _Float16* __restrict__ BpN1a, _Float16* __restrict__ BpN1b,
    _Float16* __restrict__ BpN2a, _Float16* __restrict__ BpN2b,
    _Float16* __restrict__ Bpe,
    float* __restrict__ b1c, float* __restrict__ b2c,
    _Float16* __restrict__ xh, float* __restrict__ cnts) {
  int idx = blockIdx.x * 256 + threadIdx.x;
  if (idx >= PR_END) return;
  if (idx < PR_BP1) {
    int t = idx - PR_XH;
    float4 a = *(const float4*)&x[(size_t)t * 8];
    float4 b = *(const float4*)&x[(size_t)t * 8 + 4];
    f16x8v v;
    v[0] = (_Float16)a.x; v[1] = (_Float16)a.y; v[2] = (_Float16)a.z; v[3] = (_Float16)a.w;
    v[4] = (_Float16)b.x; v[5] = (_Float16)b.y; v[6] = (_Float16)b.z; v[7] = (_Float16)b.w;
    *(f16x8v*)&xh[(size_t)t * 8] = v;
  } else if (idx < PR_BP2) {
    pack_fold(ew2, le1w, Bp1, idx - PR_BP1, 64);
  } else if (idx < PR_N1A) {
    pack_fold(ew2, le2w, Bp2, idx - PR_BP2, 256);
  } else if (idx < PR_N1B) {
    pack_direct(n1w1, BpN1a, idx - PR_N1A, 2, 256, 64);
  } else if (idx < PR_N2A) {
    pack_direct(n1w2, BpN1b, idx - PR_N1B, 8, 256, 256);
  } else if (idx < PR_N2B) {
    pack_direct(n2w1, BpN2a, idx - PR_N2A, 8, 256, 256);
  } else if (idx < PR_BPE) {
    pack_direct(n2w2, BpN2b, idx - PR_N2B, 8, 256, 256);
  } else if (idx < PR_B1C) {
    pack_direct(ew1, Bpe, idx - PR_BPE, 1, 256, 16);
  } else if (idx < PR_B2C) {
    int j = idx - PR_B1C;
    float s = le1b[j];
    for (int k = 0; k < 256; ++k) s = fmaf(eb2[k], le1w[k * 64 + j], s);
    b1c[j] = s;
  } else if (idx < PR_CNT) {
    int j = idx - PR_B2C;
    float s = le2b[j];
    for (int k = 0; k < 256; ++k) s = fmaf(eb2[k], le2w[k * 256 + j], s);
    b2c[j] = s;
  } else {
    int g = idx - PR_CNT;
    int lo = 0, hi = NN;
    while (lo < hi) { int mid = (lo + hi) >> 1; if (batch[mid] < g) lo = mid + 1; else hi = mid; }
    int start = lo;
    lo = 0; hi = NN;
    while (lo < hi) { int mid = (lo + hi) >> 1; if (batch[mid] <= g) lo = mid + 1; else hi = mid; }
    cnts[g] = (float)(lo - start);
  }
}

// ----------------------- CSR build (deterministic) -------------------------
__global__ __launch_bounds__(256) void count_deg(const int* __restrict__ eidx,
                                                 int* __restrict__ deg) {
  int e = blockIdx.x * 256 + threadIdx.x;
  if (e < NE) atomicAdd(&deg[eidx[NE + e]], 1);
}

__global__ __launch_bounds__(1024) void scan_rowptr(int* __restrict__ degcur,
                                                    int* __restrict__ rowptr) {
  __shared__ int wsum[16];
  const int tid = threadIdx.x, lane = tid & 63, w = tid >> 6;
  int base = 0;
  for (int c0 = 0; c0 < NN; c0 += 1024) {
    int i = c0 + tid;
    int v = (i < NN) ? degcur[i] : 0;
    int x = v;
#pragma unroll
    for (int off = 1; off < 64; off <<= 1) {
      int y = __shfl_up(x, off, 64);
      if (lane >= off) x += y;
    }
    if (lane == 63) wsum[w] = x;
    __syncthreads();
    int woff = 0;
    for (int k = 0; k < w; ++k) woff += wsum[k];
    int tot = 0;
    for (int k = 0; k < 16; ++k) tot += wsum[k];
    if (i < NN) {
      int ex = base + woff + x - v;
      rowptr[i] = ex;
      degcur[i] = ex;
    }
    base += tot;
    __syncthreads();
  }
  if (tid == 0) rowptr[NN] = base;
}

__global__ __launch_bounds__(256) void scatter_perm(const int* __restrict__ eidx,
                                                    int* __restrict__ cursor,
                                                    int* __restrict__ perm) {
  int e = blockIdx.x * 256 + threadIdx.x;
  if (e < NE) {
    int d = eidx[NE + e];
    int slot = atomicAdd(&cursor[d], 1);
    perm[slot] = e;
  }
}

__global__ __launch_bounds__(256) void sort_segments(const int* __restrict__ rowptr,
                                                     int* __restrict__ perm) {
  int n = blockIdx.x * 256 + threadIdx.x;
  if (n < NN) {
    int s = rowptr[n], t = rowptr[n + 1];
    for (int i = s + 1; i < t; ++i) {
      int key = perm[i], j = i - 1;
      while (j >= s && perm[j] > key) { perm[j + 1] = perm[j]; --j; }
      perm[j + 1] = key;
    }
  }
}

// ---------------------------------------------------------------------------
// MFMA edge conv, dst-sorted, sigma row permutation; MFMA t-phase (K=16 pad 32)
// ---------------------------------------------------------------------------
template <int NOUT>
__global__ __launch_bounds__(256, 4) void edge_conv_mfma(
    const float* __restrict__ edge_attr, const int* __restrict__ eidx,
    const int* __restrict__ perm,
    const _Float16* __restrict__ Bpe, const float* __restrict__ eb1,
    const _Float16* __restrict__ Bp, const float* __restrict__ bc,
    const _Float16* __restrict__ gat, float* __restrict__ aggr) {
  constexpr int NTW = NOUT / 64;
  constexpr int NG8 = NOUT / 8;
  __shared__ _Float16 ea_h[64 * 40];
  __shared__ _Float16 t_h[64 * 256];
  __shared__ int perm_s[64], src_s[64], dst_s[64];
  const int tid = threadIdx.x;
  const int e0 = blockIdx.x * 64;
  const int lane = tid & 63, w = tid >> 6;
  const int q = lane >> 4, li = lane & 15;

  if (tid < 64) {
    int p = perm[e0 + tid];
    perm_s[tid] = p;
    src_s[tid] = eidx[p];
    dst_s[tid] = eidx[NE + p];
  }
  __syncthreads();
  {
    int e2 = (tid & 127) >> 1, gq = tid & 1;
    if (tid < 128) {
      const float* src = &edge_attr[(size_t)perm_s[e2] * 16 + gq * 8];
      float4 a = *(const float4*)src;
      float4 b = *(const float4*)(src + 4);
      f16x8v v;
      v[0] = (_Float16)a.x; v[1] = (_Float16)a.y; v[2] = (_Float16)a.z; v[3] = (_Float16)a.w;
      v[4] = (_Float16)b.x; v[5] = (_Float16)b.y; v[6] = (_Float16)b.z; v[7] = (_Float16)b.w;
      *(f16x8v*)&ea_h[e2 * 40 + gq * 8] = v;
    } else {
      f16x8v z = {};
      *(f16x8v*)&ea_h[e2 * 40 + 16 + gq * 8] = z;   // zero pad k=16..31
    }
  }

  f32x4v acct[4][4];
  bias_init<4>(acct, eb1, w, li);
  __syncthreads();
  {
    f16x8v afe[4];
#pragma unroll
    for (int m = 0; m < 4; ++m)
      afe[m] = *(const f16x8v*)&ea_h[(16 * m + li) * 40 + 8 * q];
#pragma unroll
    for (int nl = 0; nl < 4; ++nl) {
      f16x8v bf = *(const f16x8v*)&Bpe[(size_t)((w * 4 + nl) * 64 + lane) * 8];
#pragma unroll
      for (int m = 0; m < 4; ++m)
        acct[m][nl] = __builtin_amdgcn_mfma_f32_16x16x32_f16(afe[m], bf, acct[m][nl], 0, 0, 0);
    }
#pragma unroll
    for (int m = 0; m < 4; ++m)
#pragma unroll
      for (int nl = 0; nl < 4; ++nl)
#pragma unroll
        for (int r = 0; r < 4; ++r) {
          int E = 16 * m + 4 * q + r;                                   // edge = D row
          int p = (((E >> 2) & 3) << 4) | ((E >> 4) << 2) | (E & 3);    // sigma(E)
          int col = (w * 4 + nl) * 16 + li;
          int g = col >> 3;
          t_h[p * 256 + ((g ^ (p & 7)) << 3) + (col & 7)] =
              (_Float16)fmaxf(acct[m][nl][r], 0.f);
        }
  }

  f32x4v acc[4][NTW];
  bias_init<NTW>(acc, bc, w, li);
  __syncthreads();

  for (int s8 = 0; s8 < 8; ++s8) {
    f16x8v af[4];
#pragma unroll
    for (int m = 0; m < 4; ++m) {
      int r = 16 * m + li;
      int gl = 4 * s8 + q;
      af[m] = *(const f16x8v*)&t_h[r * 256 + ((gl ^ (r & 7)) << 3)];
    }
#pragma unroll
    for (int nl = 0; nl < NTW; ++nl) {
      int ng = w * NTW + nl;
      f16x8v bf = *(const f16x8v*)&Bp[(size_t)((ng * 8 + s8) * 64 + lane) * 8];
#pragma unroll
      for (int m = 0; m < 4; ++m)
        acc[m][nl] = __builtin_amdgcn_mfma_f32_16x16x32_f16(af[m], bf, acc[m][nl], 0, 0, 0);
    }
  }
  __syncthreads();

  for (int c = tid; c < 64 * NG8; c += 256) {
    int e = c / NG8, g = c % NG8;
    f16x8v v = *(const f16x8v*)&gat[(size_t)src_s[e] * NOUT + g * 8];
    int pg = (g & ~7) | ((g + 2 * (e >> 4)) & 7);
    *(f16x8v*)&t_h[e * NOUT + pg * 8] = v;
  }
  __syncthreads();

#pragma unroll
  for (int nl = 0; nl < NTW; ++nl) {
    const int col = (w * NTW + nl) * 16 + li;
    const int gl2 = col >> 3;
    const int pg = (gl2 & ~7) | ((gl2 + 2 * q) & 7);
    const int loff = pg * 8 + (col & 7);
    float run = 0.f;
    int cur = dst_s[16 * q];
#pragma unroll
    for (int m = 0; m < 4; ++m) {
#pragma unroll
      for (int r = 0; r < 4; ++r) {
        int e = 16 * q + 4 * m + r;
        int d = dst_s[e];
        if (d != cur) {
          atomicAdd(&aggr[(size_t)cur * NOUT + col], run);
          run = 0.f; cur = d;
        }
        float xv = (float)t_h[e * NOUT + loff];
        run += fmaxf(xv + acc[m][nl][r], 0.f);
      }
    }
    atomicAdd(&aggr[(size_t)cur * NOUT + col], run);
  }
}

// ---------------------------------------------------------------------------
// MFMA node MLP 1
// ---------------------------------------------------------------------------
__global__ __launch_bounds__(256, 3) void node_mlp1_mfma(
    const float* __restrict__ x, const float* __restrict__ aggr1,
    const _Float16* __restrict__ BpA, const float* __restrict__ b1,
    const _Float16* __restrict__ BpB, const float* __restrict__ b2,
    _Float16* __restrict__ h1h) {
  __shared__ _Float16 t_h[64 * 256];
  const int tid = threadIdx.x;
  const int i0 = blockIdx.x * 64;
  const int lane = tid & 63, w = tid >> 6;
  const int q = lane >> 4, li = lane & 15;

#pragma unroll
  for (int r2 = 0; r2 < 2; ++r2) {
    int idx = tid + r2 * 256;
    int e = idx >> 3, g = idx & 7;
    int node = i0 + e;
    f16x8v v;
#pragma unroll
    for (int j = 0; j < 8; ++j) v[j] = (_Float16)0.f;
    if (node < NN) {
      float4 a0 = *(const float4*)&x[(size_t)node * 64 + g * 8];
      float4 a1 = *(const float4*)&x[(size_t)node * 64 + g * 8 + 4];
      float4 c0 = *(const float4*)&aggr1[(size_t)node * 64 + g * 8];
      float4 c1 = *(const float4*)&aggr1[(size_t)node * 64 + g * 8 + 4];
      v[0] = (_Float16)(a0.x + c0.x); v[1] = (_Float16)(a0.y + c0.y);
      v[2] = (_Float16)(a0.z + c0.z); v[3] = (_Float16)(a0.w + c0.w);
      v[4] = (_Float16)(a1.x + c1.x); v[5] = (_Float16)(a1.y + c1.y);
      v[6] = (_Float16)(a1.z + c1.z); v[7] = (_Float16)(a1.w + c1.w);
    }
    *(f16x8v*)&t_h[e * 64 + ((g ^ (e & 7)) << 3)] = v;
  }
  __syncthreads();

  f32x4v acc[4][4];
  bias_init<4>(acc, b1, w, li);
  mfma_gemm64<64, 256>(t_h, BpA, acc, w, lane);
  __syncthreads();

#pragma unroll
  for (int m = 0; m < 4; ++m)
#pragma unroll
    for (int nl = 0; nl < 4; ++nl)
#pragma unroll
      for (int r = 0; r < 4; ++r) {
        int row = 16 * m + 4 * q + r;
        int col = (w * 4 + nl) * 16 + li;
        int g = col >> 3;
        t_h[row * 256 + ((g ^ (row & 7)) << 3) + (col & 7)] =
            (_Float16)fmaxf(acc[m][nl][r], 0.f);
      }
  __syncthreads();

  bias_init<4>(acc, b2, w, li);
  mfma_gemm64<256, 256>(t_h, BpB, acc, w, lane);
  __syncthreads();

#pragma unroll
  for (int m = 0; m < 4; ++m)
#pragma unroll
    for (int nl = 0; nl < 4; ++nl)
#pragma unroll
      for (int r = 0; r < 4; ++r) {
        int row = 16 * m + 4 * q + r;
        int col = (w * 4 + nl) * 16 + li;
        t_h[row * 256 + col] = (_Float16)fmaxf(acc[m][nl][r], 0.f);
      }
  __syncthreads();

#pragma unroll
  for (int r8 = 0; r8 < 8; ++r8) {
    int idx = tid + r8 * 256;
    int e = idx >> 5, g = idx & 31;
    int node = i0 + e;
    if (node < NN)
      *(f16x8v*)&h1h[(size_t)node * 256 + g * 8] = *(const f16x8v*)&t_h[e * 256 + g * 8];
  }
}

// ---------------------------------------------------------------------------
// MFMA node MLP 2 + fused mean-pool numerator
// ---------------------------------------------------------------------------
__global__ __launch_bounds__(256, 3) void node_mlp2_mfma(
    const _Float16* __restrict__ h1h, const float* __restrict__ aggr2,
    const _Float16* __restrict__ BpA, const float* __restrict__ b1,
    const _Float16* __restrict__ BpB, const float* __restrict__ b2,
    const int* __restrict__ batch, float* __restrict__ pool) {
  __shared__ _Float16 t_h[64 * 256];
  __shared__ int batch_s[64];
  const int tid = threadIdx.x;
  const int i0 = blockIdx.x * 64;
  const int lane = tid & 63, w = tid >> 6;
  const int q = lane >> 4, li = lane & 15;

  if (tid < 64) batch_s[tid] = (i0 + tid < NN) ? batch[i0 + tid] : -1;

#pragma unroll
  for (int r8 = 0; r8 < 8; ++r8) {
    int idx = tid + r8 * 256;
    int e = idx >> 5, g = idx & 31;
    int node = i0 + e;
    f16x8v v;
#pragma unroll
    for (int j = 0; j < 8; ++j) v[j] = (_Float16)0.f;
    if (node < NN) {
      f16x8v a = *(const f16x8v*)&h1h[(size_t)node * 256 + g * 8];
      float4 c0 = *(const float4*)&aggr2[(size_t)node * 256 + g * 8];
      float4 c1 = *(const float4*)&aggr2[(size_t)node * 256 + g * 8 + 4];
      v[0] = (_Float16)((float)a[0] + c0.x); v[1] = (_Float16)((float)a[1] + c0.y);
      v[2] = (_Float16)((float)a[2] + c0.z); v[3] = (_Float16)((float)a[3] + c0.w);
      v[4] = (_Float16)((float)a[4] + c1.x); v[5] = (_Float16)((float)a[5] + c1.y);
      v[6] = (_Float16)((float)a[6] + c1.z); v[7] = (_Float16)((float)a[7] + c1.w);
    }
    *(f16x8v*)&t_h[e * 256 + ((g ^ (e & 7)) << 3)] = v;
  }
  __syncthreads();

  f32x4v acc[4][4];
  bias_init<4>(acc, b1, w, li);
  mfma_gemm64<256, 256>(t_h, BpA, acc, w, lane);
  __syncthreads();

#pragma unroll
  for (int m = 0; m < 4; ++m)
#pragma unroll
    for (int nl = 0; nl < 4; ++nl)
#pragma unroll
      for (int r = 0; r < 4; ++r) {
        int row = 16 * m + 4 * q + r;
        int col = (w * 4 + nl) * 16 + li;
        int g = col >> 3;
        t_h[row * 256 + ((g ^ (row & 7)) << 3) + (col & 7)] =
            (_Float16)fmaxf(acc[m][nl][r], 0.f);
      }
  __syncthreads();

  bias_init<4>(acc, b2, w, li);
  mfma_gemm64<256, 256>(t_h, BpB, acc, w, lane);
  __syncthreads();

#pragma unroll
  for (int m = 0; m < 4; ++m)
#pragma unroll
    for (int nl = 0; nl < 4; ++nl)
#pragma unroll
      for (int r = 0; r < 4; ++r) {
        int row = 16 * m + 4 * q + r;
        int col = (w * 4 + nl) * 16 + li;
        t_h[row * 256 + col] = (_Float16)fmaxf(acc[m][nl][r], 0.f);
      }
  __syncthreads();

  float run = 0.f;
  int curg = -2;
  for (int m = 0; m < 64; ++m) {
    int g = batch_s[m];
    if (g != curg) {
      if (curg >= 0) atomicAdd(&pool[curg * 256 + tid], run);
      run = 0.f; curg = g;
    }
    if (g >= 0) run += (float)t_h[m * 256 + tid];
  }
  if (curg >= 0) atomicAdd(&pool[curg * 256 + tid], run);
}

__global__ __launch_bounds__(128) void head_kernel(
    const float* __restrict__ pool, const float* __restrict__ counts,
    const float* __restrict__ l1w, const float* __restrict__ l1b,
    const float* __restrict__ l2w, const float* __restrict__ l2b,
    const float* __restrict__ hs_w, const float* __restrict__ hs_b,
    const float* __restrict__ hp_w, const float* __restrict__ hp_b,
    const float* __restrict__ hn_w, const float* __restrict__ hn_b,
    float* __restrict__ out) {
  const int g = blockIdx.x, tid = threadIdx.x;
  __shared__ float g_s[256], g1_s[128], g2_s[64];
  float cnt = fmaxf(counts[g], 1.0f);
  g_s[tid] = pool[g * 256 + tid] / cnt;
  g_s[tid + 128] = pool[g * 256 + tid + 128] / cnt;
  __syncthreads();
  float s = l1b[tid];
  for (int k = 0; k < 256; ++k) s = fmaf(g_s[k], l1w[k * 128 + tid], s);
  g1_s[tid] = fmaxf(s, 0.f);
  __syncthreads();
  if (tid < 64) {
    float s2 = l2b[tid];
    for (int k = 0; k < 128; ++k) s2 = fmaf(g1_s[k], l2w[k * 64 + tid], s2);
    g2_s[tid] = fmaxf(s2, 0.f);
  }
  __syncthreads();
  if (tid < 64) {
    float v = g2_s[tid];
    float a = v * hs_w[tid], b = v * hp_w[tid], c = v * hn_w[tid];
    for (int off = 32; off > 0; off >>= 1) {
      a += __shfl_down(a, off, 64);
      b += __shfl_down(b, off, 64);
      c += __shfl_down(c, off, 64);
    }
    if (tid == 0) {
      out[g]        = a + hs_b[0];
      out[64 + g]   = b + hp_b[0];
      out[128 + g]  = c + hn_b[0];
    }
  }
}

extern "C" void kernel_launch(void* const* d_in, const int* in_sizes, int n_in,
                              void* d_out, int out_size, void* d_ws, size_t ws_size,
                              hipStream_t stream) {
  (void)in_sizes; (void)n_in; (void)out_size; (void)ws_size;
  const float* x         = (const float*)d_in[0];
  const int*   eidx      = (const int*)d_in[1];
  const int*   batch     = (const int*)d_in[2];
  const float* edge_attr = (const float*)d_in[3];
  const float* ew1  = (const float*)d_in[4];
  const float* eb1  = (const float*)d_in[5];
  const float* ew2  = (const float*)d_in[6];
  const float* eb2  = (const float*)d_in[7];
  const float* le1w = (const float*)d_in[8];
  const float* le1b = (const float*)d_in[9];
  const float* le2w = (const float*)d_in[10];
  const float* le2b = (const float*)d_in[11];
  const float* n1w1 = (const float*)d_in[12];
  const float* n1b1 = (const float*)d_in[13];
  const float* n1w2 = (const float*)d_in[14];
  const float* n1b2 = (const float*)d_in[15];
  const float* n2w1 = (const float*)d_in[16];
  const float* n2b1 = (const float*)d_in[17];
  const float* n2w2 = (const float*)d_in[18];
  const float* n2b2 = (const float*)d_in[19];
  const float* l1w  = (const float*)d_in[20];
  const float* l1b  = (const float*)d_in[21];
  const float* l2w  = (const float*)d_in[22];
  const float* l2b  = (const float*)d_in[23];
  const float* hs_w = (const float*)d_in[24];
  const float* hs_b = (const float*)d_in[25];
  const float* hp_w = (const float*)d_in[26];
  const float* hp_b = (const float*)d_in[27];
  const float* hn_w = (const float*)d_in[28];
  const float* hn_b = (const float*)d_in[29];

  float* ws    = (float*)d_ws;
  float* b1c   = ws + OFF_B1C;
  float* b2c   = ws + OFF_B2C;
  float* aggr1 = ws + OFF_AGGR1;
  float* aggr2 = ws + OFF_AGGR2;
  _Float16* h1h = (_Float16*)(ws + OFF_H1H);
  _Float16* xh  = (_Float16*)(ws + OFF_XH);
  float* pool  = ws + OFF_POOL;
  float* cnts  = ws + OFF_CNT;
  int*   cursor= (int*)ws + OFF_CURSOR;
  int*   rowptr= (int*)ws + OFF_ROWPTR;
  int*   perm  = (int*)ws + OFF_PERM;
  _Float16* Bp1  = (_Float16*)(ws + OFF_BP1);
  _Float16* Bp2  = (_Float16*)(ws + OFF_BP2);
  _Float16* BpN1a = (_Float16*)(ws + OFF_BN1A);
  _Float16* BpN1b = (_Float16*)(ws + OFF_BN1B);
  _Float16* BpN2a = (_Float16*)(ws + OFF_BN2A);
  _Float16* BpN2b = (_Float16*)(ws + OFF_BN2B);
  _Float16* Bpe  = (_Float16*)(ws + OFF_BPE);
  float* out   = (float*)d_out;

  hipMemsetAsync(aggr1, 0, (size_t)NN * 64 * 4, stream);
  hipMemsetAsync(aggr2, 0, (size_t)NN * 256 * 4, stream);
  hipMemsetAsync(pool, 0, (size_t)NG * 256 * 4, stream);
  hipMemsetAsync(cursor, 0, (size_t)NN * 4, stream);

  prep_all<<<(PR_END + 255) / 256, 256, 0, stream>>>(
      ew1, eb1, ew2, eb2, le1w, le1b, le2w, le2b,
      n1w1, n1w2, n2w1, n2w2, x, batch,
      Bp1, Bp2, BpN1a, BpN1b, BpN2a, BpN2b, Bpe, b1c, b2c, xh, cnts);

  count_deg<<<(NE + 255) / 256, 256, 0, stream>>>(eidx, cursor);
  scan_rowptr<<<1, 1024, 0, stream>>>(cursor, rowptr);
  scatter_perm<<<(NE + 255) / 256, 256, 0, stream>>>(eidx, cursor, perm);
  sort_segments<<<(NN + 255) / 256, 256, 0, stream>>>(rowptr, perm);

  edge_conv_mfma<64><<<NE / 64, 256, 0, stream>>>(edge_attr, eidx, perm, Bpe, eb1,
                                                  Bp1, b1c, xh, aggr1);
  node_mlp1_mfma<<<(NN + 63) / 64, 256, 0, stream>>>(x, aggr1, BpN1a, n1b1, BpN1b, n1b2, h1h);
  edge_conv_mfma<256><<<NE / 64, 256, 0, stream>>>(edge_attr, eidx, perm, Bpe, eb1,
                                                   Bp2, b2c, h1h, aggr2);
  node_mlp2_mfma<<<(NN + 63) / 64, 256, 0, stream>>>(h1h, aggr2, BpN2a, n2b1, BpN2b, n2b2,
                                                     batch, pool);
  head_kernel<<<NG, 128, 0, stream>>>(pool, cnts, l1w, l1b, l2w, l2b,
                                      hs_w, hs_b, hp_w, hp_b, hn_w, hn_b, out);
}

// Round 10
// 306.853 us; speedup vs baseline: 9.9281x; 1.1833x over previous
//
#include <hip/hip_runtime.h>

constexpr int NN  = 20000;   // nodes
constexpr int NE  = 320000;  // edges
constexpr int NG  = 64;      // graphs

typedef _Float16 f16x8v __attribute__((ext_vector_type(8)));
typedef float    f32x4v __attribute__((ext_vector_type(4)));

// workspace layout (in 4-byte units)
constexpr size_t OFF_B1C    = 16384;                      // 64 fp32
constexpr size_t OFF_B2C    = 81984;                      // 256 fp32
constexpr size_t OFF_AGGR1  = 82240;                      // 20000*64 fp32
constexpr size_t OFF_AGGR2  = 1362240;                    // 20000*256 fp32
constexpr size_t OFF_H1H    = 6482240;                    // 20000*256 f16
constexpr size_t OFF_BN1A   = 9042240;                    // n1w1 packed (K=64)
constexpr size_t OFF_BN1B   = 9050432;                    // n1w2 packed
constexpr size_t OFF_BN2A   = 9083200;                    // n2w1 packed
constexpr size_t OFF_BN2B   = 9115968;                    // n2w2 packed
constexpr size_t OFF_BPE    = 9148736;                    // ew1 packed (K=16 pad 32)
constexpr size_t OFF_XH     = 9152832;                    // x cast f16
constexpr size_t OFF_POOL   = 11602240;                   // 64*256
constexpr size_t OFF_CNT    = 11618624;                   // 64
constexpr size_t OFF_CURSOR = 11618688;                   // 20000 ints
constexpr size_t OFF_ROWPTR = 11638688;                   // 20001 ints
constexpr size_t OFF_PERM   = 11658689;                   // 320000 ints
constexpr size_t OFF_BP1    = 11978752;                   // f16 frag-packed W1c (fold)
constexpr size_t OFF_BP2    = 11986944;                   // f16 frag-packed W2c (fold)

// ---------------------------------------------------------------------------
// Shared MFMA 64-row GEMM: A = f16 LDS [64][KIN] swizzled, B = frag-packed.
// k-map on both sides: k = 32*s8 + 8*q + e.
// ---------------------------------------------------------------------------
template <int KIN, int NOUT>
__device__ __forceinline__ void mfma_gemm64(const _Float16* t_h,
                                            const _Float16* __restrict__ Bp,
                                            f32x4v (&acc)[4][NOUT / 64],
                                            int w, int lane) {
  const int q = lane >> 4, li = lane & 15;
  constexpr int KSTEPS = KIN / 32;
  constexpr int NTW = NOUT / 64;
  for (int s8 = 0; s8 < KSTEPS; ++s8) {
    f16x8v af[4];
#pragma unroll
    for (int m = 0; m < 4; ++m) {
      int r = 16 * m + li;
      int gl = 4 * s8 + q;
      af[m] = *(const f16x8v*)&t_h[r * KIN + ((gl ^ (r & 7)) << 3)];
    }
#pragma unroll
    for (int nl = 0; nl < NTW; ++nl) {
      int ng = w * NTW + nl;
      f16x8v bf = *(const f16x8v*)&Bp[(size_t)((ng * KSTEPS + s8) * 64 + lane) * 8];
#pragma unroll
      for (int m = 0; m < 4; ++m)
        acc[m][nl] = __builtin_amdgcn_mfma_f32_16x16x32_f16(af[m], bf, acc[m][nl], 0, 0, 0);
    }
  }
}

template <int NTW>
__device__ __forceinline__ void bias_init(f32x4v (&acc)[4][NTW],
                                          const float* __restrict__ b, int w, int li) {
#pragma unroll
  for (int nl = 0; nl < NTW; ++nl) {
    float bv = b[(w * NTW + nl) * 16 + li];
#pragma unroll
    for (int m = 0; m < 4; ++m) { f32x4v t = {bv, bv, bv, bv}; acc[m][nl] = t; }
  }
}

// ---------------------------------------------------------------------------
// prep_all: whole prep chain + degree count in one kernel.
// Segment sizes = exact guarded work counts ((nout/16)*ksteps*64 per pack).
// ---------------------------------------------------------------------------
__device__ __forceinline__ void pack_direct(const float* __restrict__ W,
                                            _Float16* __restrict__ Bp,
                                            int t, int ksteps, int nout, int kreal) {
  int lane = t & 63;
  int s = (t >> 6) % ksteps;
  int ng = t / (64 * ksteps);
  int kbase = 32 * s + 8 * (lane >> 4);
  int col = 16 * ng + (lane & 15);
  f16x8v v;
#pragma unroll
  for (int e = 0; e < 8; ++e)
    v[e] = (kbase + e < kreal) ? (_Float16)W[(size_t)(kbase + e) * nout + col]
                               : (_Float16)0.f;
  *(f16x8v*)&Bp[(size_t)t * 8] = v;
}

__device__ __forceinline__ void pack_fold(const float* __restrict__ ew2,
                                          const float* __restrict__ lew,
                                          _Float16* __restrict__ Bp,
                                          int t, int nout) {
  int lane = t & 63;
  int s = (t >> 6) & 7;                 // ksteps = 8
  int ng = t >> 9;
  int kbase = 32 * s + 8 * (lane >> 4);
  int col = 16 * ng + (lane & 15);
  f16x8v v;
#pragma unroll
  for (int e = 0; e < 8; ++e) {
    const float* wr = &ew2[(size_t)(kbase + e) * 256];
    float sacc = 0.f;
    for (int k2 = 0; k2 < 256; ++k2) sacc = fmaf(wr[k2], lew[(size_t)k2 * nout + col], sacc);
    v[e] = (_Float16)sacc;
  }
  *(f16x8v*)&Bp[(size_t)t * 8] = v;
}

constexpr int PR_XH   = 0;                 // 160000
constexpr int PR_BP1  = PR_XH + 160000;
constexpr int PR_BP2  = PR_BP1 + 2048;
constexpr int PR_N1A  = PR_BP2 + 8192;
constexpr int PR_N1B  = PR_N1A + 2048;
constexpr int PR_N2A  = PR_N1B + 8192;
constexpr int PR_N2B  = PR_N2A + 8192;
constexpr int PR_BPE  = PR_N2B + 8192;
constexpr int PR_B1C  = PR_BPE + 1024;
constexpr int PR_B2C  = PR_B1C + 64;
constexpr int PR_CNT  = PR_B2C + 256;
constexpr int PR_DEG  = PR_CNT + 64;
constexpr int PR_END  = PR_DEG + NE;       // degree count folded in

__global__ __launch_bounds__(256) void prep_all(
    const float* __restrict__ ew1, const float* __restrict__ eb1,
    const float* __restrict__ ew2, const float* __restrict__ eb2,
    const float* __restrict__ le1w, const float* __restrict__ le1b,
    const float* __restrict__ le2w, const float* __restrict__ le2b,
    const float* __restrict__ n1w1, const float* __restrict__ n1w2,
    const float* __restrict__ n2w1, const float* __restrict__ n2w2,
    const float* __restrict__ x, const int* __restrict__ batch,
    const int* __restrict__ eidx,
    _Float16* __restrict__ Bp1, _Float16* __restrict__ Bp2,
    _Float16* __restrict__ BpN1a, _Float16* __restrict__ BpN1b,
    _Float16* __restrict__ BpN2a, _Float16* __restrict__ BpN2b,
    _Float16* __restrict__ Bpe,
    float* __restrict__ b1c, float* __restrict__ b2c,
    _Float16* __restrict__ xh, float* __restrict__ cnts,
    int* __restrict__ deg) {
  int idx = blockIdx.x * 256 + threadIdx.x;
  if (idx >= PR_END) return;
  if (idx >= PR_DEG) {
    int e = idx - PR_DEG;
    atomicAdd(&deg[eidx[NE + e]], 1);
  } else if (idx < PR_BP1) {
    int t = idx - PR_XH;
    float4 a = *(const float4*)&x[(size_t)t * 8];
    float4 b = *(const float4*)&x[(size_t)t * 8 + 4];
    f16x8v v;
    v[0] = (_Float16)a.x; v[1] = (_Float16)a.y; v[2] = (_Float16)a.z; v[3] = (_Float16)a.w;
    v[4] = (_Float16)b.x; v[5] = (_Float16)b.y; v[6] = (_Float16)b.z; v[7] = (_Float16)b.w;
    *(f16x8v*)&xh[(size_t)t * 8] = v;
  } else if (idx < PR_BP2) {
    pack_fold(ew2, le1w, Bp1, idx - PR_BP1, 64);
  } else if (idx < PR_N1A) {
    pack_fold(ew2, le2w, Bp2, idx - PR_BP2, 256);
  } else if (idx < PR_N1B) {
    pack_direct(n1w1, BpN1a, idx - PR_N1A, 2, 256, 64);
  } else if (idx < PR_N2A) {
    pack_direct(n1w2, BpN1b, idx - PR_N1B, 8, 256, 256);
  } else if (idx < PR_N2B) {
    pack_direct(n2w1, BpN2a, idx - PR_N2A, 8, 256, 256);
  } else if (idx < PR_BPE) {
    pack_direct(n2w2, BpN2b, idx - PR_N2B, 8, 256, 256);
  } else if (idx < PR_B1C) {
    pack_direct(ew1, Bpe, idx - PR_BPE, 1, 256, 16);
  } else if (idx < PR_B2C) {
    int j = idx - PR_B1C;
    float s = le1b[j];
    for (int k = 0; k < 256; ++k) s = fmaf(eb2[k], le1w[k * 64 + j], s);
    b1c[j] = s;
  } else if (idx < PR_CNT) {
    int j = idx - PR_B2C;
    float s = le2b[j];
    for (int k = 0; k < 256; ++k) s = fmaf(eb2[k], le2w[k * 256 + j], s);
    b2c[j] = s;
  } else {
    int g = idx - PR_CNT;
    int lo = 0, hi = NN;
    while (lo < hi) { int mid = (lo + hi) >> 1; if (batch[mid] < g) lo = mid + 1; else hi = mid; }
    int start = lo;
    lo = 0; hi = NN;
    while (lo < hi) { int mid = (lo + hi) >> 1; if (batch[mid] <= g) lo = mid + 1; else hi = mid; }
    cnts[g] = (float)(lo - start);
  }
}

// ----------------------- CSR build -------------------------
// NOTE: no per-segment sort. Slot order within a dst segment is atomic-order
// nondeterministic; this only reorders fp addends per (dst,col) — same class
// of reorder the cross-block fp atomics already introduce. Segments stay
// contiguous, so the epilogue's run-merge is unaffected.
__global__ __launch_bounds__(1024) void scan_rowptr(int* __restrict__ degcur,
                                                    int* __restrict__ rowptr) {
  __shared__ int wsum[16];
  const int tid = threadIdx.x, lane = tid & 63, w = tid >> 6;
  int base = 0;
  for (int c0 = 0; c0 < NN; c0 += 1024) {
    int i = c0 + tid;
    int v = (i < NN) ? degcur[i] : 0;
    int x = v;
#pragma unroll
    for (int off = 1; off < 64; off <<= 1) {
      int y = __shfl_up(x, off, 64);
      if (lane >= off) x += y;
    }
    if (lane == 63) wsum[w] = x;
    __syncthreads();
    int woff = 0;
    for (int k = 0; k < w; ++k) woff += wsum[k];
    int tot = 0;
    for (int k = 0; k < 16; ++k) tot += wsum[k];
    if (i < NN) {
      int ex = base + woff + x - v;
      rowptr[i] = ex;
      degcur[i] = ex;
    }
    base += tot;
    __syncthreads();
  }
  if (tid == 0) rowptr[NN] = base;
}

__global__ __launch_bounds__(256) void scatter_perm(const int* __restrict__ eidx,
                                                    int* __restrict__ cursor,
                                                    int* __restrict__ perm) {
  int e = blockIdx.x * 256 + threadIdx.x;
  if (e < NE) {
    int d = eidx[NE + e];
    int slot = atomicAdd(&cursor[d], 1);
    perm[slot] = e;
  }
}

// ---------------------------------------------------------------------------
// MFMA edge conv, dst-sorted, sigma row permutation; MFMA t-phase (K=16 pad 32)
// ---------------------------------------------------------------------------
template <int NOUT>
__global__ __launch_bounds__(256, 4) void edge_conv_mfma(
    const float* __restrict__ edge_attr, const int* __restrict__ eidx,
    const int* __restrict__ perm,
    const _Float16* __restrict__ Bpe, const float* __restrict__ eb1,
    const _Float16* __restrict__ Bp, const float* __restrict__ bc,
    const _Float16* __restrict__ gat, float* __restrict__ aggr) {
  constexpr int NTW = NOUT / 64;
  constexpr int NG8 = NOUT / 8;
  __shared__ _Float16 ea_h[64 * 40];
  __shared__ _Float16 t_h[64 * 256];
  __shared__ int perm_s[64], src_s[64], dst_s[64];
  const int tid = threadIdx.x;
  const int e0 = blockIdx.x * 64;
  const int lane = tid & 63, w = tid >> 6;
  const int q = lane >> 4, li = lane & 15;

  if (tid < 64) {
    int p = perm[e0 + tid];
    perm_s[tid] = p;
    src_s[tid] = eidx[p];
    dst_s[tid] = eidx[NE + p];
  }
  __syncthreads();
  {
    int e2 = (tid & 127) >> 1, gq = tid & 1;
    if (tid < 128) {
      const float* src = &edge_attr[(size_t)perm_s[e2] * 16 + gq * 8];
      float4 a = *(const float4*)src;
      float4 b = *(const float4*)(src + 4);
      f16x8v v;
      v[0] = (_Float16)a.x; v[1] = (_Float16)a.y; v[2] = (_Float16)a.z; v[3] = (_Float16)a.w;
      v[4] = (_Float16)b.x; v[5] = (_Float16)b.y; v[6] = (_Float16)b.z; v[7] = (_Float16)b.w;
      *(f16x8v*)&ea_h[e2 * 40 + gq * 8] = v;
    } else {
      f16x8v z = {};
      *(f16x8v*)&ea_h[e2 * 40 + 16 + gq * 8] = z;   // zero pad k=16..31
    }
  }

  f32x4v acct[4][4];
  bias_init<4>(acct, eb1, w, li);
  __syncthreads();
  {
    f16x8v afe[4];
#pragma unroll
    for (int m = 0; m < 4; ++m)
      afe[m] = *(const f16x8v*)&ea_h[(16 * m + li) * 40 + 8 * q];
#pragma unroll
    for (int nl = 0; nl < 4; ++nl) {
      f16x8v bf = *(const f16x8v*)&Bpe[(size_t)((w * 4 + nl) * 64 + lane) * 8];
#pragma unroll
      for (int m = 0; m < 4; ++m)
        acct[m][nl] = __builtin_amdgcn_mfma_f32_16x16x32_f16(afe[m], bf, acct[m][nl], 0, 0, 0);
    }
#pragma unroll
    for (int m = 0; m < 4; ++m)
#pragma unroll
      for (int nl = 0; nl < 4; ++nl)
#pragma unroll
        for (int r = 0; r < 4; ++r) {
          int E = 16 * m + 4 * q + r;                                   // edge = D row
          int p = (((E >> 2) & 3) << 4) | ((E >> 4) << 2) | (E & 3);    // sigma(E)
          int col = (w * 4 + nl) * 16 + li;
          int g = col >> 3;
          t_h[p * 256 + ((g ^ (p & 7)) << 3) + (col & 7)] =
              (_Float16)fmaxf(acct[m][nl][r], 0.f);
        }
  }

  f32x4v acc[4][NTW];
  bias_init<NTW>(acc, bc, w, li);
  __syncthreads();

  for (int s8 = 0; s8 < 8; ++s8) {
    f16x8v af[4];
#pragma unroll
    for (int m = 0; m < 4; ++m) {
      int r = 16 * m + li;
      int gl = 4 * s8 + q;
      af[m] = *(const f16x8v*)&t_h[r * 256 + ((gl ^ (r & 7)) << 3)];
    }
#pragma unroll
    for (int nl = 0; nl < NTW; ++nl) {
      int ng = w * NTW + nl;
      f16x8v bf = *(const f16x8v*)&Bp[(size_t)((ng * 8 + s8) * 64 + lane) * 8];
#pragma unroll
      for (int m = 0; m < 4; ++m)
        acc[m][nl] = __builtin_amdgcn_mfma_f32_16x16x32_f16(af[m], bf, acc[m][nl], 0, 0, 0);
    }
  }
  __syncthreads();

  for (int c = tid; c < 64 * NG8; c += 256) {
    int e = c / NG8, g = c % NG8;
    f16x8v v = *(const f16x8v*)&gat[(size_t)src_s[e] * NOUT + g * 8];
    int pg = (g & ~7) | ((g + 2 * (e >> 4)) & 7);
    *(f16x8v*)&t_h[e * NOUT + pg * 8] = v;
  }
  __syncthreads();

#pragma unroll
  for (int nl = 0; nl < NTW; ++nl) {
    const int col = (w * NTW + nl) * 16 + li;
    const int gl2 = col >> 3;
    const int pg = (gl2 & ~7) | ((gl2 + 2 * q) & 7);
    const int loff = pg * 8 + (col & 7);
    float run = 0.f;
    int cur = dst_s[16 * q];
#pragma unroll
    for (int m = 0; m < 4; ++m) {
#pragma unroll
      for (int r = 0; r < 4; ++r) {
        int e = 16 * q + 4 * m + r;
        int d = dst_s[e];
        if (d != cur) {
          atomicAdd(&aggr[(size_t)cur * NOUT + col], run);
          run = 0.f; cur = d;
        }
        float xv = (float)t_h[e * NOUT + loff];
        run += fmaxf(xv + acc[m][nl][r], 0.f);
      }
    }
    atomicAdd(&aggr[(size_t)cur * NOUT + col], run);
  }
}

// ---------------------------------------------------------------------------
// MFMA node MLP 1
// ---------------------------------------------------------------------------
__global__ __launch_bounds__(256, 3) void node_mlp1_mfma(
    const float* __restrict__ x, const float* __restrict__ aggr1,
    const _Float16* __restrict__ BpA, const float* __restrict__ b1,
    const _Float16* __restrict__ BpB, const float* __restrict__ b2,
    _Float16* __restrict__ h1h) {
  __shared__ _Float16 t_h[64 * 256];
  const int tid = threadIdx.x;
  const int i0 = blockIdx.x * 64;
  const int lane = tid & 63, w = tid >> 6;
  const int q = lane >> 4, li = lane & 15;

#pragma unroll
  for (int r2 = 0; r2 < 2; ++r2) {
    int idx = tid + r2 * 256;
    int e = idx >> 3, g = idx & 7;
    int node = i0 + e;
    f16x8v v;
#pragma unroll
    for (int j = 0; j < 8; ++j) v[j] = (_Float16)0.f;
    if (node < NN) {
      float4 a0 = *(const float4*)&x[(size_t)node * 64 + g * 8];
      float4 a1 = *(const float4*)&x[(size_t)node * 64 + g * 8 + 4];
      float4 c0 = *(const float4*)&aggr1[(size_t)node * 64 + g * 8];
      float4 c1 = *(const float4*)&aggr1[(size_t)node * 64 + g * 8 + 4];
      v[0] = (_Float16)(a0.x + c0.x); v[1] = (_Float16)(a0.y + c0.y);
      v[2] = (_Float16)(a0.z + c0.z); v[3] = (_Float16)(a0.w + c0.w);
      v[4] = (_Float16)(a1.x + c1.x); v[5] = (_Float16)(a1.y + c1.y);
      v[6] = (_Float16)(a1.z + c1.z); v[7] = (_Float16)(a1.w + c1.w);
    }
    *(f16x8v*)&t_h[e * 64 + ((g ^ (e & 7)) << 3)] = v;
  }
  __syncthreads();

  f32x4v acc[4][4];
  bias_init<4>(acc, b1, w, li);
  mfma_gemm64<64, 256>(t_h, BpA, acc, w, lane);
  __syncthreads();

#pragma unroll
  for (int m = 0; m < 4; ++m)
#pragma unroll
    for (int nl = 0; nl < 4; ++nl)
#pragma unroll
      for (int r = 0; r < 4; ++r) {
        int row = 16 * m + 4 * q + r;
        int col = (w * 4 + nl) * 16 + li;
        int g = col >> 3;
        t_h[row * 256 + ((g ^ (row & 7)) << 3) + (col & 7)] =
            (_Float16)fmaxf(acc[m][nl][r], 0.f);
      }
  __syncthreads();

  bias_init<4>(acc, b2, w, li);
  mfma_gemm64<256, 256>(t_h, BpB, acc, w, lane);
  __syncthreads();

#pragma unroll
  for (int m = 0; m < 4; ++m)
#pragma unroll
    for (int nl = 0; nl < 4; ++nl)
#pragma unroll
      for (int r = 0; r < 4; ++r) {
        int row = 16 * m + 4 * q + r;
        int col = (w * 4 + nl) * 16 + li;
        t_h[row * 256 + col] = (_Float16)fmaxf(acc[m][nl][r], 0.f);
      }
  __syncthreads();

#pragma unroll
  for (int r8 = 0; r8 < 8; ++r8) {
    int idx = tid + r8 * 256;
    int e = idx >> 5, g = idx & 31;
    int node = i0 + e;
    if (node < NN)
      *(f16x8v*)&h1h[(size_t)node * 256 + g * 8] = *(const f16x8v*)&t_h[e * 256 + g * 8];
  }
}

// ---------------------------------------------------------------------------
// MFMA node MLP 2 + fused mean-pool numerator
// ---------------------------------------------------------------------------
__global__ __launch_bounds__(256, 3) void node_mlp2_mfma(
    const _Float16* __restrict__ h1h, const float* __restrict__ aggr2,
    const _Float16* __restrict__ BpA, const float* __restrict__ b1,
    const _Float16* __restrict__ BpB, const float* __restrict__ b2,
    const int* __restrict__ batch, float* __restrict__ pool) {
  __shared__ _Float16 t_h[64 * 256];
  __shared__ int batch_s[64];
  const int tid = threadIdx.x;
  const int i0 = blockIdx.x * 64;
  const int lane = tid & 63, w = tid >> 6;
  const int q = lane >> 4, li = lane & 15;

  if (tid < 64) batch_s[tid] = (i0 + tid < NN) ? batch[i0 + tid] : -1;

#pragma unroll
  for (int r8 = 0; r8 < 8; ++r8) {
    int idx = tid + r8 * 256;
    int e = idx >> 5, g = idx & 31;
    int node = i0 + e;
    f16x8v v;
#pragma unroll
    for (int j = 0; j < 8; ++j) v[j] = (_Float16)0.f;
    if (node < NN) {
      f16x8v a = *(const f16x8v*)&h1h[(size_t)node * 256 + g * 8];
      float4 c0 = *(const float4*)&aggr2[(size_t)node * 256 + g * 8];
      float4 c1 = *(const float4*)&aggr2[(size_t)node * 256 + g * 8 + 4];
      v[0] = (_Float16)((float)a[0] + c0.x); v[1] = (_Float16)((float)a[1] + c0.y);
      v[2] = (_Float16)((float)a[2] + c0.z); v[3] = (_Float16)((float)a[3] + c0.w);
      v[4] = (_Float16)((float)a[4] + c1.x); v[5] = (_Float16)((float)a[5] + c1.y);
      v[6] = (_Float16)((float)a[6] + c1.z); v[7] = (_Float16)((float)a[7] + c1.w);
    }
    *(f16x8v*)&t_h[e * 256 + ((g ^ (e & 7)) << 3)] = v;
  }
  __syncthreads();

  f32x4v acc[4][4];
  bias_init<4>(acc, b1, w, li);
  mfma_gemm64<256, 256>(t_h, BpA, acc, w, lane);
  __syncthreads();

#pragma unroll
  for (int m = 0; m < 4; ++m)
#pragma unroll
    for (int nl = 0; nl < 4; ++nl)
#pragma unroll
      for (int r = 0; r < 4; ++r) {
        int row = 16 * m + 4 * q + r;
        int col = (w * 4 + nl) * 16 + li;
        int g = col >> 3;
        t_h[row * 256 + ((g ^ (row & 7)) << 3) + (col & 7)] =
            (_Float16)fmaxf(acc[m][nl][r], 0.f);
      }
  __syncthreads();

  bias_init<4>(acc, b2, w, li);
  mfma_gemm64<256, 256>(t_h, BpB, acc, w, lane);
  __syncthreads();

#pragma unroll
  for (int m = 0; m < 4; ++m)
#pragma unroll
    for (int nl = 0; nl < 4; ++nl)
#pragma unroll
      for (int r = 0; r < 4; ++r) {
        int row = 16 * m + 4 * q + r;
        int col = (w * 4 + nl) * 16 + li;
        t_h[row * 256 + col] = (_Float16)fmaxf(acc[m][nl][r], 0.f);
      }
  __syncthreads();

  float run = 0.f;
  int curg = -2;
  for (int m = 0; m < 64; ++m) {
    int g = batch_s[m];
    if (g != curg) {
      if (curg >= 0) atomicAdd(&pool[curg * 256 + tid], run);
      run = 0.f; curg = g;
    }
    if (g >= 0) run += (float)t_h[m * 256 + tid];
  }
  if (curg >= 0) atomicAdd(&pool[curg * 256 + tid], run);
}

__global__ __launch_bounds__(128) void head_kernel(
    const float* __restrict__ pool, const float* __restrict__ counts,
    const float* __restrict__ l1w, const float* __restrict__ l1b,
    const float* __restrict__ l2w, const float* __restrict__ l2b,
    const float* __restrict__ hs_w, const float* __restrict__ hs_b,
    const float* __restrict__ hp_w, const float* __restrict__ hp_b,
    const float* __restrict__ hn_w, const float* __restrict__ hn_b,
    float* __restrict__ out) {
  const int g = blockIdx.x, tid = threadIdx.x;
  __shared__ float g_s[256], g1_s[128], g2_s[64];
  float cnt = fmaxf(counts[g], 1.0f);
  g_s[tid] = pool[g * 256 + tid] / cnt;
  g_s[tid + 128] = pool[g * 256 + tid + 128] / cnt;
  __syncthreads();
  float s = l1b[tid];
  for (int k = 0; k < 256; ++k) s = fmaf(g_s[k], l1w[k * 128 + tid], s);
  g1_s[tid] = fmaxf(s, 0.f);
  __syncthreads();
  if (tid < 64) {
    float s2 = l2b[tid];
    for (int k = 0; k < 128; ++k) s2 = fmaf(g1_s[k], l2w[k * 64 + tid], s2);
    g2_s[tid] = fmaxf(s2, 0.f);
  }
  __syncthreads();
  if (tid < 64) {
    float v = g2_s[tid];
    float a = v * hs_w[tid], b = v * hp_w[tid], c = v * hn_w[tid];
    for (int off = 32; off > 0; off >>= 1) {
      a += __shfl_down(a, off, 64);
      b += __shfl_down(b, off, 64);
      c += __shfl_down(c, off, 64);
    }
    if (tid == 0) {
      out[g]        = a + hs_b[0];
      out[64 + g]   = b + hp_b[0];
      out[128 + g]  = c + hn_b[0];
    }
  }
}

extern "C" void kernel_launch(void* const* d_in, const int* in_sizes, int n_in,
                              void* d_out, int out_size, void* d_ws, size_t ws_size,
                              hipStream_t stream) {
  (void)in_sizes; (void)n_in; (void)out_size; (void)ws_size;
  const float* x         = (const float*)d_in[0];
  const int*   eidx      = (const int*)d_in[1];
  const int*   batch     = (const int*)d_in[2];
  const float* edge_attr = (const float*)d_in[3];
  const float* ew1  = (const float*)d_in[4];
  const float* eb1  = (const float*)d_in[5];
  const float* ew2  = (const float*)d_in[6];
  const float* eb2  = (const float*)d_in[7];
  const float* le1w = (const float*)d_in[8];
  const float* le1b = (const float*)d_in[9];
  const float* le2w = (const float*)d_in[10];
  const float* le2b = (const float*)d_in[11];
  const float* n1w1 = (const float*)d_in[12];
  const float* n1b1 = (const float*)d_in[13];
  const float* n1w2 = (const float*)d_in[14];
  const float* n1b2 = (const float*)d_in[15];
  const float* n2w1 = (const float*)d_in[16];
  const float* n2b1 = (const float*)d_in[17];
  const float* n2w2 = (const float*)d_in[18];
  const float* n2b2 = (const float*)d_in[19];
  const float* l1w  = (const float*)d_in[20];
  const float* l1b  = (const float*)d_in[21];
  const float* l2w  = (const float*)d_in[22];
  const float* l2b  = (const float*)d_in[23];
  const float* hs_w = (const float*)d_in[24];
  const float* hs_b = (const float*)d_in[25];
  const float* hp_w = (const float*)d_in[26];
  const float* hp_b = (const float*)d_in[27];
  const float* hn_w = (const float*)d_in[28];
  const float* hn_b = (const float*)d_in[29];

  float* ws    = (float*)d_ws;
  float* b1c   = ws + OFF_B1C;
  float* b2c   = ws + OFF_B2C;
  float* aggr1 = ws + OFF_AGGR1;
  float* aggr2 = ws + OFF_AGGR2;
  _Float16* h1h = (_Float16*)(ws + OFF_H1H);
  _Float16* xh  = (_Float16*)(ws + OFF_XH);
  float* pool  = ws + OFF_POOL;
  float* cnts  = ws + OFF_CNT;
  int*   cursor= (int*)ws + OFF_CURSOR;
  int*   rowptr= (int*)ws + OFF_ROWPTR;
  int*   perm  = (int*)ws + OFF_PERM;
  _Float16* Bp1  = (_Float16*)(ws + OFF_BP1);
  _Float16* Bp2  = (_Float16*)(ws + OFF_BP2);
  _Float16* BpN1a = (_Float16*)(ws + OFF_BN1A);
  _Float16* BpN1b = (_Float16*)(ws + OFF_BN1B);
  _Float16* BpN2a = (_Float16*)(ws + OFF_BN2A);
  _Float16* BpN2b = (_Float16*)(ws + OFF_BN2B);
  _Float16* Bpe  = (_Float16*)(ws + OFF_BPE);
  float* out   = (float*)d_out;

  hipMemsetAsync(aggr1, 0, (size_t)NN * 64 * 4, stream);
  hipMemsetAsync(aggr2, 0, (size_t)NN * 256 * 4, stream);
  hipMemsetAsync(pool, 0, (size_t)NG * 256 * 4, stream);
  hipMemsetAsync(cursor, 0, (size_t)NN * 4, stream);

  prep_all<<<(PR_END + 255) / 256, 256, 0, stream>>>(
      ew1, eb1, ew2, eb2, le1w, le1b, le2w, le2b,
      n1w1, n1w2, n2w1, n2w2, x, batch, eidx,
      Bp1, Bp2, BpN1a, BpN1b, BpN2a, BpN2b, Bpe, b1c, b2c, xh, cnts, cursor);

  scan_rowptr<<<1, 1024, 0, stream>>>(cursor, rowptr);
  scatter_perm<<<(NE + 255) / 256, 256, 0, stream>>>(eidx, cursor, perm);

  edge_conv_mfma<64><<<NE / 64, 256, 0, stream>>>(edge_attr, eidx, perm, Bpe, eb1,
                                                  Bp1, b1c, xh, aggr1);
  node_mlp1_mfma<<<(NN + 63) / 64, 256, 0, stream>>>(x, aggr1, BpN1a, n1b1, BpN1b, n1b2, h1h);
  edge_conv_mfma<256><<<NE / 64, 256, 0, stream>>>(edge_attr, eidx, perm, Bpe, eb1,
                                                   Bp2, b2c, h1h, aggr2);
  node_mlp2_mfma<<<(NN + 63) / 64, 256, 0, stream>>>(h1h, aggr2, BpN2a, n2b1, BpN2b, n2b2,
                                                     batch, pool);
  head_kernel<<<NG, 128, 0, stream>>>(pool, cnts, l1w, l1b, l2w, l2b,
                                      hs_w, hs_b, hp_w, hp_b, hn_w, hn_b, out);
}